// Round 4
// baseline (1151.145 us; speedup 1.0000x reference)
//
#include <hip/hip_runtime.h>
#include <hip/hip_bf16.h>

#define B_   2
#define N_   384
#define DIM_ 256
#define H_   4
#define DH_  64
#define PD_  128
#define ED_  16
#define NU_  ((B_ * N_ * N_) / 32)   // 9216 wave-units (32 pairs each)

typedef _Float16 v8h __attribute__((ext_vector_type(8)));
typedef float    v4f __attribute__((ext_vector_type(4)));

__device__ __forceinline__ float gelu_(float x) {
    return 0.5f * x * (1.0f + erff(x * 0.70710678118654752f));
}

// full-block reduction over 256 threads (4 waves)
__device__ __forceinline__ float block_reduce256(float v, float* red) {
    #pragma unroll
    for (int o = 32; o > 0; o >>= 1) v += __shfl_xor(v, o, 64);
    __syncthreads();
    if ((threadIdx.x & 63) == 0) red[threadIdx.x >> 6] = v;
    __syncthreads();
    return red[0] + red[1] + red[2] + red[3];
}

// batched float4 block reduction over 384 threads (6 waves).
__device__ __forceinline__ float4 block_reduce4(float4 v, bool ismax, float4* red, int slot) {
    #pragma unroll
    for (int o = 32; o > 0; o >>= 1) {
        float x = __shfl_xor(v.x, o), y = __shfl_xor(v.y, o);
        float z = __shfl_xor(v.z, o), w = __shfl_xor(v.w, o);
        if (ismax) { v.x = fmaxf(v.x, x); v.y = fmaxf(v.y, y); v.z = fmaxf(v.z, z); v.w = fmaxf(v.w, w); }
        else       { v.x += x; v.y += y; v.z += z; v.w += w; }
    }
    if ((threadIdx.x & 63) == 0) red[slot * 8 + (threadIdx.x >> 6)] = v;
    __syncthreads();
    float4 r = red[slot * 8];
    #pragma unroll
    for (int w2 = 1; w2 < 6; w2++) {
        float4 o = red[slot * 8 + w2];
        if (ismax) { r.x = fmaxf(r.x, o.x); r.y = fmaxf(r.y, o.y); r.z = fmaxf(r.z, o.z); r.w = fmaxf(r.w, o.w); }
        else       { r.x += o.x; r.y += o.y; r.z += o.z; r.w += o.w; }
    }
    return r;
}

// ---------- K1: LayerNorm + QKV + gates ----------
__global__ __launch_bounds__(256) void eq_k1(
    const float* __restrict__ feats, const float* __restrict__ gamma,
    const float* __restrict__ w_qkv, const float* __restrict__ w_gate,
    const float* __restrict__ b_gate,
    float* __restrict__ q, float* __restrict__ kT, float* __restrict__ v,
    float* __restrict__ og, float* __restrict__ rg) {
    int row = blockIdx.x;           // b*N + n
    int b = row / N_, n = row - b * N_;
    int t = threadIdx.x;
    __shared__ float xs[DIM_];
    __shared__ float red[4];
    float f = feats[(long)row * DIM_ + t];
    float mean = block_reduce256(f, red) * (1.0f / DIM_);
    float d = f - mean;
    float var = block_reduce256(d * d, red) * (1.0f / DIM_);
    float x = d * rsqrtf(var + 1e-5f) * gamma[t];
    xs[t] = x;
    __syncthreads();
    float a0 = 0, a1 = 0, a2 = 0;
    for (int c = 0; c < DIM_; c++) {
        float xc = xs[c];
        const float* wr = w_qkv + (long)c * 768;
        a0 += xc * wr[t];
        a1 += xc * wr[t + 256];
        a2 += xc * wr[t + 512];
    }
    int h = t >> 6, dd = t & 63;
    q[((b * H_ + h) * N_ + n) * DH_ + dd]  = a0 * 0.125f;      // dh^-0.5 pre-applied
    kT[((b * H_ + h) * DH_ + dd) * N_ + n] = a1;               // transposed for coalesced reads
    v[((b * H_ + h) * N_ + n) * DH_ + dd]  = a2;
    if (t < 8) {
        float acc = b_gate[t];
        for (int c = 0; c < DIM_; c++) acc += xs[c] * w_gate[c * 8 + t];
        float g = 1.0f / (1.0f + __expf(-acc));
        if (t < 4) og[(b * H_ + t) * N_ + n] = g;
        else       rg[(b * H_ + (t - 4)) * N_ + n] = g;
    }
}

// ---------- K2: position-bias MLP, wave-independent MFMA ----------
// Each wave owns 32 pairs (2 m-tiles x 16) and ALL 128 channels (8 n-tiles):
// LayerNorm = 4-step shfl butterfly within 16-lane groups -> NO barriers in
// the main loop. W1^T/W2^T in LDS (B-frag reads), wave-private h slices.
// 512 thr/block, 145152 B dynamic LDS -> 1 block/CU, 2 waves/SIMD;
// amdgpu_waves_per_eu(2,2) pins the VGPR budget at 256 (no spill).
#define MFMA16(a, b, c) __builtin_amdgcn_mfma_f32_16x16x32_f16(a, b, c, 0, 0, 0)

#define LNAPPLY(gr_, ber_)                                                        \
{                                                                                  \
    _Pragma("unroll")                                                              \
    for (int mt = 0; mt < 2; mt++) {                                               \
        _Pragma("unroll")                                                          \
        for (int rg2 = 0; rg2 < 4; rg2++) {                                        \
            float s = 0.f, sq = 0.f;                                               \
            _Pragma("unroll")                                                      \
            for (int nt = 0; nt < 8; nt++) {                                       \
                float v0 = acc[mt][nt][rg2]; s += v0; sq += v0 * v0;               \
            }                                                                      \
            s += __shfl_xor(s, 1); sq += __shfl_xor(sq, 1);                        \
            s += __shfl_xor(s, 2); sq += __shfl_xor(sq, 2);                        \
            s += __shfl_xor(s, 4); sq += __shfl_xor(sq, 4);                        \
            s += __shfl_xor(s, 8); sq += __shfl_xor(sq, 8);                        \
            float mean = s * (1.f / 128.f);                                        \
            float inv = rsqrtf(sq * (1.f / 128.f) - mean * mean + 1e-5f);          \
            int row2 = mt * 16 + quad * 4 + rg2;                                   \
            _Pragma("unroll")                                                      \
            for (int nt = 0; nt < 8; nt++) {                                       \
                float y = (acc[mt][nt][rg2] - mean) * inv * gr_[nt] + ber_[nt];    \
                y = y / (1.f + __expf(-y));                                        \
                myslice[row2 * 136 + nt * 16 + l15] = (_Float16)y;                 \
            }                                                                      \
        }                                                                          \
    }                                                                              \
}

__global__ __launch_bounds__(512) __attribute__((amdgpu_waves_per_eu(2, 2)))
void eq_k2(
    const float* __restrict__ coors,
    const float* __restrict__ w0, const float* __restrict__ b0,
    const float* __restrict__ g0, const float* __restrict__ be0,
    const float* __restrict__ W1g, const float* __restrict__ b1,
    const float* __restrict__ g1, const float* __restrict__ be1,
    const float* __restrict__ W2g, const float* __restrict__ b2,
    const float* __restrict__ g2, const float* __restrict__ be2,
    const float* __restrict__ wqk, const float* __restrict__ bqk,
    _Float16* __restrict__ pout, float* __restrict__ qkpos) {

    extern __shared__ char smem[];
    _Float16* W1T    = (_Float16*)smem;                  // 128x136 = 34816 B
    _Float16* W2T    = (_Float16*)(smem + 34816);        // 34816 B
    _Float16* slices = (_Float16*)(smem + 69632);        // 8 x 32x136 = 69632 B
    _Float16* wqT    = (_Float16*)(smem + 139264);       // 16x136 = 4352 B
    float*    PQR    = (float*)(smem + 143616);          // 3x128 f32 = 1536 B

    const int t = threadIdx.x;
    const int lane = t & 63, wv = t >> 6;
    const int l15 = lane & 15, quad = lane >> 4;
    _Float16* myslice = slices + wv * (32 * 136);

    for (int idx = t; idx < 16384; idx += 512) {
        int k = idx >> 7, n = idx & 127;
        W1T[n * 136 + k] = (_Float16)W1g[idx];
        W2T[n * 136 + k] = (_Float16)W2g[idx];
    }
    for (int idx = t; idx < 2048; idx += 512) {
        int n = idx >> 7, k = idx & 127;
        wqT[n * 136 + k] = (n < 4) ? (_Float16)wqk[k * 4 + n] : (_Float16)0.f;
    }
    // layer0 closed-form LN stats (redundant per thread, init-only)
    float Sw = 0, Sb = 0, Sww = 0, Swb = 0, Sbb = 0;
    for (int c = 0; c < 128; c++) {
        float w = w0[c], bb2v = b0[c];
        Sw += w; Sb += bb2v; Sww += w * w; Swb += w * bb2v; Sbb += bb2v * bb2v;
    }
    const float mw = Sw * (1.f / 128.f), mbb = Sb * (1.f / 128.f);
    const float A2 = Sww * (1.f / 128.f) - mw * mw;
    const float AD = Swb * (1.f / 128.f) - mw * mbb;
    const float D2 = Sbb * (1.f / 128.f) - mbb * mbb;
    if (t < 128) {
        PQR[t]       = (w0[t] - mw) * g0[t];
        PQR[128 + t] = (b0[t] - mbb) * g0[t];
        PQR[256 + t] = be0[t];
    }
    // per-lane channel params for layers 1/2 (c = nt*16 + l15)
    float b1r[8], g1r[8], be1r[8], b2r[8], g2r[8], be2r[8];
    #pragma unroll
    for (int nt = 0; nt < 8; nt++) {
        int c = nt * 16 + l15;
        b1r[nt] = b1[c]; g1r[nt] = g1[c]; be1r[nt] = be1[c];
        b2r[nt] = b2[c]; g2r[nt] = g2[c]; be2r[nt] = be2[c];
    }
    const float bq = (l15 < 4) ? bqk[l15] : 0.f;
    __syncthreads();   // the only barrier

    for (int unit = blockIdx.x * 8 + wv; unit < NU_; unit += 256 * 8) {
        const int P0w = unit * 32;
        const int b = P0w / (N_ * N_);
        const int rem = P0w - b * (N_ * N_);
        const int ii = rem / N_;
        const int j0 = rem - ii * N_;
        const float cix = coors[(b * N_ + ii) * 3 + 0];
        const float ciy = coors[(b * N_ + ii) * 3 + 1];
        const float ciz = coors[(b * N_ + ii) * 3 + 2];
        float tt[2], uu[2];
        v8h A[2][4];
        #pragma unroll
        for (int mt = 0; mt < 2; mt++) {
            int j = j0 + mt * 16 + l15;
            float dx = cix - coors[(b * N_ + j) * 3 + 0];
            float dy = ciy - coors[(b * N_ + j) * 3 + 1];
            float dz = ciz - coors[(b * N_ + j) * 3 + 2];
            float d = sqrtf(dx * dx + dy * dy + dz * dz);
            float var = (d * d) * A2 + 2.f * d * AD + D2;
            float inv = rsqrtf(var + 1e-5f);
            tt[mt] = d * inv; uu[mt] = inv;
        }
        // layer0 directly into A-fragments: y = t*P + u*Q + R, silu
        #pragma unroll
        for (int kt = 0; kt < 4; kt++) {
            int base = kt * 32 + quad * 8;
            float4 Pa = *(const float4*)&PQR[base],       Pb = *(const float4*)&PQR[base + 4];
            float4 Qa = *(const float4*)&PQR[128 + base], Qb = *(const float4*)&PQR[128 + base + 4];
            float4 Ra = *(const float4*)&PQR[256 + base], Rb = *(const float4*)&PQR[256 + base + 4];
            float Pj[8] = {Pa.x, Pa.y, Pa.z, Pa.w, Pb.x, Pb.y, Pb.z, Pb.w};
            float Qj[8] = {Qa.x, Qa.y, Qa.z, Qa.w, Qb.x, Qb.y, Qb.z, Qb.w};
            float Rj[8] = {Ra.x, Ra.y, Ra.z, Ra.w, Rb.x, Rb.y, Rb.z, Rb.w};
            #pragma unroll
            for (int mt = 0; mt < 2; mt++) {
                v8h av;
                #pragma unroll
                for (int jj = 0; jj < 8; jj++) {
                    float y = tt[mt] * Pj[jj] + uu[mt] * Qj[jj] + Rj[jj];
                    av[jj] = (_Float16)(y / (1.f + __expf(-y)));
                }
                A[mt][kt] = av;
            }
        }
        // ---- layer1: h0 @ W1 + b1 ----
        v4f acc[2][8];
        #pragma unroll
        for (int nt = 0; nt < 8; nt++) {
            v4f ci = {b1r[nt], b1r[nt], b1r[nt], b1r[nt]};
            acc[0][nt] = ci; acc[1][nt] = ci;
        }
        #pragma unroll
        for (int kt = 0; kt < 4; kt++) {
            #pragma unroll
            for (int nt = 0; nt < 8; nt++) {
                v8h Bv = *(const v8h*)&W1T[(nt * 16 + l15) * 136 + kt * 32 + quad * 8];
                acc[0][nt] = MFMA16(A[0][kt], Bv, acc[0][nt]);
                acc[1][nt] = MFMA16(A[1][kt], Bv, acc[1][nt]);
            }
        }
        LNAPPLY(g1r, be1r)
        // ---- layer2: h1 @ W2 + b2 ----
        #pragma unroll
        for (int mt = 0; mt < 2; mt++)
            #pragma unroll
            for (int kt = 0; kt < 4; kt++)
                A[mt][kt] = *(const v8h*)&myslice[(mt * 16 + l15) * 136 + kt * 32 + quad * 8];
        #pragma unroll
        for (int nt = 0; nt < 8; nt++) {
            v4f ci = {b2r[nt], b2r[nt], b2r[nt], b2r[nt]};
            acc[0][nt] = ci; acc[1][nt] = ci;
        }
        #pragma unroll
        for (int kt = 0; kt < 4; kt++) {
            #pragma unroll
            for (int nt = 0; nt < 8; nt++) {
                v8h Bv = *(const v8h*)&W2T[(nt * 16 + l15) * 136 + kt * 32 + quad * 8];
                acc[0][nt] = MFMA16(A[0][kt], Bv, acc[0][nt]);
                acc[1][nt] = MFMA16(A[1][kt], Bv, acc[1][nt]);
            }
        }
        LNAPPLY(g2r, be2r)
        // ---- p store: 16B/lane coalesced from own slice ----
        #pragma unroll
        for (int it = 0; it < 8; it++) {
            int pos = it * 512 + lane * 8;
            int row = pos >> 7, cc = pos & 127;
            *(v8h*)&pout[(long)(P0w + row) * 128 + cc] = *(const v8h*)&myslice[row * 136 + cc];
        }
        // ---- qk_pos = p @ wqk + bqk ----
        #pragma unroll
        for (int mt = 0; mt < 2; mt++) {
            v4f c = {0.f, 0.f, 0.f, 0.f};
            #pragma unroll
            for (int kt = 0; kt < 4; kt++) {
                v8h av = *(const v8h*)&myslice[(mt * 16 + l15) * 136 + kt * 32 + quad * 8];
                v8h wq = *(const v8h*)&wqT[l15 * 136 + kt * 32 + quad * 8];
                c = MFMA16(av, wq, c);
            }
            if (l15 < 4) {
                #pragma unroll
                for (int rg2 = 0; rg2 < 4; rg2++) {
                    int row = mt * 16 + quad * 4 + rg2;
                    qkpos[(long)(P0w + row) * 4 + l15] = c[rg2] + bq;
                }
            }
        }
    }
}

// ---------- K3M: fused scores/edge-MLP/softmax/coor-branch/ap/attn@v/out-proj ----------
__global__ __launch_bounds__(384) void eq_k3m(
    const float* __restrict__ q, const float* __restrict__ kT,
    const float* __restrict__ edges, const float* __restrict__ qkpos,
    const _Float16* __restrict__ p, const float* __restrict__ v,
    const float* __restrict__ coors,
    const float* __restrict__ w_e1, const float* __restrict__ w_e2,
    const float* __restrict__ w_c, const float* __restrict__ w_cg,
    const float* __restrict__ b_cg, const float* __restrict__ w_th,
    const float* __restrict__ cscale, const float* __restrict__ ccomb,
    const float* __restrict__ og, const float* __restrict__ rg,
    const float* __restrict__ w_vpos, const float* __restrict__ b_vpos,
    const float* __restrict__ w_out, const float* __restrict__ b_out,
    float* __restrict__ out0, float* __restrict__ out1) {
    int row = blockIdx.x;           // b*N + i
    int b = row / N_, i = row - b * N_;
    int j = threadIdx.x;            // 0..383
    __shared__ float qs[H_ * DH_];
    __shared__ float we1[20 * 40];
    __shared__ float we2[40 * 4];
    __shared__ float wcs[16], wcgs[16], bcgs[4], wths[16];
    __shared__ float attnS[4 * N_];
    __shared__ float apS[4 * PD_];
    __shared__ float nodeS[256];
    __shared__ float4 red4[16];

    if (j < 256) qs[j] = q[((b * H_ + (j >> 6)) * N_ + i) * DH_ + (j & 63)];
    for (int idx = j; idx < 800; idx += 384) we1[idx] = w_e1[idx];
    if (j < 160) we2[j] = w_e2[j];
    if (j < 16) { wcs[j] = w_c[j]; wcgs[j] = w_cg[j]; wths[j] = w_th[j]; }
    if (j < 4) bcgs[j] = b_cg[j];
    __syncthreads();

    // ---- phase A: scores + edge MLP (per j) ----
    long pair = ((long)row) * N_ + j;
    float in20[20];
    #pragma unroll
    for (int h = 0; h < H_; h++) {
        float acc = 0;
        const float* kp = kT + ((long)(b * H_ + h) * DH_) * N_ + j;
        #pragma unroll 8
        for (int d = 0; d < DH_; d++) acc += qs[h * DH_ + d] * kp[(long)d * N_];
        in20[h] = acc;
    }
    {
        float4 qp = *(const float4*)(qkpos + pair * 4);
        in20[0] += qp.x; in20[1] += qp.y; in20[2] += qp.z; in20[3] += qp.w;
    }
    const float4* ep = (const float4*)(edges + pair * ED_);
    float4 e0 = ep[0], e1 = ep[1], e2 = ep[2], e3 = ep[3];
    in20[4] = e0.x;  in20[5] = e0.y;  in20[6] = e0.z;  in20[7] = e0.w;
    in20[8] = e1.x;  in20[9] = e1.y;  in20[10] = e1.z; in20[11] = e1.w;
    in20[12] = e2.x; in20[13] = e2.y; in20[14] = e2.z; in20[15] = e2.w;
    in20[16] = e3.x; in20[17] = e3.y; in20[18] = e3.z; in20[19] = e3.w;

    // edge MLP hidden layer: a[40] in registers, float4 LDS weight reads
    float a[40];
    #pragma unroll
    for (int o = 0; o < 40; o++) a[o] = 0.f;
    #pragma unroll
    for (int c = 0; c < 20; c++) {
        float xc = in20[c];
        #pragma unroll
        for (int o4 = 0; o4 < 10; o4++) {
            float4 wv4 = *(const float4*)&we1[c * 40 + o4 * 4];
            a[o4 * 4 + 0] += xc * wv4.x;
            a[o4 * 4 + 1] += xc * wv4.y;
            a[o4 * 4 + 2] += xc * wv4.z;
            a[o4 * 4 + 3] += xc * wv4.w;
        }
    }
    float c0 = 0, c1 = 0, c2 = 0, c3 = 0;
    #pragma unroll
    for (int o = 0; o < 40; o++) {
        float gg = gelu_(a[o]);
        float4 w2v = *(const float4*)&we2[o * 4];
        c0 += gg * w2v.x; c1 += gg * w2v.y; c2 += gg * w2v.z; c3 += gg * w2v.w;
    }
    float cmi[4] = {c0, c1, c2, c3};
    float gc[4], cp[4], rs[4];
    #pragma unroll
    for (int h = 0; h < 4; h++) gc[h] = gelu_(cmi[h]);
    #pragma unroll
    for (int h = 0; h < 4; h++) {
        cp[h] = gc[0] * wcs[h] + gc[1] * wcs[4 + h] + gc[2] * wcs[8 + h] + gc[3] * wcs[12 + h];
        rs[h] = cmi[0] * wcgs[h] + cmi[1] * wcgs[4 + h] + cmi[2] * wcgs[8 + h] + cmi[3] * wcgs[12 + h] + bcgs[h];
    }

    // ---- phase B: softmax over j + talking heads -> attnS ----
    float4 m4 = block_reduce4(make_float4(cmi[0], cmi[1], cmi[2], cmi[3]), true, red4, 0);
    float e[4];
    e[0] = __expf(cmi[0] - m4.x); e[1] = __expf(cmi[1] - m4.y);
    e[2] = __expf(cmi[2] - m4.z); e[3] = __expf(cmi[3] - m4.w);
    float4 l4 = block_reduce4(make_float4(e[0], e[1], e[2], e[3]), false, red4, 1);
    float sm[4] = {e[0] / l4.x, e[1] / l4.y, e[2] / l4.z, e[3] / l4.w};
    #pragma unroll
    for (int h = 0; h < 4; h++)
        attnS[h * N_ + j] = wths[h * 4 + 0] * sm[0] + wths[h * 4 + 1] * sm[1]
                          + wths[h * 4 + 2] * sm[2] + wths[h * 4 + 3] * sm[3];

    // ---- phase C: coordinate branch -> out1 ----
    float dx = coors[(b * N_ + i) * 3 + 0] - coors[(b * N_ + j) * 3 + 0];
    float dy = coors[(b * N_ + i) * 3 + 1] - coors[(b * N_ + j) * 3 + 1];
    float dz = coors[(b * N_ + i) * 3 + 2] - coors[(b * N_ + j) * 3 + 2];
    float nrm = sqrtf(dx * dx + dy * dy + dz * dz);
    float sc = cscale[0] / fmaxf(nrm, 1e-8f);
    float rx = dx * sc, ry = dy * sc, rz = dz * sc;
    float4 cm4 = block_reduce4(make_float4(cp[0], cp[1], cp[2], cp[3]), true, red4, 0);
    float ec[4];
    ec[0] = __expf(cp[0] - cm4.x); ec[1] = __expf(cp[1] - cm4.y);
    ec[2] = __expf(cp[2] - cm4.z); ec[3] = __expf(cp[3] - cm4.w);
    float4 cl4 = block_reduce4(make_float4(ec[0], ec[1], ec[2], ec[3]), false, red4, 1);
    float w[4] = {ec[0] / cl4.x * rs[0], ec[1] / cl4.y * rs[1],
                  ec[2] / cl4.z * rs[2], ec[3] / cl4.w * rs[3]};
    float4 sx4 = block_reduce4(make_float4(w[0] * rx, w[1] * rx, w[2] * rx, w[3] * rx), false, red4, 0);
    float4 sy4 = block_reduce4(make_float4(w[0] * ry, w[1] * ry, w[2] * ry, w[3] * ry), false, red4, 1);
    float4 sz4 = block_reduce4(make_float4(w[0] * rz, w[1] * rz, w[2] * rz, w[3] * rz), false, red4, 0);
    if (j == 0) {
        float f0 = ccomb[0] * rg[(b * H_ + 0) * N_ + i];
        float f1 = ccomb[1] * rg[(b * H_ + 1) * N_ + i];
        float f2 = ccomb[2] * rg[(b * H_ + 2) * N_ + i];
        float f3 = ccomb[3] * rg[(b * H_ + 3) * N_ + i];
        out1[(b * N_ + i) * 3 + 0] = f0 * sx4.x + f1 * sx4.y + f2 * sx4.z + f3 * sx4.w;
        out1[(b * N_ + i) * 3 + 1] = f0 * sy4.x + f1 * sy4.y + f2 * sy4.z + f3 * sy4.w;
        out1[(b * N_ + i) * 3 + 2] = f0 * sz4.x + f1 * sz4.y + f2 * sz4.z + f3 * sz4.w;
    }
    __syncthreads();

    // ---- phase D: threads 0..127 -> ap; threads 128..383 -> attn@v ----
    if (j < 128) {
        float a0 = 0, a1 = 0, a2 = 0, a3 = 0;
        const _Float16* pp = p + ((long)row * N_) * PD_ + j;
        #pragma unroll 4
        for (int jj = 0; jj < N_; jj++) {
            float pv = (float)pp[(long)jj * PD_];
            a0 += attnS[jj] * pv;
            a1 += attnS[N_ + jj] * pv;
            a2 += attnS[2 * N_ + jj] * pv;
            a3 += attnS[3 * N_ + jj] * pv;
        }
        apS[j] = a0; apS[PD_ + j] = a1; apS[2 * PD_ + j] = a2; apS[3 * PD_ + j] = a3;
    } else {
        int tt = j - 128, h = tt >> 6, d = tt & 63;
        float acc = 0;
        const float* vp = v + ((long)(b * H_ + h) * N_) * DH_ + d;
        #pragma unroll 8
        for (int jj = 0; jj < N_; jj++) acc += attnS[h * N_ + jj] * vp[(long)jj * DH_];
        nodeS[tt] = acc;
    }
    __syncthreads();

    // ---- phase E: node = (attnv + ap@w_vpos + Sh*b_vpos) * out_gate ----
    float nv = 0;
    if (j < 256) {
        int h = j >> 6, d = j & 63;
        float accp = 0;
        const float* wv = w_vpos + h * DH_ + d;
        #pragma unroll 8
        for (int c = 0; c < PD_; c++) accp += apS[h * PD_ + c] * wv[(long)c * (H_ * DH_)];
        float Sh = wths[h * 4 + 0] + wths[h * 4 + 1] + wths[h * 4 + 2] + wths[h * 4 + 3];
        nv = (nodeS[j] + accp + Sh * b_vpos[h * DH_ + d]) * og[(b * H_ + h) * N_ + i];
    }
    __syncthreads();
    if (j < 256) nodeS[j] = nv;
    __syncthreads();

    // ---- phase F: out0 = node @ w_out + b_out ----
    if (j < 256) {
        float acc = b_out[j];
        #pragma unroll 8
        for (int c = 0; c < 256; c++) acc += nodeS[c] * w_out[(long)c * 256 + j];
        out0[(long)row * 256 + j] = acc;
    }
}

extern "C" void kernel_launch(void* const* d_in, const int* in_sizes, int n_in,
                              void* d_out, int out_size, void* d_ws, size_t ws_size,
                              hipStream_t stream) {
    (void)in_sizes; (void)n_in; (void)out_size; (void)ws_size;
    const float* feats   = (const float*)d_in[0];
    const float* coors   = (const float*)d_in[1];
    const float* edges   = (const float*)d_in[2];
    const float* gamma   = (const float*)d_in[3];
    const float* w_qkv   = (const float*)d_in[4];
    const float* w_gate  = (const float*)d_in[5];
    const float* b_gate  = (const float*)d_in[6];
    const float* w_th    = (const float*)d_in[7];
    const float* w_e1    = (const float*)d_in[8];
    const float* w_e2    = (const float*)d_in[9];
    const float* w_c     = (const float*)d_in[10];
    const float* w_cg    = (const float*)d_in[11];
    const float* b_cg    = (const float*)d_in[12];
    const float* cscale  = (const float*)d_in[13];
    const float* ccomb   = (const float*)d_in[14];
    const float* pb_w0   = (const float*)d_in[15];
    const float* pb_b0   = (const float*)d_in[16];
    const float* pb_g0   = (const float*)d_in[17];
    const float* pb_be0  = (const float*)d_in[18];
    const float* pb_w1   = (const float*)d_in[19];
    const float* pb_b1   = (const float*)d_in[20];
    const float* pb_g1   = (const float*)d_in[21];
    const float* pb_be1  = (const float*)d_in[22];
    const float* pb_w2   = (const float*)d_in[23];
    const float* pb_b2   = (const float*)d_in[24];
    const float* pb_g2   = (const float*)d_in[25];
    const float* pb_be2  = (const float*)d_in[26];
    const float* w_qkpos = (const float*)d_in[27];
    const float* b_qkpos = (const float*)d_in[28];
    const float* w_vpos  = (const float*)d_in[29];
    const float* b_vpos  = (const float*)d_in[30];
    const float* w_out   = (const float*)d_in[31];
    const float* b_out   = (const float*)d_in[32];

    // workspace carve (floats)
    float* wsf    = (float*)d_ws;
    float* q      = wsf;                    // 196608
    float* kT     = q      + 196608;        // 196608
    float* v      = kT     + 196608;        // 196608
    float* og     = v      + 196608;        // 3072
    float* rg     = og     + 3072;          // 3072
    float* qkpos  = rg     + 3072;          // 1179648 (b,i,j,h)
    _Float16* pbuf = (_Float16*)(qkpos + 1179648);  // 37748736 f16

    float* out0 = (float*)d_out;
    float* out1 = out0 + (long)B_ * N_ * DIM_;

    const int K2_LDS = 145152;
    hipFuncSetAttribute((const void*)eq_k2, hipFuncAttributeMaxDynamicSharedMemorySize, K2_LDS);

    eq_k1<<<B_ * N_, 256, 0, stream>>>(feats, gamma, w_qkv, w_gate, b_gate, q, kT, v, og, rg);
    eq_k2<<<256, 512, K2_LDS, stream>>>(coors, pb_w0, pb_b0, pb_g0, pb_be0,
                                        pb_w1, pb_b1, pb_g1, pb_be1,
                                        pb_w2, pb_b2, pb_g2, pb_be2,
                                        w_qkpos, b_qkpos, pbuf, qkpos);
    eq_k3m<<<B_ * N_, 384, 0, stream>>>(q, kT, edges, qkpos, pbuf, v, coors,
                                        w_e1, w_e2, w_c, w_cg, b_cg, w_th,
                                        cscale, ccomb, og, rg,
                                        w_vpos, b_vpos, w_out, b_out, out0, out1);
}

// Round 5
// 559.731 us; speedup vs baseline: 2.0566x; 2.0566x over previous
//
#include <hip/hip_runtime.h>
#include <hip/hip_bf16.h>

#define B_   2
#define N_   384
#define DIM_ 256
#define H_   4
#define DH_  64
#define PD_  128
#define ED_  16
#define NU_  ((B_ * N_ * N_) / 32)   // 9216 wave-units (32 pairs each)

typedef _Float16 v8h __attribute__((ext_vector_type(8)));
typedef float    v4f __attribute__((ext_vector_type(4)));

__device__ __forceinline__ float gelu_(float x) {
    return 0.5f * x * (1.0f + erff(x * 0.70710678118654752f));
}

// full-block reduction over 256 threads (4 waves)
__device__ __forceinline__ float block_reduce256(float v, float* red) {
    #pragma unroll
    for (int o = 32; o > 0; o >>= 1) v += __shfl_xor(v, o, 64);
    __syncthreads();
    if ((threadIdx.x & 63) == 0) red[threadIdx.x >> 6] = v;
    __syncthreads();
    return red[0] + red[1] + red[2] + red[3];
}

// batched float4 block reduction over 384 threads (6 waves).
__device__ __forceinline__ float4 block_reduce4(float4 v, bool ismax, float4* red, int slot) {
    #pragma unroll
    for (int o = 32; o > 0; o >>= 1) {
        float x = __shfl_xor(v.x, o), y = __shfl_xor(v.y, o);
        float z = __shfl_xor(v.z, o), w = __shfl_xor(v.w, o);
        if (ismax) { v.x = fmaxf(v.x, x); v.y = fmaxf(v.y, y); v.z = fmaxf(v.z, z); v.w = fmaxf(v.w, w); }
        else       { v.x += x; v.y += y; v.z += z; v.w += w; }
    }
    if ((threadIdx.x & 63) == 0) red[slot * 8 + (threadIdx.x >> 6)] = v;
    __syncthreads();
    float4 r = red[slot * 8];
    #pragma unroll
    for (int w2 = 1; w2 < 6; w2++) {
        float4 o = red[slot * 8 + w2];
        if (ismax) { r.x = fmaxf(r.x, o.x); r.y = fmaxf(r.y, o.y); r.z = fmaxf(r.z, o.z); r.w = fmaxf(r.w, o.w); }
        else       { r.x += o.x; r.y += o.y; r.z += o.z; r.w += o.w; }
    }
    return r;
}

// ---------- K1: LayerNorm + QKV + gates ----------
__global__ __launch_bounds__(256) void eq_k1(
    const float* __restrict__ feats, const float* __restrict__ gamma,
    const float* __restrict__ w_qkv, const float* __restrict__ w_gate,
    const float* __restrict__ b_gate,
    float* __restrict__ q, float* __restrict__ kT, float* __restrict__ v,
    float* __restrict__ og, float* __restrict__ rg) {
    int row = blockIdx.x;           // b*N + n
    int b = row / N_, n = row - b * N_;
    int t = threadIdx.x;
    __shared__ float xs[DIM_];
    __shared__ float red[4];
    float f = feats[(long)row * DIM_ + t];
    float mean = block_reduce256(f, red) * (1.0f / DIM_);
    float d = f - mean;
    float var = block_reduce256(d * d, red) * (1.0f / DIM_);
    float x = d * rsqrtf(var + 1e-5f) * gamma[t];
    xs[t] = x;
    __syncthreads();
    float a0 = 0, a1 = 0, a2 = 0;
    for (int c = 0; c < DIM_; c++) {
        float xc = xs[c];
        const float* wr = w_qkv + (long)c * 768;
        a0 += xc * wr[t];
        a1 += xc * wr[t + 256];
        a2 += xc * wr[t + 512];
    }
    int h = t >> 6, dd = t & 63;
    q[((b * H_ + h) * N_ + n) * DH_ + dd]  = a0 * 0.125f;      // dh^-0.5 pre-applied
    kT[((b * H_ + h) * DH_ + dd) * N_ + n] = a1;               // transposed for coalesced reads
    v[((b * H_ + h) * N_ + n) * DH_ + dd]  = a2;
    if (t < 8) {
        float acc = b_gate[t];
        for (int c = 0; c < DIM_; c++) acc += xs[c] * w_gate[c * 8 + t];
        float g = 1.0f / (1.0f + __expf(-acc));
        if (t < 4) og[(b * H_ + t) * N_ + n] = g;
        else       rg[(b * H_ + (t - 4)) * N_ + n] = g;
    }
}

// ---------- K2: position-bias MLP, wave-independent MFMA ----------
// Each wave owns 32 pairs (2 m-tiles x 16) and ALL 128 channels (8 n-tiles):
// LayerNorm = 4-step shfl butterfly within 16-lane groups -> NO barriers in
// the main loop. W1^T/W2^T in LDS (B-frag reads), wave-private h slices.
#define MFMA16(a, b, c) __builtin_amdgcn_mfma_f32_16x16x32_f16(a, b, c, 0, 0, 0)

#define LNAPPLY(gr_, ber_)                                                        \
{                                                                                  \
    _Pragma("unroll")                                                              \
    for (int mt = 0; mt < 2; mt++) {                                               \
        _Pragma("unroll")                                                          \
        for (int rg2 = 0; rg2 < 4; rg2++) {                                        \
            float s = 0.f, sq = 0.f;                                               \
            _Pragma("unroll")                                                      \
            for (int nt = 0; nt < 8; nt++) {                                       \
                float v0 = acc[mt][nt][rg2]; s += v0; sq += v0 * v0;               \
            }                                                                      \
            s += __shfl_xor(s, 1); sq += __shfl_xor(sq, 1);                        \
            s += __shfl_xor(s, 2); sq += __shfl_xor(sq, 2);                        \
            s += __shfl_xor(s, 4); sq += __shfl_xor(sq, 4);                        \
            s += __shfl_xor(s, 8); sq += __shfl_xor(sq, 8);                        \
            float mean = s * (1.f / 128.f);                                        \
            float inv = rsqrtf(sq * (1.f / 128.f) - mean * mean + 1e-5f);          \
            int row2 = mt * 16 + quad * 4 + rg2;                                   \
            _Pragma("unroll")                                                      \
            for (int nt = 0; nt < 8; nt++) {                                       \
                float y = (acc[mt][nt][rg2] - mean) * inv * gr_[nt] + ber_[nt];    \
                y = y / (1.f + __expf(-y));                                        \
                myslice[row2 * 136 + nt * 16 + l15] = (_Float16)y;                 \
            }                                                                      \
        }                                                                          \
    }                                                                              \
}

__global__ __launch_bounds__(512) __attribute__((amdgpu_waves_per_eu(2, 2)))
void eq_k2(
    const float* __restrict__ coors,
    const float* __restrict__ w0, const float* __restrict__ b0,
    const float* __restrict__ g0, const float* __restrict__ be0,
    const float* __restrict__ W1g, const float* __restrict__ b1,
    const float* __restrict__ g1, const float* __restrict__ be1,
    const float* __restrict__ W2g, const float* __restrict__ b2,
    const float* __restrict__ g2, const float* __restrict__ be2,
    const float* __restrict__ wqk, const float* __restrict__ bqk,
    _Float16* __restrict__ pout, float* __restrict__ qkpos) {

    extern __shared__ char smem[];
    _Float16* W1T    = (_Float16*)smem;                  // 128x136 = 34816 B
    _Float16* W2T    = (_Float16*)(smem + 34816);        // 34816 B
    _Float16* slices = (_Float16*)(smem + 69632);        // 8 x 32x136 = 69632 B
    _Float16* wqT    = (_Float16*)(smem + 139264);       // 16x136 = 4352 B
    float*    PQR    = (float*)(smem + 143616);          // 3x128 f32 = 1536 B

    const int t = threadIdx.x;
    const int lane = t & 63, wv = t >> 6;
    const int l15 = lane & 15, quad = lane >> 4;
    _Float16* myslice = slices + wv * (32 * 136);

    for (int idx = t; idx < 16384; idx += 512) {
        int k = idx >> 7, n = idx & 127;
        W1T[n * 136 + k] = (_Float16)W1g[idx];
        W2T[n * 136 + k] = (_Float16)W2g[idx];
    }
    for (int idx = t; idx < 2048; idx += 512) {
        int n = idx >> 7, k = idx & 127;
        wqT[n * 136 + k] = (n < 4) ? (_Float16)wqk[k * 4 + n] : (_Float16)0.f;
    }
    // layer0 closed-form LN stats (redundant per thread, init-only)
    float Sw = 0, Sb = 0, Sww = 0, Swb = 0, Sbb = 0;
    for (int c = 0; c < 128; c++) {
        float w = w0[c], bb2v = b0[c];
        Sw += w; Sb += bb2v; Sww += w * w; Swb += w * bb2v; Sbb += bb2v * bb2v;
    }
    const float mw = Sw * (1.f / 128.f), mbb = Sb * (1.f / 128.f);
    const float A2 = Sww * (1.f / 128.f) - mw * mw;
    const float AD = Swb * (1.f / 128.f) - mw * mbb;
    const float D2 = Sbb * (1.f / 128.f) - mbb * mbb;
    if (t < 128) {
        PQR[t]       = (w0[t] - mw) * g0[t];
        PQR[128 + t] = (b0[t] - mbb) * g0[t];
        PQR[256 + t] = be0[t];
    }
    // per-lane channel params for layers 1/2 (c = nt*16 + l15)
    float b1r[8], g1r[8], be1r[8], b2r[8], g2r[8], be2r[8];
    #pragma unroll
    for (int nt = 0; nt < 8; nt++) {
        int c = nt * 16 + l15;
        b1r[nt] = b1[c]; g1r[nt] = g1[c]; be1r[nt] = be1[c];
        b2r[nt] = b2[c]; g2r[nt] = g2[c]; be2r[nt] = be2[c];
    }
    const float bq = (l15 < 4) ? bqk[l15] : 0.f;
    __syncthreads();   // the only barrier

    for (int unit = blockIdx.x * 8 + wv; unit < NU_; unit += 256 * 8) {
        const int P0w = unit * 32;
        const int b = P0w / (N_ * N_);
        const int rem = P0w - b * (N_ * N_);
        const int ii = rem / N_;
        const int j0 = rem - ii * N_;
        const float cix = coors[(b * N_ + ii) * 3 + 0];
        const float ciy = coors[(b * N_ + ii) * 3 + 1];
        const float ciz = coors[(b * N_ + ii) * 3 + 2];
        float tt[2], uu[2];
        v8h A[2][4];
        #pragma unroll
        for (int mt = 0; mt < 2; mt++) {
            int j = j0 + mt * 16 + l15;
            float dx = cix - coors[(b * N_ + j) * 3 + 0];
            float dy = ciy - coors[(b * N_ + j) * 3 + 1];
            float dz = ciz - coors[(b * N_ + j) * 3 + 2];
            float d = sqrtf(dx * dx + dy * dy + dz * dz);
            float var = (d * d) * A2 + 2.f * d * AD + D2;
            float inv = rsqrtf(var + 1e-5f);
            tt[mt] = d * inv; uu[mt] = inv;
        }
        // layer0 directly into A-fragments: y = t*P + u*Q + R, silu
        #pragma unroll
        for (int kt = 0; kt < 4; kt++) {
            int base = kt * 32 + quad * 8;
            float4 Pa = *(const float4*)&PQR[base],       Pb = *(const float4*)&PQR[base + 4];
            float4 Qa = *(const float4*)&PQR[128 + base], Qb = *(const float4*)&PQR[128 + base + 4];
            float4 Ra = *(const float4*)&PQR[256 + base], Rb = *(const float4*)&PQR[256 + base + 4];
            float Pj[8] = {Pa.x, Pa.y, Pa.z, Pa.w, Pb.x, Pb.y, Pb.z, Pb.w};
            float Qj[8] = {Qa.x, Qa.y, Qa.z, Qa.w, Qb.x, Qb.y, Qb.z, Qb.w};
            float Rj[8] = {Ra.x, Ra.y, Ra.z, Ra.w, Rb.x, Rb.y, Rb.z, Rb.w};
            #pragma unroll
            for (int mt = 0; mt < 2; mt++) {
                v8h av;
                #pragma unroll
                for (int jj = 0; jj < 8; jj++) {
                    float y = tt[mt] * Pj[jj] + uu[mt] * Qj[jj] + Rj[jj];
                    av[jj] = (_Float16)(y / (1.f + __expf(-y)));
                }
                A[mt][kt] = av;
            }
        }
        // ---- layer1: h0 @ W1 + b1 ----
        v4f acc[2][8];
        #pragma unroll
        for (int nt = 0; nt < 8; nt++) {
            v4f ci = {b1r[nt], b1r[nt], b1r[nt], b1r[nt]};
            acc[0][nt] = ci; acc[1][nt] = ci;
        }
        #pragma unroll
        for (int kt = 0; kt < 4; kt++) {
            #pragma unroll
            for (int nt = 0; nt < 8; nt++) {
                v8h Bv = *(const v8h*)&W1T[(nt * 16 + l15) * 136 + kt * 32 + quad * 8];
                acc[0][nt] = MFMA16(A[0][kt], Bv, acc[0][nt]);
                acc[1][nt] = MFMA16(A[1][kt], Bv, acc[1][nt]);
            }
        }
        LNAPPLY(g1r, be1r)
        // ---- layer2: h1 @ W2 + b2 ----
        #pragma unroll
        for (int mt = 0; mt < 2; mt++)
            #pragma unroll
            for (int kt = 0; kt < 4; kt++)
                A[mt][kt] = *(const v8h*)&myslice[(mt * 16 + l15) * 136 + kt * 32 + quad * 8];
        #pragma unroll
        for (int nt = 0; nt < 8; nt++) {
            v4f ci = {b2r[nt], b2r[nt], b2r[nt], b2r[nt]};
            acc[0][nt] = ci; acc[1][nt] = ci;
        }
        #pragma unroll
        for (int kt = 0; kt < 4; kt++) {
            #pragma unroll
            for (int nt = 0; nt < 8; nt++) {
                v8h Bv = *(const v8h*)&W2T[(nt * 16 + l15) * 136 + kt * 32 + quad * 8];
                acc[0][nt] = MFMA16(A[0][kt], Bv, acc[0][nt]);
                acc[1][nt] = MFMA16(A[1][kt], Bv, acc[1][nt]);
            }
        }
        LNAPPLY(g2r, be2r)
        // ---- p store: 16B/lane coalesced from own slice ----
        #pragma unroll
        for (int it = 0; it < 8; it++) {
            int pos = it * 512 + lane * 8;
            int row = pos >> 7, cc = pos & 127;
            *(v8h*)&pout[(long)(P0w + row) * 128 + cc] = *(const v8h*)&myslice[row * 136 + cc];
        }
        // ---- qk_pos = p @ wqk + bqk ----
        #pragma unroll
        for (int mt = 0; mt < 2; mt++) {
            v4f c = {0.f, 0.f, 0.f, 0.f};
            #pragma unroll
            for (int kt = 0; kt < 4; kt++) {
                v8h av = *(const v8h*)&myslice[(mt * 16 + l15) * 136 + kt * 32 + quad * 8];
                v8h wq = *(const v8h*)&wqT[l15 * 136 + kt * 32 + quad * 8];
                c = MFMA16(av, wq, c);
            }
            if (l15 < 4) {
                #pragma unroll
                for (int rg2 = 0; rg2 < 4; rg2++) {
                    int row = mt * 16 + quad * 4 + rg2;
                    qkpos[(long)(P0w + row) * 4 + l15] = c[rg2] + bq;
                }
            }
        }
    }
}

// ---------- K3M: fused scores/edge-MLP/softmax/coor-branch/ap/attn@v/out-proj ----------
__global__ __launch_bounds__(384) void eq_k3m(
    const float* __restrict__ q, const float* __restrict__ kT,
    const float* __restrict__ edges, const float* __restrict__ qkpos,
    const _Float16* __restrict__ p, const float* __restrict__ v,
    const float* __restrict__ coors,
    const float* __restrict__ w_e1, const float* __restrict__ w_e2,
    const float* __restrict__ w_c, const float* __restrict__ w_cg,
    const float* __restrict__ b_cg, const float* __restrict__ w_th,
    const float* __restrict__ cscale, const float* __restrict__ ccomb,
    const float* __restrict__ og, const float* __restrict__ rg,
    const float* __restrict__ w_vpos, const float* __restrict__ b_vpos,
    const float* __restrict__ w_out, const float* __restrict__ b_out,
    float* __restrict__ out0, float* __restrict__ out1) {
    int row = blockIdx.x;           // b*N + i
    int b = row / N_, i = row - b * N_;
    int j = threadIdx.x;            // 0..383
    __shared__ float qs[H_ * DH_];
    __shared__ float we1[20 * 40];
    __shared__ float we2[40 * 4];
    __shared__ float wcs[16], wcgs[16], bcgs[4], wths[16];
    __shared__ float attnS[4 * N_];
    __shared__ float apS[4 * PD_];
    __shared__ float nodeS[256];
    __shared__ float4 red4[16];

    if (j < 256) qs[j] = q[((b * H_ + (j >> 6)) * N_ + i) * DH_ + (j & 63)];
    for (int idx = j; idx < 800; idx += 384) we1[idx] = w_e1[idx];
    if (j < 160) we2[j] = w_e2[j];
    if (j < 16) { wcs[j] = w_c[j]; wcgs[j] = w_cg[j]; wths[j] = w_th[j]; }
    if (j < 4) bcgs[j] = b_cg[j];
    __syncthreads();

    // ---- phase A: scores + edge MLP (per j) ----
    long pair = ((long)row) * N_ + j;
    float in20[20];
    #pragma unroll
    for (int h = 0; h < H_; h++) {
        float acc = 0;
        const float* kp = kT + ((long)(b * H_ + h) * DH_) * N_ + j;
        #pragma unroll 8
        for (int d = 0; d < DH_; d++) acc += qs[h * DH_ + d] * kp[(long)d * N_];
        in20[h] = acc;
    }
    {
        float4 qp = *(const float4*)(qkpos + pair * 4);
        in20[0] += qp.x; in20[1] += qp.y; in20[2] += qp.z; in20[3] += qp.w;
    }
    const float4* ep = (const float4*)(edges + pair * ED_);
    float4 e0 = ep[0], e1 = ep[1], e2 = ep[2], e3 = ep[3];
    in20[4] = e0.x;  in20[5] = e0.y;  in20[6] = e0.z;  in20[7] = e0.w;
    in20[8] = e1.x;  in20[9] = e1.y;  in20[10] = e1.z; in20[11] = e1.w;
    in20[12] = e2.x; in20[13] = e2.y; in20[14] = e2.z; in20[15] = e2.w;
    in20[16] = e3.x; in20[17] = e3.y; in20[18] = e3.z; in20[19] = e3.w;

    // edge MLP hidden layer: 5 chunks of 8 outputs -> a8[8] live (no spill),
    // float4 LDS weight reads (ds_read_b128).
    float c0 = 0, c1 = 0, c2 = 0, c3 = 0;
    #pragma unroll
    for (int oc = 0; oc < 5; oc++) {
        float a8[8] = {0.f, 0.f, 0.f, 0.f, 0.f, 0.f, 0.f, 0.f};
        #pragma unroll
        for (int c = 0; c < 20; c++) {
            float xc = in20[c];
            float4 wa = *(const float4*)&we1[c * 40 + oc * 8];
            float4 wb = *(const float4*)&we1[c * 40 + oc * 8 + 4];
            a8[0] += xc * wa.x; a8[1] += xc * wa.y; a8[2] += xc * wa.z; a8[3] += xc * wa.w;
            a8[4] += xc * wb.x; a8[5] += xc * wb.y; a8[6] += xc * wb.z; a8[7] += xc * wb.w;
        }
        #pragma unroll
        for (int o = 0; o < 8; o++) {
            float gg = gelu_(a8[o]);
            float4 w2v = *(const float4*)&we2[(oc * 8 + o) * 4];
            c0 += gg * w2v.x; c1 += gg * w2v.y; c2 += gg * w2v.z; c3 += gg * w2v.w;
        }
    }
    float cmi[4] = {c0, c1, c2, c3};
    float gc[4], cp[4], rs[4];
    #pragma unroll
    for (int h = 0; h < 4; h++) gc[h] = gelu_(cmi[h]);
    #pragma unroll
    for (int h = 0; h < 4; h++) {
        cp[h] = gc[0] * wcs[h] + gc[1] * wcs[4 + h] + gc[2] * wcs[8 + h] + gc[3] * wcs[12 + h];
        rs[h] = cmi[0] * wcgs[h] + cmi[1] * wcgs[4 + h] + cmi[2] * wcgs[8 + h] + cmi[3] * wcgs[12 + h] + bcgs[h];
    }

    // ---- phase B: softmax over j + talking heads -> attnS ----
    float4 m4 = block_reduce4(make_float4(cmi[0], cmi[1], cmi[2], cmi[3]), true, red4, 0);
    float e[4];
    e[0] = __expf(cmi[0] - m4.x); e[1] = __expf(cmi[1] - m4.y);
    e[2] = __expf(cmi[2] - m4.z); e[3] = __expf(cmi[3] - m4.w);
    float4 l4 = block_reduce4(make_float4(e[0], e[1], e[2], e[3]), false, red4, 1);
    float sm[4] = {e[0] / l4.x, e[1] / l4.y, e[2] / l4.z, e[3] / l4.w};
    #pragma unroll
    for (int h = 0; h < 4; h++)
        attnS[h * N_ + j] = wths[h * 4 + 0] * sm[0] + wths[h * 4 + 1] * sm[1]
                          + wths[h * 4 + 2] * sm[2] + wths[h * 4 + 3] * sm[3];

    // ---- phase C: coordinate branch -> out1 ----
    float dx = coors[(b * N_ + i) * 3 + 0] - coors[(b * N_ + j) * 3 + 0];
    float dy = coors[(b * N_ + i) * 3 + 1] - coors[(b * N_ + j) * 3 + 1];
    float dz = coors[(b * N_ + i) * 3 + 2] - coors[(b * N_ + j) * 3 + 2];
    float nrm = sqrtf(dx * dx + dy * dy + dz * dz);
    float sc = cscale[0] / fmaxf(nrm, 1e-8f);
    float rx = dx * sc, ry = dy * sc, rz = dz * sc;
    float4 cm4 = block_reduce4(make_float4(cp[0], cp[1], cp[2], cp[3]), true, red4, 0);
    float ec[4];
    ec[0] = __expf(cp[0] - cm4.x); ec[1] = __expf(cp[1] - cm4.y);
    ec[2] = __expf(cp[2] - cm4.z); ec[3] = __expf(cp[3] - cm4.w);
    float4 cl4 = block_reduce4(make_float4(ec[0], ec[1], ec[2], ec[3]), false, red4, 1);
    float w[4] = {ec[0] / cl4.x * rs[0], ec[1] / cl4.y * rs[1],
                  ec[2] / cl4.z * rs[2], ec[3] / cl4.w * rs[3]};
    float4 sx4 = block_reduce4(make_float4(w[0] * rx, w[1] * rx, w[2] * rx, w[3] * rx), false, red4, 0);
    float4 sy4 = block_reduce4(make_float4(w[0] * ry, w[1] * ry, w[2] * ry, w[3] * ry), false, red4, 1);
    float4 sz4 = block_reduce4(make_float4(w[0] * rz, w[1] * rz, w[2] * rz, w[3] * rz), false, red4, 0);
    if (j == 0) {
        float f0 = ccomb[0] * rg[(b * H_ + 0) * N_ + i];
        float f1 = ccomb[1] * rg[(b * H_ + 1) * N_ + i];
        float f2 = ccomb[2] * rg[(b * H_ + 2) * N_ + i];
        float f3 = ccomb[3] * rg[(b * H_ + 3) * N_ + i];
        out1[(b * N_ + i) * 3 + 0] = f0 * sx4.x + f1 * sx4.y + f2 * sx4.z + f3 * sx4.w;
        out1[(b * N_ + i) * 3 + 1] = f0 * sy4.x + f1 * sy4.y + f2 * sy4.z + f3 * sy4.w;
        out1[(b * N_ + i) * 3 + 2] = f0 * sz4.x + f1 * sz4.y + f2 * sz4.z + f3 * sz4.w;
    }
    __syncthreads();

    // ---- phase D: threads 0..127 -> ap; threads 128..383 -> attn@v ----
    if (j < 128) {
        float a0 = 0, a1 = 0, a2 = 0, a3 = 0;
        const _Float16* pp = p + ((long)row * N_) * PD_ + j;
        #pragma unroll 4
        for (int jj = 0; jj < N_; jj++) {
            float pv = (float)pp[(long)jj * PD_];
            a0 += attnS[jj] * pv;
            a1 += attnS[N_ + jj] * pv;
            a2 += attnS[2 * N_ + jj] * pv;
            a3 += attnS[3 * N_ + jj] * pv;
        }
        apS[j] = a0; apS[PD_ + j] = a1; apS[2 * PD_ + j] = a2; apS[3 * PD_ + j] = a3;
    } else {
        int tt = j - 128, h = tt >> 6, d = tt & 63;
        float acc = 0;
        const float* vp = v + ((long)(b * H_ + h) * N_) * DH_ + d;
        #pragma unroll 8
        for (int jj = 0; jj < N_; jj++) acc += attnS[h * N_ + jj] * vp[(long)jj * DH_];
        nodeS[tt] = acc;
    }
    __syncthreads();

    // ---- phase E: node = (attnv + ap@w_vpos + Sh*b_vpos) * out_gate ----
    float nv = 0;
    if (j < 256) {
        int h = j >> 6, d = j & 63;
        float accp = 0;
        const float* wv = w_vpos + h * DH_ + d;
        #pragma unroll 8
        for (int c = 0; c < PD_; c++) accp += apS[h * PD_ + c] * wv[(long)c * (H_ * DH_)];
        float Sh = wths[h * 4 + 0] + wths[h * 4 + 1] + wths[h * 4 + 2] + wths[h * 4 + 3];
        nv = (nodeS[j] + accp + Sh * b_vpos[h * DH_ + d]) * og[(b * H_ + h) * N_ + i];
    }
    __syncthreads();
    if (j < 256) nodeS[j] = nv;
    __syncthreads();

    // ---- phase F: out0 = node @ w_out + b_out ----
    if (j < 256) {
        float acc = b_out[j];
        #pragma unroll 8
        for (int c = 0; c < 256; c++) acc += nodeS[c] * w_out[(long)c * 256 + j];
        out0[(long)row * 256 + j] = acc;
    }
}

extern "C" void kernel_launch(void* const* d_in, const int* in_sizes, int n_in,
                              void* d_out, int out_size, void* d_ws, size_t ws_size,
                              hipStream_t stream) {
    (void)in_sizes; (void)n_in; (void)out_size; (void)ws_size;
    const float* feats   = (const float*)d_in[0];
    const float* coors   = (const float*)d_in[1];
    const float* edges   = (const float*)d_in[2];
    const float* gamma   = (const float*)d_in[3];
    const float* w_qkv   = (const float*)d_in[4];
    const float* w_gate  = (const float*)d_in[5];
    const float* b_gate  = (const float*)d_in[6];
    const float* w_th    = (const float*)d_in[7];
    const float* w_e1    = (const float*)d_in[8];
    const float* w_e2    = (const float*)d_in[9];
    const float* w_c     = (const float*)d_in[10];
    const float* w_cg    = (const float*)d_in[11];
    const float* b_cg    = (const float*)d_in[12];
    const float* cscale  = (const float*)d_in[13];
    const float* ccomb   = (const float*)d_in[14];
    const float* pb_w0   = (const float*)d_in[15];
    const float* pb_b0   = (const float*)d_in[16];
    const float* pb_g0   = (const float*)d_in[17];
    const float* pb_be0  = (const float*)d_in[18];
    const float* pb_w1   = (const float*)d_in[19];
    const float* pb_b1   = (const float*)d_in[20];
    const float* pb_g1   = (const float*)d_in[21];
    const float* pb_be1  = (const float*)d_in[22];
    const float* pb_w2   = (const float*)d_in[23];
    const float* pb_b2   = (const float*)d_in[24];
    const float* pb_g2   = (const float*)d_in[25];
    const float* pb_be2  = (const float*)d_in[26];
    const float* w_qkpos = (const float*)d_in[27];
    const float* b_qkpos = (const float*)d_in[28];
    const float* w_vpos  = (const float*)d_in[29];
    const float* b_vpos  = (const float*)d_in[30];
    const float* w_out   = (const float*)d_in[31];
    const float* b_out   = (const float*)d_in[32];

    // workspace carve (floats)
    float* wsf    = (float*)d_ws;
    float* q      = wsf;                    // 196608
    float* kT     = q      + 196608;        // 196608
    float* v      = kT     + 196608;        // 196608
    float* og     = v      + 196608;        // 3072
    float* rg     = og     + 3072;          // 3072
    float* qkpos  = rg     + 3072;          // 1179648 (b,i,j,h)
    _Float16* pbuf = (_Float16*)(qkpos + 1179648);  // 37748736 f16

    float* out0 = (float*)d_out;
    float* out1 = out0 + (long)B_ * N_ * DIM_;

    const int K2_LDS = 145152;
    hipFuncSetAttribute((const void*)eq_k2, hipFuncAttributeMaxDynamicSharedMemorySize, K2_LDS);

    eq_k1<<<B_ * N_, 256, 0, stream>>>(feats, gamma, w_qkv, w_gate, b_gate, q, kT, v, og, rg);
    eq_k2<<<256, 512, K2_LDS, stream>>>(coors, pb_w0, pb_b0, pb_g0, pb_be0,
                                        pb_w1, pb_b1, pb_g1, pb_be1,
                                        pb_w2, pb_b2, pb_g2, pb_be2,
                                        w_qkpos, b_qkpos, pbuf, qkpos);
    eq_k3m<<<B_ * N_, 384, 0, stream>>>(q, kT, edges, qkpos, pbuf, v, coors,
                                        w_e1, w_e2, w_c, w_cg, b_cg, w_th,
                                        cscale, ccomb, og, rg,
                                        w_vpos, b_vpos, w_out, b_out, out0, out1);
}

// Round 6
// 448.100 us; speedup vs baseline: 2.5689x; 1.2491x over previous
//
#include <hip/hip_runtime.h>
#include <hip/hip_bf16.h>

#define B_   2
#define N_   384
#define DIM_ 256
#define H_   4
#define DH_  64
#define PD_  128
#define ED_  16
#define NU2_ ((B_ * N_ * N_) / 16)   // 18432 wave-units (16 pairs each)

typedef _Float16 v8h __attribute__((ext_vector_type(8)));
typedef float    v4f __attribute__((ext_vector_type(4)));

__device__ __forceinline__ float gelu_(float x) {
    return 0.5f * x * (1.0f + erff(x * 0.70710678118654752f));
}

// full-block reduction over 256 threads (4 waves)
__device__ __forceinline__ float block_reduce256(float v, float* red) {
    #pragma unroll
    for (int o = 32; o > 0; o >>= 1) v += __shfl_xor(v, o, 64);
    __syncthreads();
    if ((threadIdx.x & 63) == 0) red[threadIdx.x >> 6] = v;
    __syncthreads();
    return red[0] + red[1] + red[2] + red[3];
}

// batched float4 block reduction over 384 threads (6 waves).
__device__ __forceinline__ float4 block_reduce4(float4 v, bool ismax, float4* red, int slot) {
    #pragma unroll
    for (int o = 32; o > 0; o >>= 1) {
        float x = __shfl_xor(v.x, o), y = __shfl_xor(v.y, o);
        float z = __shfl_xor(v.z, o), w = __shfl_xor(v.w, o);
        if (ismax) { v.x = fmaxf(v.x, x); v.y = fmaxf(v.y, y); v.z = fmaxf(v.z, z); v.w = fmaxf(v.w, w); }
        else       { v.x += x; v.y += y; v.z += z; v.w += w; }
    }
    if ((threadIdx.x & 63) == 0) red[slot * 8 + (threadIdx.x >> 6)] = v;
    __syncthreads();
    float4 r = red[slot * 8];
    #pragma unroll
    for (int w2 = 1; w2 < 6; w2++) {
        float4 o = red[slot * 8 + w2];
        if (ismax) { r.x = fmaxf(r.x, o.x); r.y = fmaxf(r.y, o.y); r.z = fmaxf(r.z, o.z); r.w = fmaxf(r.w, o.w); }
        else       { r.x += o.x; r.y += o.y; r.z += o.z; r.w += o.w; }
    }
    return r;
}

// ---------- K1: LayerNorm + QKV + gates ----------
__global__ __launch_bounds__(256) void eq_k1(
    const float* __restrict__ feats, const float* __restrict__ gamma,
    const float* __restrict__ w_qkv, const float* __restrict__ w_gate,
    const float* __restrict__ b_gate,
    float* __restrict__ q, float* __restrict__ kT, float* __restrict__ v,
    float* __restrict__ og, float* __restrict__ rg) {
    int row = blockIdx.x;           // b*N + n
    int b = row / N_, n = row - b * N_;
    int t = threadIdx.x;
    __shared__ float xs[DIM_];
    __shared__ float red[4];
    float f = feats[(long)row * DIM_ + t];
    float mean = block_reduce256(f, red) * (1.0f / DIM_);
    float d = f - mean;
    float var = block_reduce256(d * d, red) * (1.0f / DIM_);
    float x = d * rsqrtf(var + 1e-5f) * gamma[t];
    xs[t] = x;
    __syncthreads();
    float a0 = 0, a1 = 0, a2 = 0;
    for (int c = 0; c < DIM_; c++) {
        float xc = xs[c];
        const float* wr = w_qkv + (long)c * 768;
        a0 += xc * wr[t];
        a1 += xc * wr[t + 256];
        a2 += xc * wr[t + 512];
    }
    int h = t >> 6, dd = t & 63;
    q[((b * H_ + h) * N_ + n) * DH_ + dd]  = a0 * 0.125f;      // dh^-0.5 pre-applied
    kT[((b * H_ + h) * DH_ + dd) * N_ + n] = a1;               // transposed for coalesced reads
    v[((b * H_ + h) * N_ + n) * DH_ + dd]  = a2;
    if (t < 8) {
        float acc = b_gate[t];
        for (int c = 0; c < DIM_; c++) acc += xs[c] * w_gate[c * 8 + t];
        float g = 1.0f / (1.0f + __expf(-acc));
        if (t < 4) og[(b * H_ + t) * N_ + n] = g;
        else       rg[(b * H_ + (t - 4)) * N_ + n] = g;
    }
}

// ---------- K2: position-bias MLP, wave-independent MFMA, low-VGPR ----------
// Each wave owns 16 pairs (1 m-tile) and all 128 channels (8 n-tiles).
// Registers: A 16 + acc 32 + biases 16 + temps ~40 -> fits 128, no spill.
// 1024-thread blocks: 16 waves share one LDS copy of W1^T/W2^T -> 4 waves/SIMD.
// LayerNorm = shfl butterfly over l15 within quad rows; no barriers in main loop.
#define MFMA16(a, b, c) __builtin_amdgcn_mfma_f32_16x16x32_f16(a, b, c, 0, 0, 0)

#define LNAPPLY(GOFF_, BOFF_)                                                     \
{                                                                                  \
    float gv[8], bev[8];                                                           \
    _Pragma("unroll")                                                              \
    for (int nt = 0; nt < 8; nt++) {                                               \
        gv[nt]  = GB[(GOFF_) + nt * 16 + l15];                                     \
        bev[nt] = GB[(BOFF_) + nt * 16 + l15];                                     \
    }                                                                              \
    _Pragma("unroll")                                                              \
    for (int rg2 = 0; rg2 < 4; rg2++) {                                            \
        float s = 0.f, sq = 0.f;                                                   \
        _Pragma("unroll")                                                          \
        for (int nt = 0; nt < 8; nt++) {                                           \
            float v0 = acc[nt][rg2]; s += v0; sq += v0 * v0;                       \
        }                                                                          \
        s += __shfl_xor(s, 1); sq += __shfl_xor(sq, 1);                            \
        s += __shfl_xor(s, 2); sq += __shfl_xor(sq, 2);                            \
        s += __shfl_xor(s, 4); sq += __shfl_xor(sq, 4);                            \
        s += __shfl_xor(s, 8); sq += __shfl_xor(sq, 8);                            \
        float mean = s * (1.f / 128.f);                                            \
        float inv = rsqrtf(sq * (1.f / 128.f) - mean * mean + 1e-5f);              \
        int row2 = quad * 4 + rg2;                                                 \
        _Pragma("unroll")                                                          \
        for (int nt = 0; nt < 8; nt++) {                                           \
            float y = (acc[nt][rg2] - mean) * inv * gv[nt] + bev[nt];              \
            y = y / (1.f + __expf(-y));                                            \
            myslice[row2 * 136 + nt * 16 + l15] = (_Float16)y;                     \
        }                                                                          \
    }                                                                              \
}

__global__ __launch_bounds__(1024) void eq_k2(
    const float* __restrict__ coors,
    const float* __restrict__ w0, const float* __restrict__ b0,
    const float* __restrict__ g0, const float* __restrict__ be0,
    const float* __restrict__ W1g, const float* __restrict__ b1,
    const float* __restrict__ g1, const float* __restrict__ be1,
    const float* __restrict__ W2g, const float* __restrict__ b2,
    const float* __restrict__ g2, const float* __restrict__ be2,
    const float* __restrict__ wqk, const float* __restrict__ bqk,
    _Float16* __restrict__ pout, float* __restrict__ qkpos) {

    extern __shared__ char smem[];
    _Float16* W1T    = (_Float16*)smem;                  // 128x136 = 34816 B
    _Float16* W2T    = (_Float16*)(smem + 34816);        // 34816 B
    _Float16* slices = (_Float16*)(smem + 69632);        // 16 x 16x136 = 69632 B
    _Float16* wqT    = (_Float16*)(smem + 139264);       // 16x136 = 4352 B
    float*    PQR    = (float*)(smem + 143616);          // 3x128 f32 = 1536 B
    float*    GB     = (float*)(smem + 145152);          // g1,be1,g2,be2 = 2048 B

    const int t = threadIdx.x;
    const int lane = t & 63, wv = t >> 6;           // wv 0..15
    const int l15 = lane & 15, quad = lane >> 4;
    _Float16* myslice = slices + wv * (16 * 136);

    for (int idx = t; idx < 16384; idx += 1024) {
        int k = idx >> 7, n = idx & 127;
        W1T[n * 136 + k] = (_Float16)W1g[idx];
        W2T[n * 136 + k] = (_Float16)W2g[idx];
    }
    for (int idx = t; idx < 2048; idx += 1024) {
        int n = idx >> 7, k = idx & 127;
        wqT[n * 136 + k] = (n < 4) ? (_Float16)wqk[k * 4 + n] : (_Float16)0.f;
    }
    // layer0 closed-form LN stats (redundant per thread, init-only)
    float Sw = 0, Sb = 0, Sww = 0, Swb = 0, Sbb = 0;
    for (int c = 0; c < 128; c++) {
        float w = w0[c], bb2v = b0[c];
        Sw += w; Sb += bb2v; Sww += w * w; Swb += w * bb2v; Sbb += bb2v * bb2v;
    }
    const float mw = Sw * (1.f / 128.f), mbb = Sb * (1.f / 128.f);
    const float A2 = Sww * (1.f / 128.f) - mw * mw;
    const float AD = Swb * (1.f / 128.f) - mw * mbb;
    const float D2 = Sbb * (1.f / 128.f) - mbb * mbb;
    if (t < 128) {
        PQR[t]       = (w0[t] - mw) * g0[t];
        PQR[128 + t] = (b0[t] - mbb) * g0[t];
        PQR[256 + t] = be0[t];
        GB[t]        = g1[t];
        GB[128 + t]  = be1[t];
        GB[256 + t]  = g2[t];
        GB[384 + t]  = be2[t];
    }
    // per-lane biases for layers 1/2 (c = nt*16 + l15)
    float b1r[8], b2r[8];
    #pragma unroll
    for (int nt = 0; nt < 8; nt++) {
        int c = nt * 16 + l15;
        b1r[nt] = b1[c]; b2r[nt] = b2[c];
    }
    const float bq = (l15 < 4) ? bqk[l15] : 0.f;
    __syncthreads();   // the only barrier

    for (int unit = blockIdx.x * 16 + wv; unit < NU2_; unit += 256 * 16) {
        const int P0w = unit * 16;
        const int b = P0w / (N_ * N_);
        const int rem = P0w - b * (N_ * N_);
        const int ii = rem / N_;
        const int j0 = rem - ii * N_;
        const float cix = coors[(b * N_ + ii) * 3 + 0];
        const float ciy = coors[(b * N_ + ii) * 3 + 1];
        const float ciz = coors[(b * N_ + ii) * 3 + 2];
        float tt, uu;
        {
            int j = j0 + l15;
            float dx = cix - coors[(b * N_ + j) * 3 + 0];
            float dy = ciy - coors[(b * N_ + j) * 3 + 1];
            float dz = ciz - coors[(b * N_ + j) * 3 + 2];
            float d = sqrtf(dx * dx + dy * dy + dz * dz);
            float var = (d * d) * A2 + 2.f * d * AD + D2;
            float inv = rsqrtf(var + 1e-5f);
            tt = d * inv; uu = inv;
        }
        // layer0 directly into A-fragments: y = t*P + u*Q + R, silu
        v8h A[4];
        #pragma unroll
        for (int kt = 0; kt < 4; kt++) {
            int base = kt * 32 + quad * 8;
            float4 Pa = *(const float4*)&PQR[base],       Pb = *(const float4*)&PQR[base + 4];
            float4 Qa = *(const float4*)&PQR[128 + base], Qb = *(const float4*)&PQR[128 + base + 4];
            float4 Ra = *(const float4*)&PQR[256 + base], Rb = *(const float4*)&PQR[256 + base + 4];
            float Pj[8] = {Pa.x, Pa.y, Pa.z, Pa.w, Pb.x, Pb.y, Pb.z, Pb.w};
            float Qj[8] = {Qa.x, Qa.y, Qa.z, Qa.w, Qb.x, Qb.y, Qb.z, Qb.w};
            float Rj[8] = {Ra.x, Ra.y, Ra.z, Ra.w, Rb.x, Rb.y, Rb.z, Rb.w};
            v8h av;
            #pragma unroll
            for (int jj = 0; jj < 8; jj++) {
                float y = tt * Pj[jj] + uu * Qj[jj] + Rj[jj];
                av[jj] = (_Float16)(y / (1.f + __expf(-y)));
            }
            A[kt] = av;
        }
        // ---- layer1: h0 @ W1 + b1 ----
        v4f acc[8];
        #pragma unroll
        for (int nt = 0; nt < 8; nt++) {
            v4f ci = {b1r[nt], b1r[nt], b1r[nt], b1r[nt]};
            acc[nt] = ci;
        }
        #pragma unroll
        for (int kt = 0; kt < 4; kt++) {
            #pragma unroll
            for (int nt = 0; nt < 8; nt++) {
                v8h Bv = *(const v8h*)&W1T[(nt * 16 + l15) * 136 + kt * 32 + quad * 8];
                acc[nt] = MFMA16(A[kt], Bv, acc[nt]);
            }
        }
        LNAPPLY(0, 128)
        // ---- layer2: h1 @ W2 + b2 ----
        #pragma unroll
        for (int kt = 0; kt < 4; kt++)
            A[kt] = *(const v8h*)&myslice[l15 * 136 + kt * 32 + quad * 8];
        #pragma unroll
        for (int nt = 0; nt < 8; nt++) {
            v4f ci = {b2r[nt], b2r[nt], b2r[nt], b2r[nt]};
            acc[nt] = ci;
        }
        #pragma unroll
        for (int kt = 0; kt < 4; kt++) {
            #pragma unroll
            for (int nt = 0; nt < 8; nt++) {
                v8h Bv = *(const v8h*)&W2T[(nt * 16 + l15) * 136 + kt * 32 + quad * 8];
                acc[nt] = MFMA16(A[kt], Bv, acc[nt]);
            }
        }
        LNAPPLY(256, 384)
        // ---- p store: 16B/lane coalesced from own slice ----
        #pragma unroll
        for (int it = 0; it < 4; it++) {
            int pos = it * 512 + lane * 8;
            int row = pos >> 7, cc = pos & 127;
            *(v8h*)&pout[(long)(P0w + row) * 128 + cc] = *(const v8h*)&myslice[row * 136 + cc];
        }
        // ---- qk_pos = p @ wqk + bqk ----
        {
            v4f c = {0.f, 0.f, 0.f, 0.f};
            #pragma unroll
            for (int kt = 0; kt < 4; kt++) {
                v8h av = *(const v8h*)&myslice[l15 * 136 + kt * 32 + quad * 8];
                v8h wq = *(const v8h*)&wqT[l15 * 136 + kt * 32 + quad * 8];
                c = MFMA16(av, wq, c);
            }
            if (l15 < 4) {
                #pragma unroll
                for (int rg2 = 0; rg2 < 4; rg2++) {
                    int row = quad * 4 + rg2;
                    qkpos[(long)(P0w + row) * 4 + l15] = c[rg2] + bq;
                }
            }
        }
    }
}

// ---------- K3M: fused scores/edge-MLP/softmax/coor-branch/ap/attn@v/out-proj ----------
__global__ __launch_bounds__(384) void eq_k3m(
    const float* __restrict__ q, const float* __restrict__ kT,
    const float* __restrict__ edges, const float* __restrict__ qkpos,
    const _Float16* __restrict__ p, const float* __restrict__ v,
    const float* __restrict__ coors,
    const float* __restrict__ w_e1, const float* __restrict__ w_e2,
    const float* __restrict__ w_c, const float* __restrict__ w_cg,
    const float* __restrict__ b_cg, const float* __restrict__ w_th,
    const float* __restrict__ cscale, const float* __restrict__ ccomb,
    const float* __restrict__ og, const float* __restrict__ rg,
    const float* __restrict__ w_vpos, const float* __restrict__ b_vpos,
    const float* __restrict__ w_out, const float* __restrict__ b_out,
    float* __restrict__ out0, float* __restrict__ out1) {
    int row = blockIdx.x;           // b*N + i
    int b = row / N_, i = row - b * N_;
    int j = threadIdx.x;            // 0..383
    __shared__ float qs[H_ * DH_];
    __shared__ float we1[20 * 40];
    __shared__ float we2[40 * 4];
    __shared__ float wcs[16], wcgs[16], bcgs[4], wths[16];
    __shared__ float attnS[4 * N_];
    __shared__ float apS[4 * PD_];
    __shared__ float nodeS[256];
    __shared__ float4 red4[16];

    if (j < 256) qs[j] = q[((b * H_ + (j >> 6)) * N_ + i) * DH_ + (j & 63)];
    for (int idx = j; idx < 800; idx += 384) we1[idx] = w_e1[idx];
    if (j < 160) we2[j] = w_e2[j];
    if (j < 16) { wcs[j] = w_c[j]; wcgs[j] = w_cg[j]; wths[j] = w_th[j]; }
    if (j < 4) bcgs[j] = b_cg[j];
    __syncthreads();

    // ---- phase A: scores + edge MLP (per j) ----
    long pair = ((long)row) * N_ + j;
    float in20[20];
    #pragma unroll
    for (int h = 0; h < H_; h++) {
        float acc = 0;
        const float* kp = kT + ((long)(b * H_ + h) * DH_) * N_ + j;
        #pragma unroll 8
        for (int d = 0; d < DH_; d++) acc += qs[h * DH_ + d] * kp[(long)d * N_];
        in20[h] = acc;
    }
    {
        float4 qp = *(const float4*)(qkpos + pair * 4);
        in20[0] += qp.x; in20[1] += qp.y; in20[2] += qp.z; in20[3] += qp.w;
    }
    const float4* ep = (const float4*)(edges + pair * ED_);
    float4 e0 = ep[0], e1 = ep[1], e2 = ep[2], e3 = ep[3];
    in20[4] = e0.x;  in20[5] = e0.y;  in20[6] = e0.z;  in20[7] = e0.w;
    in20[8] = e1.x;  in20[9] = e1.y;  in20[10] = e1.z; in20[11] = e1.w;
    in20[12] = e2.x; in20[13] = e2.y; in20[14] = e2.z; in20[15] = e2.w;
    in20[16] = e3.x; in20[17] = e3.y; in20[18] = e3.z; in20[19] = e3.w;

    // edge MLP hidden layer: 5 chunks of 8 outputs, oc loop NOT unrolled so
    // only one chunk's a8[8] is live at a time (no VGPR spill).
    float c0 = 0, c1 = 0, c2 = 0, c3 = 0;
    #pragma unroll 1
    for (int oc = 0; oc < 5; oc++) {
        float a8[8] = {0.f, 0.f, 0.f, 0.f, 0.f, 0.f, 0.f, 0.f};
        #pragma unroll
        for (int c = 0; c < 20; c++) {
            float xc = in20[c];
            float4 wa = *(const float4*)&we1[c * 40 + oc * 8];
            float4 wb = *(const float4*)&we1[c * 40 + oc * 8 + 4];
            a8[0] += xc * wa.x; a8[1] += xc * wa.y; a8[2] += xc * wa.z; a8[3] += xc * wa.w;
            a8[4] += xc * wb.x; a8[5] += xc * wb.y; a8[6] += xc * wb.z; a8[7] += xc * wb.w;
        }
        #pragma unroll
        for (int o = 0; o < 8; o++) {
            float gg = gelu_(a8[o]);
            float4 w2v = *(const float4*)&we2[(oc * 8 + o) * 4];
            c0 += gg * w2v.x; c1 += gg * w2v.y; c2 += gg * w2v.z; c3 += gg * w2v.w;
        }
    }
    float cmi[4] = {c0, c1, c2, c3};
    float gc[4], cp[4], rs[4];
    #pragma unroll
    for (int h = 0; h < 4; h++) gc[h] = gelu_(cmi[h]);
    #pragma unroll
    for (int h = 0; h < 4; h++) {
        cp[h] = gc[0] * wcs[h] + gc[1] * wcs[4 + h] + gc[2] * wcs[8 + h] + gc[3] * wcs[12 + h];
        rs[h] = cmi[0] * wcgs[h] + cmi[1] * wcgs[4 + h] + cmi[2] * wcgs[8 + h] + cmi[3] * wcgs[12 + h] + bcgs[h];
    }

    // ---- phase B: softmax over j + talking heads -> attnS ----
    float4 m4 = block_reduce4(make_float4(cmi[0], cmi[1], cmi[2], cmi[3]), true, red4, 0);
    float e[4];
    e[0] = __expf(cmi[0] - m4.x); e[1] = __expf(cmi[1] - m4.y);
    e[2] = __expf(cmi[2] - m4.z); e[3] = __expf(cmi[3] - m4.w);
    float4 l4 = block_reduce4(make_float4(e[0], e[1], e[2], e[3]), false, red4, 1);
    float sm[4] = {e[0] / l4.x, e[1] / l4.y, e[2] / l4.z, e[3] / l4.w};
    #pragma unroll
    for (int h = 0; h < 4; h++)
        attnS[h * N_ + j] = wths[h * 4 + 0] * sm[0] + wths[h * 4 + 1] * sm[1]
                          + wths[h * 4 + 2] * sm[2] + wths[h * 4 + 3] * sm[3];

    // ---- phase C: coordinate branch -> out1 ----
    float dx = coors[(b * N_ + i) * 3 + 0] - coors[(b * N_ + j) * 3 + 0];
    float dy = coors[(b * N_ + i) * 3 + 1] - coors[(b * N_ + j) * 3 + 1];
    float dz = coors[(b * N_ + i) * 3 + 2] - coors[(b * N_ + j) * 3 + 2];
    float nrm = sqrtf(dx * dx + dy * dy + dz * dz);
    float sc = cscale[0] / fmaxf(nrm, 1e-8f);
    float rx = dx * sc, ry = dy * sc, rz = dz * sc;
    float4 cm4 = block_reduce4(make_float4(cp[0], cp[1], cp[2], cp[3]), true, red4, 0);
    float ec[4];
    ec[0] = __expf(cp[0] - cm4.x); ec[1] = __expf(cp[1] - cm4.y);
    ec[2] = __expf(cp[2] - cm4.z); ec[3] = __expf(cp[3] - cm4.w);
    float4 cl4 = block_reduce4(make_float4(ec[0], ec[1], ec[2], ec[3]), false, red4, 1);
    float w[4] = {ec[0] / cl4.x * rs[0], ec[1] / cl4.y * rs[1],
                  ec[2] / cl4.z * rs[2], ec[3] / cl4.w * rs[3]};
    float4 sx4 = block_reduce4(make_float4(w[0] * rx, w[1] * rx, w[2] * rx, w[3] * rx), false, red4, 0);
    float4 sy4 = block_reduce4(make_float4(w[0] * ry, w[1] * ry, w[2] * ry, w[3] * ry), false, red4, 1);
    float4 sz4 = block_reduce4(make_float4(w[0] * rz, w[1] * rz, w[2] * rz, w[3] * rz), false, red4, 0);
    if (j == 0) {
        float f0 = ccomb[0] * rg[(b * H_ + 0) * N_ + i];
        float f1 = ccomb[1] * rg[(b * H_ + 1) * N_ + i];
        float f2 = ccomb[2] * rg[(b * H_ + 2) * N_ + i];
        float f3 = ccomb[3] * rg[(b * H_ + 3) * N_ + i];
        out1[(b * N_ + i) * 3 + 0] = f0 * sx4.x + f1 * sx4.y + f2 * sx4.z + f3 * sx4.w;
        out1[(b * N_ + i) * 3 + 1] = f0 * sy4.x + f1 * sy4.y + f2 * sy4.z + f3 * sy4.w;
        out1[(b * N_ + i) * 3 + 2] = f0 * sz4.x + f1 * sz4.y + f2 * sz4.z + f3 * sz4.w;
    }
    __syncthreads();

    // ---- phase D: threads 0..127 -> ap; threads 128..383 -> attn@v ----
    if (j < 128) {
        float a0 = 0, a1 = 0, a2 = 0, a3 = 0;
        const _Float16* pp = p + ((long)row * N_) * PD_ + j;
        #pragma unroll 4
        for (int jj = 0; jj < N_; jj++) {
            float pv = (float)pp[(long)jj * PD_];
            a0 += attnS[jj] * pv;
            a1 += attnS[N_ + jj] * pv;
            a2 += attnS[2 * N_ + jj] * pv;
            a3 += attnS[3 * N_ + jj] * pv;
        }
        apS[j] = a0; apS[PD_ + j] = a1; apS[2 * PD_ + j] = a2; apS[3 * PD_ + j] = a3;
    } else {
        int tt = j - 128, h = tt >> 6, d = tt & 63;
        float acc = 0;
        const float* vp = v + ((long)(b * H_ + h) * N_) * DH_ + d;
        #pragma unroll 8
        for (int jj = 0; jj < N_; jj++) acc += attnS[h * N_ + jj] * vp[(long)jj * DH_];
        nodeS[tt] = acc;
    }
    __syncthreads();

    // ---- phase E: node = (attnv + ap@w_vpos + Sh*b_vpos) * out_gate ----
    float nv = 0;
    if (j < 256) {
        int h = j >> 6, d = j & 63;
        float accp = 0;
        const float* wv = w_vpos + h * DH_ + d;
        #pragma unroll 8
        for (int c = 0; c < PD_; c++) accp += apS[h * PD_ + c] * wv[(long)c * (H_ * DH_)];
        float Sh = wths[h * 4 + 0] + wths[h * 4 + 1] + wths[h * 4 + 2] + wths[h * 4 + 3];
        nv = (nodeS[j] + accp + Sh * b_vpos[h * DH_ + d]) * og[(b * H_ + h) * N_ + i];
    }
    __syncthreads();
    if (j < 256) nodeS[j] = nv;
    __syncthreads();

    // ---- phase F: out0 = node @ w_out + b_out ----
    if (j < 256) {
        float acc = b_out[j];
        #pragma unroll 8
        for (int c = 0; c < 256; c++) acc += nodeS[c] * w_out[(long)c * 256 + j];
        out0[(long)row * 256 + j] = acc;
    }
}

extern "C" void kernel_launch(void* const* d_in, const int* in_sizes, int n_in,
                              void* d_out, int out_size, void* d_ws, size_t ws_size,
                              hipStream_t stream) {
    (void)in_sizes; (void)n_in; (void)out_size; (void)ws_size;
    const float* feats   = (const float*)d_in[0];
    const float* coors   = (const float*)d_in[1];
    const float* edges   = (const float*)d_in[2];
    const float* gamma   = (const float*)d_in[3];
    const float* w_qkv   = (const float*)d_in[4];
    const float* w_gate  = (const float*)d_in[5];
    const float* b_gate  = (const float*)d_in[6];
    const float* w_th    = (const float*)d_in[7];
    const float* w_e1    = (const float*)d_in[8];
    const float* w_e2    = (const float*)d_in[9];
    const float* w_c     = (const float*)d_in[10];
    const float* w_cg    = (const float*)d_in[11];
    const float* b_cg    = (const float*)d_in[12];
    const float* cscale  = (const float*)d_in[13];
    const float* ccomb   = (const float*)d_in[14];
    const float* pb_w0   = (const float*)d_in[15];
    const float* pb_b0   = (const float*)d_in[16];
    const float* pb_g0   = (const float*)d_in[17];
    const float* pb_be0  = (const float*)d_in[18];
    const float* pb_w1   = (const float*)d_in[19];
    const float* pb_b1   = (const float*)d_in[20];
    const float* pb_g1   = (const float*)d_in[21];
    const float* pb_be1  = (const float*)d_in[22];
    const float* pb_w2   = (const float*)d_in[23];
    const float* pb_b2   = (const float*)d_in[24];
    const float* pb_g2   = (const float*)d_in[25];
    const float* pb_be2  = (const float*)d_in[26];
    const float* w_qkpos = (const float*)d_in[27];
    const float* b_qkpos = (const float*)d_in[28];
    const float* w_vpos  = (const float*)d_in[29];
    const float* b_vpos  = (const float*)d_in[30];
    const float* w_out   = (const float*)d_in[31];
    const float* b_out   = (const float*)d_in[32];

    // workspace carve (floats)
    float* wsf    = (float*)d_ws;
    float* q      = wsf;                    // 196608
    float* kT     = q      + 196608;        // 196608
    float* v      = kT     + 196608;        // 196608
    float* og     = v      + 196608;        // 3072
    float* rg     = og     + 3072;          // 3072
    float* qkpos  = rg     + 3072;          // 1179648 (b,i,j,h)
    _Float16* pbuf = (_Float16*)(qkpos + 1179648);  // 37748736 f16

    float* out0 = (float*)d_out;
    float* out1 = out0 + (long)B_ * N_ * DIM_;

    const int K2_LDS = 147200;
    hipFuncSetAttribute((const void*)eq_k2, hipFuncAttributeMaxDynamicSharedMemorySize, K2_LDS);

    eq_k1<<<B_ * N_, 256, 0, stream>>>(feats, gamma, w_qkv, w_gate, b_gate, q, kT, v, og, rg);
    eq_k2<<<256, 1024, K2_LDS, stream>>>(coors, pb_w0, pb_b0, pb_g0, pb_be0,
                                         pb_w1, pb_b1, pb_g1, pb_be1,
                                         pb_w2, pb_b2, pb_g2, pb_be2,
                                         w_qkpos, b_qkpos, pbuf, qkpos);
    eq_k3m<<<B_ * N_, 384, 0, stream>>>(q, kT, edges, qkpos, pbuf, v, coors,
                                        w_e1, w_e2, w_c, w_cg, b_cg, w_th,
                                        cscale, ccomb, og, rg,
                                        w_vpos, b_vpos, w_out, b_out, out0, out1);
}

// Round 7
// 399.553 us; speedup vs baseline: 2.8811x; 1.1215x over previous
//
#include <hip/hip_runtime.h>
#include <hip/hip_bf16.h>

#define B_   2
#define N_   384
#define DIM_ 256
#define H_   4
#define DH_  64
#define PD_  128
#define ED_  16
#define NU2_ ((B_ * N_ * N_) / 16)   // 18432 wave-units (16 pairs each)

typedef _Float16 v8h __attribute__((ext_vector_type(8)));
typedef float    v4f __attribute__((ext_vector_type(4)));

__device__ __forceinline__ float gelu_(float x) {
    return 0.5f * x * (1.0f + erff(x * 0.70710678118654752f));
}

// batched float4 block reduction over 256 threads (4 waves)
__device__ __forceinline__ float4 block_reduce256_f4(float4 v, float4* red) {
    #pragma unroll
    for (int o = 32; o > 0; o >>= 1) {
        v.x += __shfl_xor(v.x, o); v.y += __shfl_xor(v.y, o);
        v.z += __shfl_xor(v.z, o); v.w += __shfl_xor(v.w, o);
    }
    __syncthreads();
    if ((threadIdx.x & 63) == 0) red[threadIdx.x >> 6] = v;
    __syncthreads();
    float4 r = red[0];
    #pragma unroll
    for (int w2 = 1; w2 < 4; w2++) {
        float4 o = red[w2];
        r.x += o.x; r.y += o.y; r.z += o.z; r.w += o.w;
    }
    return r;
}

// batched float4 block reduction over 384 threads (6 waves).
__device__ __forceinline__ float4 block_reduce4(float4 v, bool ismax, float4* red, int slot) {
    #pragma unroll
    for (int o = 32; o > 0; o >>= 1) {
        float x = __shfl_xor(v.x, o), y = __shfl_xor(v.y, o);
        float z = __shfl_xor(v.z, o), w = __shfl_xor(v.w, o);
        if (ismax) { v.x = fmaxf(v.x, x); v.y = fmaxf(v.y, y); v.z = fmaxf(v.z, z); v.w = fmaxf(v.w, w); }
        else       { v.x += x; v.y += y; v.z += z; v.w += w; }
    }
    if ((threadIdx.x & 63) == 0) red[slot * 8 + (threadIdx.x >> 6)] = v;
    __syncthreads();
    float4 r = red[slot * 8];
    #pragma unroll
    for (int w2 = 1; w2 < 6; w2++) {
        float4 o = red[slot * 8 + w2];
        if (ismax) { r.x = fmaxf(r.x, o.x); r.y = fmaxf(r.y, o.y); r.z = fmaxf(r.z, o.z); r.w = fmaxf(r.w, o.w); }
        else       { r.x += o.x; r.y += o.y; r.z += o.z; r.w += o.w; }
    }
    return r;
}

// ---------- K1: LayerNorm + QKV (4 rows/block, f16 q/k out) + gates ----------
__global__ __launch_bounds__(256) void eq_k1(
    const float* __restrict__ feats, const float* __restrict__ gamma,
    const float* __restrict__ w_qkv, const float* __restrict__ w_gate,
    const float* __restrict__ b_gate,
    _Float16* __restrict__ qh, _Float16* __restrict__ kh, float* __restrict__ v,
    float* __restrict__ og, float* __restrict__ rg) {
    const int r0 = blockIdx.x * 4;       // 192 blocks, rows r0..r0+3 (same b: 384%4==0)
    const int b = r0 / N_;
    const int t = threadIdx.x;
    __shared__ float xs[4][DIM_];
    __shared__ float4 red4k[4];
    float4 f;
    f.x = feats[(long)(r0 + 0) * DIM_ + t];
    f.y = feats[(long)(r0 + 1) * DIM_ + t];
    f.z = feats[(long)(r0 + 2) * DIM_ + t];
    f.w = feats[(long)(r0 + 3) * DIM_ + t];
    float4 s = block_reduce256_f4(f, red4k);
    float4 mean = make_float4(s.x * (1.f/DIM_), s.y * (1.f/DIM_), s.z * (1.f/DIM_), s.w * (1.f/DIM_));
    float4 d = make_float4(f.x - mean.x, f.y - mean.y, f.z - mean.z, f.w - mean.w);
    float4 vr = block_reduce256_f4(make_float4(d.x*d.x, d.y*d.y, d.z*d.z, d.w*d.w), red4k);
    float g = gamma[t];
    xs[0][t] = d.x * rsqrtf(vr.x * (1.f/DIM_) + 1e-5f) * g;
    xs[1][t] = d.y * rsqrtf(vr.y * (1.f/DIM_) + 1e-5f) * g;
    xs[2][t] = d.z * rsqrtf(vr.z * (1.f/DIM_) + 1e-5f) * g;
    xs[3][t] = d.w * rsqrtf(vr.w * (1.f/DIM_) + 1e-5f) * g;
    __syncthreads();
    float acc[12];
    #pragma unroll
    for (int k = 0; k < 12; k++) acc[k] = 0.f;
    for (int c = 0; c < DIM_; c++) {
        const float* wr = w_qkv + (long)c * 768;
        float w0 = wr[t], w1 = wr[t + 256], w2 = wr[t + 512];
        #pragma unroll
        for (int r = 0; r < 4; r++) {
            float xc = xs[r][c];
            acc[r * 3 + 0] += xc * w0;
            acc[r * 3 + 1] += xc * w1;
            acc[r * 3 + 2] += xc * w2;
        }
    }
    int h = t >> 6, dd = t & 63;
    #pragma unroll
    for (int r = 0; r < 4; r++) {
        int n = r0 + r - b * N_;
        long idx = ((long)(b * H_ + h) * N_ + n) * DH_ + dd;
        qh[idx] = (_Float16)(acc[r * 3 + 0] * 0.125f);     // dh^-0.5 pre-applied
        kh[idx] = (_Float16)(acc[r * 3 + 1]);
        v[idx]  = acc[r * 3 + 2];
    }
    if (t < 32) {
        int rr = t >> 3, gg = t & 7;
        float a = b_gate[gg];
        for (int c = 0; c < DIM_; c++) a += xs[rr][c] * w_gate[c * 8 + gg];
        float gv = 1.0f / (1.0f + __expf(-a));
        int n = r0 + rr - b * N_;
        if (gg < 4) og[(b * H_ + gg) * N_ + n] = gv;
        else        rg[(b * H_ + (gg - 4)) * N_ + n] = gv;
    }
}

// ---------- K2: position-bias MLP, wave-independent MFMA ----------
// 512-thr blocks (8 waves), 1 block/CU (112KB LDS) -> 2 waves/SIMD ->
// VGPR budget 256: guaranteed no spill (body needs ~110).
// Each wave owns 16 pairs and all 128 channels. Stores p TRANSPOSED: pT[b,i,c,j].
#define MFMA16(a, b, c) __builtin_amdgcn_mfma_f32_16x16x32_f16(a, b, c, 0, 0, 0)

#define LNAPPLY(GOFF_, BOFF_)                                                     \
{                                                                                  \
    float gv[8], bev[8];                                                           \
    _Pragma("unroll")                                                              \
    for (int nt = 0; nt < 8; nt++) {                                               \
        gv[nt]  = GB[(GOFF_) + nt * 16 + l15];                                     \
        bev[nt] = GB[(BOFF_) + nt * 16 + l15];                                     \
    }                                                                              \
    _Pragma("unroll")                                                              \
    for (int rg2 = 0; rg2 < 4; rg2++) {                                            \
        float s = 0.f, sq = 0.f;                                                   \
        _Pragma("unroll")                                                          \
        for (int nt = 0; nt < 8; nt++) {                                           \
            float v0 = acc[nt][rg2]; s += v0; sq += v0 * v0;                       \
        }                                                                          \
        s += __shfl_xor(s, 1); sq += __shfl_xor(sq, 1);                            \
        s += __shfl_xor(s, 2); sq += __shfl_xor(sq, 2);                            \
        s += __shfl_xor(s, 4); sq += __shfl_xor(sq, 4);                            \
        s += __shfl_xor(s, 8); sq += __shfl_xor(sq, 8);                            \
        float mean = s * (1.f / 128.f);                                            \
        float inv = rsqrtf(sq * (1.f / 128.f) - mean * mean + 1e-5f);              \
        int row2 = quad * 4 + rg2;                                                 \
        _Pragma("unroll")                                                          \
        for (int nt = 0; nt < 8; nt++) {                                           \
            float y = (acc[nt][rg2] - mean) * inv * gv[nt] + bev[nt];              \
            y = y / (1.f + __expf(-y));                                            \
            myslice[row2 * 136 + nt * 16 + l15] = (_Float16)y;                     \
        }                                                                          \
    }                                                                              \
}

__global__ __launch_bounds__(512) __attribute__((amdgpu_waves_per_eu(2, 2)))
void eq_k2(
    const float* __restrict__ coors,
    const float* __restrict__ w0, const float* __restrict__ b0,
    const float* __restrict__ g0, const float* __restrict__ be0,
    const float* __restrict__ W1g, const float* __restrict__ b1,
    const float* __restrict__ g1, const float* __restrict__ be1,
    const float* __restrict__ W2g, const float* __restrict__ b2,
    const float* __restrict__ g2, const float* __restrict__ be2,
    const float* __restrict__ wqk, const float* __restrict__ bqk,
    _Float16* __restrict__ pT, float* __restrict__ qkpos) {

    extern __shared__ char smem[];
    _Float16* W1T    = (_Float16*)smem;                   // 128x136 = 34816 B
    _Float16* W2T    = (_Float16*)(smem + 34816);         // 34816 B
    _Float16* slices = (_Float16*)(smem + 69632);         // 8 x 16x136 = 34816 B
    _Float16* wqT    = (_Float16*)(smem + 104448);        // 16x136 = 4352 B
    float*    PQR    = (float*)(smem + 108800);           // 3x128 f32 = 1536 B
    float*    GB     = (float*)(smem + 110336);           // g1,be1,g2,be2 = 2048 B

    const int t = threadIdx.x;
    const int lane = t & 63, wv = t >> 6;            // wv 0..7
    const int l15 = lane & 15, quad = lane >> 4;
    _Float16* myslice = slices + wv * (16 * 136);

    for (int idx = t; idx < 16384; idx += 512) {
        int k = idx >> 7, n = idx & 127;
        W1T[n * 136 + k] = (_Float16)W1g[idx];
        W2T[n * 136 + k] = (_Float16)W2g[idx];
    }
    for (int idx = t; idx < 2048; idx += 512) {
        int n = idx >> 7, k = idx & 127;
        wqT[n * 136 + k] = (n < 4) ? (_Float16)wqk[k * 4 + n] : (_Float16)0.f;
    }
    // layer0 closed-form LN stats (redundant per thread, init-only)
    float Sw = 0, Sb = 0, Sww = 0, Swb = 0, Sbb = 0;
    for (int c = 0; c < 128; c++) {
        float w = w0[c], bb2v = b0[c];
        Sw += w; Sb += bb2v; Sww += w * w; Swb += w * bb2v; Sbb += bb2v * bb2v;
    }
    const float mw = Sw * (1.f / 128.f), mbb = Sb * (1.f / 128.f);
    const float A2 = Sww * (1.f / 128.f) - mw * mw;
    const float AD = Swb * (1.f / 128.f) - mw * mbb;
    const float D2 = Sbb * (1.f / 128.f) - mbb * mbb;
    if (t < 128) {
        PQR[t]       = (w0[t] - mw) * g0[t];
        PQR[128 + t] = (b0[t] - mbb) * g0[t];
        PQR[256 + t] = be0[t];
        GB[t]        = g1[t];
        GB[128 + t]  = be1[t];
        GB[256 + t]  = g2[t];
        GB[384 + t]  = be2[t];
    }
    float b1r[8], b2r[8];
    #pragma unroll
    for (int nt = 0; nt < 8; nt++) {
        int c = nt * 16 + l15;
        b1r[nt] = b1[c]; b2r[nt] = b2[c];
    }
    const float bq = (l15 < 4) ? bqk[l15] : 0.f;
    __syncthreads();   // the only barrier

    for (int unit = blockIdx.x * 8 + wv; unit < NU2_; unit += 256 * 8) {
        const int P0w = unit * 16;
        const int b = P0w / (N_ * N_);
        const int rem = P0w - b * (N_ * N_);
        const int ii = rem / N_;
        const int j0 = rem - ii * N_;
        const long bi = (long)(b * N_ + ii);
        const float cix = coors[(b * N_ + ii) * 3 + 0];
        const float ciy = coors[(b * N_ + ii) * 3 + 1];
        const float ciz = coors[(b * N_ + ii) * 3 + 2];
        float tt, uu;
        {
            int j = j0 + l15;
            float dx = cix - coors[(b * N_ + j) * 3 + 0];
            float dy = ciy - coors[(b * N_ + j) * 3 + 1];
            float dz = ciz - coors[(b * N_ + j) * 3 + 2];
            float d = sqrtf(dx * dx + dy * dy + dz * dz);
            float var = (d * d) * A2 + 2.f * d * AD + D2;
            float inv = rsqrtf(var + 1e-5f);
            tt = d * inv; uu = inv;
        }
        // layer0 directly into A-fragments
        v8h A[4];
        #pragma unroll
        for (int kt = 0; kt < 4; kt++) {
            int base = kt * 32 + quad * 8;
            v8h av;
            #pragma unroll
            for (int jj = 0; jj < 8; jj++) {
                float y = tt * PQR[base + jj] + uu * PQR[128 + base + jj] + PQR[256 + base + jj];
                av[jj] = (_Float16)(y / (1.f + __expf(-y)));
            }
            A[kt] = av;
        }
        // ---- layer1 ----
        v4f acc[8];
        #pragma unroll
        for (int nt = 0; nt < 8; nt++) {
            v4f ci = {b1r[nt], b1r[nt], b1r[nt], b1r[nt]};
            acc[nt] = ci;
        }
        #pragma unroll
        for (int kt = 0; kt < 4; kt++) {
            #pragma unroll
            for (int nt = 0; nt < 8; nt++) {
                v8h Bv = *(const v8h*)&W1T[(nt * 16 + l15) * 136 + kt * 32 + quad * 8];
                acc[nt] = MFMA16(A[kt], Bv, acc[nt]);
            }
        }
        LNAPPLY(0, 128)
        // ---- layer2 ----
        #pragma unroll
        for (int kt = 0; kt < 4; kt++)
            A[kt] = *(const v8h*)&myslice[l15 * 136 + kt * 32 + quad * 8];
        #pragma unroll
        for (int nt = 0; nt < 8; nt++) {
            v4f ci = {b2r[nt], b2r[nt], b2r[nt], b2r[nt]};
            acc[nt] = ci;
        }
        #pragma unroll
        for (int kt = 0; kt < 4; kt++) {
            #pragma unroll
            for (int nt = 0; nt < 8; nt++) {
                v8h Bv = *(const v8h*)&W2T[(nt * 16 + l15) * 136 + kt * 32 + quad * 8];
                acc[nt] = MFMA16(A[kt], Bv, acc[nt]);
            }
        }
        LNAPPLY(256, 384)
        // ---- pT store: transposed [b,i,c,j], 2 channels/lane, 16B stores ----
        #pragma unroll
        for (int cc = 0; cc < 2; cc++) {
            int c = lane + cc * 64;
            v8h lo, hi;
            #pragma unroll
            for (int k = 0; k < 8; k++) {
                lo[k] = myslice[k * 136 + c];
                hi[k] = myslice[(k + 8) * 136 + c];
            }
            _Float16* dst = pT + (bi * PD_ + c) * N_ + j0;
            *(v8h*)dst = lo;
            *(v8h*)(dst + 8) = hi;
        }
        // ---- qk_pos = p @ wqk + bqk ----
        {
            v4f c = {0.f, 0.f, 0.f, 0.f};
            #pragma unroll
            for (int kt = 0; kt < 4; kt++) {
                v8h av = *(const v8h*)&myslice[l15 * 136 + kt * 32 + quad * 8];
                v8h wq = *(const v8h*)&wqT[l15 * 136 + kt * 32 + quad * 8];
                c = MFMA16(av, wq, c);
            }
            if (l15 < 4) {
                #pragma unroll
                for (int rg2 = 0; rg2 < 4; rg2++) {
                    int row = quad * 4 + rg2;
                    qkpos[(long)(P0w + row) * 4 + l15] = c[rg2] + bq;
                }
            }
        }
    }
}

// ---------- K2b: qk = q @ k^T via MFMA, accumulated into qkpos ----------
// grid = 8 bh x 24 i-tiles x 2 n-halves = 384 blocks x 64 threads.
__global__ __launch_bounds__(64) void eq_k2b(
    const _Float16* __restrict__ qh, const _Float16* __restrict__ kh,
    float* __restrict__ qkpos) {
    const int blk = blockIdx.x;
    const int bh = blk / 48;
    const int rest = blk - bh * 48;
    const int it = rest >> 1, nh = rest & 1;
    const int b = bh >> 2, h = bh & 3;
    const int i0 = it * 16;
    const int t = threadIdx.x;
    const int l15 = t & 15, quad = t >> 4;

    v8h A0 = *(const v8h*)&qh[((long)(bh * N_) + i0 + l15) * DH_ + quad * 8];
    v8h A1 = *(const v8h*)&qh[((long)(bh * N_) + i0 + l15) * DH_ + 32 + quad * 8];
    #pragma unroll 1
    for (int nt = 0; nt < 12; nt++) {
        int j0 = nh * 192 + nt * 16;
        v8h B0 = *(const v8h*)&kh[((long)(bh * N_) + j0 + l15) * DH_ + quad * 8];
        v8h B1 = *(const v8h*)&kh[((long)(bh * N_) + j0 + l15) * DH_ + 32 + quad * 8];
        v4f c = {0.f, 0.f, 0.f, 0.f};
        c = MFMA16(A0, B0, c);
        c = MFMA16(A1, B1, c);
        #pragma unroll
        for (int rg2 = 0; rg2 < 4; rg2++) {
            int i = i0 + quad * 4 + rg2;
            int j = j0 + l15;
            long idx = (((long)(b * N_ + i)) * N_ + j) * 4 + h;
            qkpos[idx] += c[rg2];
        }
    }
}

// ---------- K3M: fused edge-MLP/softmax/coor-branch/ap(MFMA)/attn@v/out-proj ----------
__global__ __launch_bounds__(384) void eq_k3m(
    const float* __restrict__ edges, const float* __restrict__ qkpos,
    const _Float16* __restrict__ pT, const float* __restrict__ v,
    const float* __restrict__ coors,
    const float* __restrict__ w_e1, const float* __restrict__ w_e2,
    const float* __restrict__ w_c, const float* __restrict__ w_cg,
    const float* __restrict__ b_cg, const float* __restrict__ w_th,
    const float* __restrict__ cscale, const float* __restrict__ ccomb,
    const float* __restrict__ og, const float* __restrict__ rg,
    const float* __restrict__ w_vpos, const float* __restrict__ b_vpos,
    const float* __restrict__ w_out, const float* __restrict__ b_out,
    float* __restrict__ out0, float* __restrict__ out1) {
    int row = blockIdx.x;           // b*N + i
    int b = row / N_, i = row - b * N_;
    int j = threadIdx.x;            // 0..383
    __shared__ float we1[20 * 40];
    __shared__ float we2[40 * 4];
    __shared__ float wcs[16], wcgs[16], bcgs[4], wths[16];
    __shared__ float attnS[4 * N_];
    __shared__ float apS[2 * 4 * PD_];
    __shared__ float nodeS[256];
    __shared__ float4 red4[16];

    for (int idx = j; idx < 800; idx += 384) we1[idx] = w_e1[idx];
    if (j < 160) we2[j] = w_e2[j];
    if (j < 16) { wcs[j] = w_c[j]; wcgs[j] = w_cg[j]; wths[j] = w_th[j]; }
    if (j < 4) bcgs[j] = b_cg[j];
    __syncthreads();

    // ---- phase A: scores (qk + pos, precomputed) + edge MLP ----
    long pair = ((long)row) * N_ + j;
    float in20[20];
    {
        float4 qp = *(const float4*)(qkpos + pair * 4);
        in20[0] = qp.x; in20[1] = qp.y; in20[2] = qp.z; in20[3] = qp.w;
    }
    const float4* ep = (const float4*)(edges + pair * ED_);
    float4 e0 = ep[0], e1 = ep[1], e2 = ep[2], e3 = ep[3];
    in20[4] = e0.x;  in20[5] = e0.y;  in20[6] = e0.z;  in20[7] = e0.w;
    in20[8] = e1.x;  in20[9] = e1.y;  in20[10] = e1.z; in20[11] = e1.w;
    in20[12] = e2.x; in20[13] = e2.y; in20[14] = e2.z; in20[15] = e2.w;
    in20[16] = e3.x; in20[17] = e3.y; in20[18] = e3.z; in20[19] = e3.w;

    float c0 = 0, c1 = 0, c2 = 0, c3 = 0;
    #pragma unroll 1
    for (int oc = 0; oc < 5; oc++) {
        float a8[8] = {0.f, 0.f, 0.f, 0.f, 0.f, 0.f, 0.f, 0.f};
        #pragma unroll
        for (int c = 0; c < 20; c++) {
            float xc = in20[c];
            float4 wa = *(const float4*)&we1[c * 40 + oc * 8];
            float4 wb = *(const float4*)&we1[c * 40 + oc * 8 + 4];
            a8[0] += xc * wa.x; a8[1] += xc * wa.y; a8[2] += xc * wa.z; a8[3] += xc * wa.w;
            a8[4] += xc * wb.x; a8[5] += xc * wb.y; a8[6] += xc * wb.z; a8[7] += xc * wb.w;
        }
        #pragma unroll
        for (int o = 0; o < 8; o++) {
            float gg = gelu_(a8[o]);
            float4 w2v = *(const float4*)&we2[(oc * 8 + o) * 4];
            c0 += gg * w2v.x; c1 += gg * w2v.y; c2 += gg * w2v.z; c3 += gg * w2v.w;
        }
    }
    float cmi[4] = {c0, c1, c2, c3};
    float gc[4], cp[4], rs[4];
    #pragma unroll
    for (int h = 0; h < 4; h++) gc[h] = gelu_(cmi[h]);
    #pragma unroll
    for (int h = 0; h < 4; h++) {
        cp[h] = gc[0] * wcs[h] + gc[1] * wcs[4 + h] + gc[2] * wcs[8 + h] + gc[3] * wcs[12 + h];
        rs[h] = cmi[0] * wcgs[h] + cmi[1] * wcgs[4 + h] + cmi[2] * wcgs[8 + h] + cmi[3] * wcgs[12 + h] + bcgs[h];
    }

    // ---- phase B: softmax over j + talking heads -> attnS ----
    float4 m4 = block_reduce4(make_float4(cmi[0], cmi[1], cmi[2], cmi[3]), true, red4, 0);
    float e[4];
    e[0] = __expf(cmi[0] - m4.x); e[1] = __expf(cmi[1] - m4.y);
    e[2] = __expf(cmi[2] - m4.z); e[3] = __expf(cmi[3] - m4.w);
    float4 l4 = block_reduce4(make_float4(e[0], e[1], e[2], e[3]), false, red4, 1);
    float sm[4] = {e[0] / l4.x, e[1] / l4.y, e[2] / l4.z, e[3] / l4.w};
    #pragma unroll
    for (int h = 0; h < 4; h++)
        attnS[h * N_ + j] = wths[h * 4 + 0] * sm[0] + wths[h * 4 + 1] * sm[1]
                          + wths[h * 4 + 2] * sm[2] + wths[h * 4 + 3] * sm[3];

    // ---- phase C: coordinate branch -> out1 ----
    float dx = coors[(b * N_ + i) * 3 + 0] - coors[(b * N_ + j) * 3 + 0];
    float dy = coors[(b * N_ + i) * 3 + 1] - coors[(b * N_ + j) * 3 + 1];
    float dz = coors[(b * N_ + i) * 3 + 2] - coors[(b * N_ + j) * 3 + 2];
    float nrm = sqrtf(dx * dx + dy * dy + dz * dz);
    float sc = cscale[0] / fmaxf(nrm, 1e-8f);
    float rx = dx * sc, ry = dy * sc, rz = dz * sc;
    float4 cm4 = block_reduce4(make_float4(cp[0], cp[1], cp[2], cp[3]), true, red4, 0);
    float ec[4];
    ec[0] = __expf(cp[0] - cm4.x); ec[1] = __expf(cp[1] - cm4.y);
    ec[2] = __expf(cp[2] - cm4.z); ec[3] = __expf(cp[3] - cm4.w);
    float4 cl4 = block_reduce4(make_float4(ec[0], ec[1], ec[2], ec[3]), false, red4, 1);
    float w[4] = {ec[0] / cl4.x * rs[0], ec[1] / cl4.y * rs[1],
                  ec[2] / cl4.z * rs[2], ec[3] / cl4.w * rs[3]};
    float4 sx4 = block_reduce4(make_float4(w[0] * rx, w[1] * rx, w[2] * rx, w[3] * rx), false, red4, 0);
    float4 sy4 = block_reduce4(make_float4(w[0] * ry, w[1] * ry, w[2] * ry, w[3] * ry), false, red4, 1);
    float4 sz4 = block_reduce4(make_float4(w[0] * rz, w[1] * rz, w[2] * rz, w[3] * rz), false, red4, 0);
    if (j == 0) {
        float f0 = ccomb[0] * rg[(b * H_ + 0) * N_ + i];
        float f1 = ccomb[1] * rg[(b * H_ + 1) * N_ + i];
        float f2 = ccomb[2] * rg[(b * H_ + 2) * N_ + i];
        float f3 = ccomb[3] * rg[(b * H_ + 3) * N_ + i];
        out1[(b * N_ + i) * 3 + 0] = f0 * sx4.x + f1 * sx4.y + f2 * sx4.z + f3 * sx4.w;
        out1[(b * N_ + i) * 3 + 1] = f0 * sy4.x + f1 * sy4.y + f2 * sy4.z + f3 * sy4.w;
        out1[(b * N_ + i) * 3 + 2] = f0 * sz4.x + f1 * sz4.y + f2 * sz4.z + f3 * sz4.w;
    }
    __syncthreads();

    // ---- phase D: waves 0-1 -> ap via MFMA (pT B-frags); threads 128..383 -> attn@v ----
    if (j < 128) {
        const int lane = j & 63, l15d = lane & 15, quadd = lane >> 4;
        const int parity = j >> 6;      // wave 0 or 1: kt halves
        v4f acc[8];
        #pragma unroll
        for (int nt = 0; nt < 8; nt++) { v4f z = {0.f, 0.f, 0.f, 0.f}; acc[nt] = z; }
        #pragma unroll 1
        for (int kth = 0; kth < 6; kth++) {
            int kt = parity * 6 + kth;
            v8h Af;
            #pragma unroll
            for (int jj = 0; jj < 8; jj++) {
                float av = (l15d < 4) ? attnS[l15d * N_ + kt * 32 + quadd * 8 + jj] : 0.f;
                Af[jj] = (_Float16)av;
            }
            #pragma unroll
            for (int nt = 0; nt < 8; nt++) {
                v8h Bv = *(const v8h*)&pT[((long)row * PD_ + nt * 16 + l15d) * N_ + kt * 32 + quadd * 8];
                acc[nt] = MFMA16(Af, Bv, acc[nt]);
            }
        }
        if (quadd == 0) {
            #pragma unroll
            for (int nt = 0; nt < 8; nt++)
                #pragma unroll
                for (int rg2 = 0; rg2 < 4; rg2++)
                    apS[parity * 512 + rg2 * 128 + nt * 16 + l15d] = acc[nt][rg2];
        }
    } else {
        int tt = j - 128, h = tt >> 6, d = tt & 63;
        float acc = 0;
        const float* vp = v + ((long)(b * H_ + h) * N_) * DH_ + d;
        #pragma unroll 8
        for (int jj = 0; jj < N_; jj++) acc += attnS[h * N_ + jj] * vp[(long)jj * DH_];
        nodeS[tt] = acc;
    }
    __syncthreads();

    // ---- phase E: node = (attnv + ap@w_vpos + Sh*b_vpos) * out_gate ----
    float nv = 0;
    if (j < 256) {
        int h = j >> 6, d = j & 63;
        float accp = 0;
        const float* wv = w_vpos + h * DH_ + d;
        #pragma unroll 8
        for (int c = 0; c < PD_; c++)
            accp += (apS[h * 128 + c] + apS[512 + h * 128 + c]) * wv[(long)c * (H_ * DH_)];
        float Sh = wths[h * 4 + 0] + wths[h * 4 + 1] + wths[h * 4 + 2] + wths[h * 4 + 3];
        nv = (nodeS[j] + accp + Sh * b_vpos[h * DH_ + d]) * og[(b * H_ + h) * N_ + i];
    }
    __syncthreads();
    if (j < 256) nodeS[j] = nv;
    __syncthreads();

    // ---- phase F: out0 = node @ w_out + b_out ----
    if (j < 256) {
        float acc = b_out[j];
        #pragma unroll 8
        for (int c = 0; c < 256; c++) acc += nodeS[c] * w_out[(long)c * 256 + j];
        out0[(long)row * 256 + j] = acc;
    }
}

extern "C" void kernel_launch(void* const* d_in, const int* in_sizes, int n_in,
                              void* d_out, int out_size, void* d_ws, size_t ws_size,
                              hipStream_t stream) {
    (void)in_sizes; (void)n_in; (void)out_size; (void)ws_size;
    const float* feats   = (const float*)d_in[0];
    const float* coors   = (const float*)d_in[1];
    const float* edges   = (const float*)d_in[2];
    const float* gamma   = (const float*)d_in[3];
    const float* w_qkv   = (const float*)d_in[4];
    const float* w_gate  = (const float*)d_in[5];
    const float* b_gate  = (const float*)d_in[6];
    const float* w_th    = (const float*)d_in[7];
    const float* w_e1    = (const float*)d_in[8];
    const float* w_e2    = (const float*)d_in[9];
    const float* w_c     = (const float*)d_in[10];
    const float* w_cg    = (const float*)d_in[11];
    const float* b_cg    = (const float*)d_in[12];
    const float* cscale  = (const float*)d_in[13];
    const float* ccomb   = (const float*)d_in[14];
    const float* pb_w0   = (const float*)d_in[15];
    const float* pb_b0   = (const float*)d_in[16];
    const float* pb_g0   = (const float*)d_in[17];
    const float* pb_be0  = (const float*)d_in[18];
    const float* pb_w1   = (const float*)d_in[19];
    const float* pb_b1   = (const float*)d_in[20];
    const float* pb_g1   = (const float*)d_in[21];
    const float* pb_be1  = (const float*)d_in[22];
    const float* pb_w2   = (const float*)d_in[23];
    const float* pb_b2   = (const float*)d_in[24];
    const float* pb_g2   = (const float*)d_in[25];
    const float* pb_be2  = (const float*)d_in[26];
    const float* w_qkpos = (const float*)d_in[27];
    const float* b_qkpos = (const float*)d_in[28];
    const float* w_vpos  = (const float*)d_in[29];
    const float* b_vpos  = (const float*)d_in[30];
    const float* w_out   = (const float*)d_in[31];
    const float* b_out   = (const float*)d_in[32];

    // workspace carve (bytes)
    char* ws = (char*)d_ws;
    _Float16* qh   = (_Float16*)(ws + 0);            // 393216 B
    _Float16* kh   = (_Float16*)(ws + 393216);       // 393216 B
    float* v       = (float*)(ws + 786432);          // 786432 B
    float* og      = (float*)(ws + 1572864);         // 12288 B
    float* rg      = (float*)(ws + 1585152);         // 12288 B
    float* qkpos   = (float*)(ws + 1597440);         // 4718592 B
    _Float16* pT   = (_Float16*)(ws + 6316032);      // 75497472 B

    float* out0 = (float*)d_out;
    float* out1 = out0 + (long)B_ * N_ * DIM_;

    const int K2_LDS = 112384;
    hipFuncSetAttribute((const void*)eq_k2, hipFuncAttributeMaxDynamicSharedMemorySize, K2_LDS);

    eq_k1<<<192, 256, 0, stream>>>(feats, gamma, w_qkv, w_gate, b_gate, qh, kh, v, og, rg);
    eq_k2<<<256, 512, K2_LDS, stream>>>(coors, pb_w0, pb_b0, pb_g0, pb_be0,
                                        pb_w1, pb_b1, pb_g1, pb_be1,
                                        pb_w2, pb_b2, pb_g2, pb_be2,
                                        w_qkpos, b_qkpos, pT, qkpos);
    eq_k2b<<<384, 64, 0, stream>>>(qh, kh, qkpos);
    eq_k3m<<<B_ * N_, 384, 0, stream>>>(edges, qkpos, pT, v, coors,
                                        w_e1, w_e2, w_c, w_cg, b_cg, w_th,
                                        cscale, ccomb, og, rg,
                                        w_vpos, b_vpos, w_out, b_out, out0, out1);
}

// Round 8
// 395.275 us; speedup vs baseline: 2.9123x; 1.0108x over previous
//
#include <hip/hip_runtime.h>
#include <hip/hip_bf16.h>

#define B_   2
#define N_   384
#define DIM_ 256
#define H_   4
#define DH_  64
#define PD_  128
#define ED_  16
#define NU2_ ((B_ * N_ * N_) / 16)   // 18432 wave-units (16 pairs each)

typedef _Float16 v8h __attribute__((ext_vector_type(8)));
typedef float    v4f __attribute__((ext_vector_type(4)));

// fast erf: Abramowitz-Stegun 7.1.26, |err| <= 1.5e-7 (vs libm erff ~100 inst)
__device__ __forceinline__ float erf_fast(float x) {
    float ax = fabsf(x);
    float t = 1.0f / fmaf(0.3275911f, ax, 1.0f);
    float y = t * fmaf(t, fmaf(t, fmaf(t, fmaf(t, 1.061405429f, -1.453152027f),
                                       1.421413741f), -0.284496736f), 0.254829592f);
    float r = 1.0f - y * __expf(-ax * ax);
    return (x < 0.f) ? -r : r;
}
__device__ __forceinline__ float gelu_(float x) {
    return 0.5f * x * (1.0f + erf_fast(x * 0.70710678118654752f));
}

// batched float4 block reduction over 256 threads (4 waves)
__device__ __forceinline__ float4 block_reduce256_f4(float4 v, float4* red) {
    #pragma unroll
    for (int o = 32; o > 0; o >>= 1) {
        v.x += __shfl_xor(v.x, o); v.y += __shfl_xor(v.y, o);
        v.z += __shfl_xor(v.z, o); v.w += __shfl_xor(v.w, o);
    }
    __syncthreads();
    if ((threadIdx.x & 63) == 0) red[threadIdx.x >> 6] = v;
    __syncthreads();
    float4 r = red[0];
    #pragma unroll
    for (int w2 = 1; w2 < 4; w2++) {
        float4 o = red[w2];
        r.x += o.x; r.y += o.y; r.z += o.z; r.w += o.w;
    }
    return r;
}

// batched float4 block reduction over 384 threads (6 waves).
__device__ __forceinline__ float4 block_reduce4(float4 v, bool ismax, float4* red, int slot) {
    #pragma unroll
    for (int o = 32; o > 0; o >>= 1) {
        float x = __shfl_xor(v.x, o), y = __shfl_xor(v.y, o);
        float z = __shfl_xor(v.z, o), w = __shfl_xor(v.w, o);
        if (ismax) { v.x = fmaxf(v.x, x); v.y = fmaxf(v.y, y); v.z = fmaxf(v.z, z); v.w = fmaxf(v.w, w); }
        else       { v.x += x; v.y += y; v.z += z; v.w += w; }
    }
    if ((threadIdx.x & 63) == 0) red[slot * 8 + (threadIdx.x >> 6)] = v;
    __syncthreads();
    float4 r = red[slot * 8];
    #pragma unroll
    for (int w2 = 1; w2 < 6; w2++) {
        float4 o = red[slot * 8 + w2];
        if (ismax) { r.x = fmaxf(r.x, o.x); r.y = fmaxf(r.y, o.y); r.z = fmaxf(r.z, o.z); r.w = fmaxf(r.w, o.w); }
        else       { r.x += o.x; r.y += o.y; r.z += o.z; r.w += o.w; }
    }
    return r;
}

// ---------- K1: LayerNorm + QKV (4 rows/block, f16 q/k out) + gates ----------
__global__ __launch_bounds__(256) void eq_k1(
    const float* __restrict__ feats, const float* __restrict__ gamma,
    const float* __restrict__ w_qkv, const float* __restrict__ w_gate,
    const float* __restrict__ b_gate,
    _Float16* __restrict__ qh, _Float16* __restrict__ kh, float* __restrict__ v,
    float* __restrict__ og, float* __restrict__ rg) {
    const int r0 = blockIdx.x * 4;       // 192 blocks, rows r0..r0+3 (same b: 384%4==0)
    const int b = r0 / N_;
    const int t = threadIdx.x;
    __shared__ float xs[4][DIM_];
    __shared__ float4 red4k[4];
    float4 f;
    f.x = feats[(long)(r0 + 0) * DIM_ + t];
    f.y = feats[(long)(r0 + 1) * DIM_ + t];
    f.z = feats[(long)(r0 + 2) * DIM_ + t];
    f.w = feats[(long)(r0 + 3) * DIM_ + t];
    float4 s = block_reduce256_f4(f, red4k);
    float4 mean = make_float4(s.x * (1.f/DIM_), s.y * (1.f/DIM_), s.z * (1.f/DIM_), s.w * (1.f/DIM_));
    float4 d = make_float4(f.x - mean.x, f.y - mean.y, f.z - mean.z, f.w - mean.w);
    float4 vr = block_reduce256_f4(make_float4(d.x*d.x, d.y*d.y, d.z*d.z, d.w*d.w), red4k);
    float g = gamma[t];
    xs[0][t] = d.x * rsqrtf(vr.x * (1.f/DIM_) + 1e-5f) * g;
    xs[1][t] = d.y * rsqrtf(vr.y * (1.f/DIM_) + 1e-5f) * g;
    xs[2][t] = d.z * rsqrtf(vr.z * (1.f/DIM_) + 1e-5f) * g;
    xs[3][t] = d.w * rsqrtf(vr.w * (1.f/DIM_) + 1e-5f) * g;
    __syncthreads();
    float acc[12];
    #pragma unroll
    for (int k = 0; k < 12; k++) acc[k] = 0.f;
    for (int c = 0; c < DIM_; c++) {
        const float* wr = w_qkv + (long)c * 768;
        float w0 = wr[t], w1 = wr[t + 256], w2 = wr[t + 512];
        #pragma unroll
        for (int r = 0; r < 4; r++) {
            float xc = xs[r][c];
            acc[r * 3 + 0] += xc * w0;
            acc[r * 3 + 1] += xc * w1;
            acc[r * 3 + 2] += xc * w2;
        }
    }
    int h = t >> 6, dd = t & 63;
    #pragma unroll
    for (int r = 0; r < 4; r++) {
        int n = r0 + r - b * N_;
        long idx = ((long)(b * H_ + h) * N_ + n) * DH_ + dd;
        qh[idx] = (_Float16)(acc[r * 3 + 0] * 0.125f);     // dh^-0.5 pre-applied
        kh[idx] = (_Float16)(acc[r * 3 + 1]);
        v[idx]  = acc[r * 3 + 2];
    }
    if (t < 32) {
        int rr = t >> 3, gg = t & 7;
        float a = b_gate[gg];
        for (int c = 0; c < DIM_; c++) a += xs[rr][c] * w_gate[c * 8 + gg];
        float gv = 1.0f / (1.0f + __expf(-a));
        int n = r0 + rr - b * N_;
        if (gg < 4) og[(b * H_ + gg) * N_ + n] = gv;
        else        rg[(b * H_ + (gg - 4)) * N_ + n] = gv;
    }
}

// ---------- K2: position-bias MLP, wave-independent MFMA ----------
#define MFMA16(a, b, c) __builtin_amdgcn_mfma_f32_16x16x32_f16(a, b, c, 0, 0, 0)

#define LNAPPLY(GOFF_, BOFF_)                                                     \
{                                                                                  \
    float gv[8], bev[8];                                                           \
    _Pragma("unroll")                                                              \
    for (int nt = 0; nt < 8; nt++) {                                               \
        gv[nt]  = GB[(GOFF_) + nt * 16 + l15];                                     \
        bev[nt] = GB[(BOFF_) + nt * 16 + l15];                                     \
    }                                                                              \
    _Pragma("unroll")                                                              \
    for (int rg2 = 0; rg2 < 4; rg2++) {                                            \
        float s = 0.f, sq = 0.f;                                                   \
        _Pragma("unroll")                                                          \
        for (int nt = 0; nt < 8; nt++) {                                           \
            float v0 = acc[nt][rg2]; s += v0; sq += v0 * v0;                       \
        }                                                                          \
        s += __shfl_xor(s, 1); sq += __shfl_xor(sq, 1);                            \
        s += __shfl_xor(s, 2); sq += __shfl_xor(sq, 2);                            \
        s += __shfl_xor(s, 4); sq += __shfl_xor(sq, 4);                            \
        s += __shfl_xor(s, 8); sq += __shfl_xor(sq, 8);                            \
        float mean = s * (1.f / 128.f);                                            \
        float inv = rsqrtf(sq * (1.f / 128.f) - mean * mean + 1e-5f);              \
        int row2 = quad * 4 + rg2;                                                 \
        _Pragma("unroll")                                                          \
        for (int nt = 0; nt < 8; nt++) {                                           \
            float y = (acc[nt][rg2] - mean) * inv * gv[nt] + bev[nt];              \
            y = y / (1.f + __expf(-y));                                            \
            myslice[row2 * 136 + nt * 16 + l15] = (_Float16)y;                     \
        }                                                                          \
    }                                                                              \
}

__global__ __launch_bounds__(512) __attribute__((amdgpu_waves_per_eu(2, 2)))
void eq_k2(
    const float* __restrict__ coors,
    const float* __restrict__ w0, const float* __restrict__ b0,
    const float* __restrict__ g0, const float* __restrict__ be0,
    const float* __restrict__ W1g, const float* __restrict__ b1,
    const float* __restrict__ g1, const float* __restrict__ be1,
    const float* __restrict__ W2g, const float* __restrict__ b2,
    const float* __restrict__ g2, const float* __restrict__ be2,
    const float* __restrict__ wqk, const float* __restrict__ bqk,
    _Float16* __restrict__ pT, float* __restrict__ qkpos) {

    extern __shared__ char smem[];
    _Float16* W1T    = (_Float16*)smem;                   // 128x136 = 34816 B
    _Float16* W2T    = (_Float16*)(smem + 34816);         // 34816 B
    _Float16* slices = (_Float16*)(smem + 69632);         // 8 x 16x136 = 34816 B
    _Float16* wqT    = (_Float16*)(smem + 104448);        // 16x136 = 4352 B
    float*    PQR    = (float*)(smem + 108800);           // 3x128 f32 = 1536 B
    float*    GB     = (float*)(smem + 110336);           // g1,be1,g2,be2 = 2048 B

    const int t = threadIdx.x;
    const int lane = t & 63, wv = t >> 6;            // wv 0..7
    const int l15 = lane & 15, quad = lane >> 4;
    _Float16* myslice = slices + wv * (16 * 136);

    for (int idx = t; idx < 16384; idx += 512) {
        int k = idx >> 7, n = idx & 127;
        W1T[n * 136 + k] = (_Float16)W1g[idx];
        W2T[n * 136 + k] = (_Float16)W2g[idx];
    }
    for (int idx = t; idx < 2048; idx += 512) {
        int n = idx >> 7, k = idx & 127;
        wqT[n * 136 + k] = (n < 4) ? (_Float16)wqk[k * 4 + n] : (_Float16)0.f;
    }
    // layer0 closed-form LN stats (redundant per thread, init-only)
    float Sw = 0, Sb = 0, Sww = 0, Swb = 0, Sbb = 0;
    for (int c = 0; c < 128; c++) {
        float w = w0[c], bb2v = b0[c];
        Sw += w; Sb += bb2v; Sww += w * w; Swb += w * bb2v; Sbb += bb2v * bb2v;
    }
    const float mw = Sw * (1.f / 128.f), mbb = Sb * (1.f / 128.f);
    const float A2 = Sww * (1.f / 128.f) - mw * mw;
    const float AD = Swb * (1.f / 128.f) - mw * mbb;
    const float D2 = Sbb * (1.f / 128.f) - mbb * mbb;
    if (t < 128) {
        PQR[t]       = (w0[t] - mw) * g0[t];
        PQR[128 + t] = (b0[t] - mbb) * g0[t];
        PQR[256 + t] = be0[t];
        GB[t]        = g1[t];
        GB[128 + t]  = be1[t];
        GB[256 + t]  = g2[t];
        GB[384 + t]  = be2[t];
    }
    float b1r[8], b2r[8];
    #pragma unroll
    for (int nt = 0; nt < 8; nt++) {
        int c = nt * 16 + l15;
        b1r[nt] = b1[c]; b2r[nt] = b2[c];
    }
    const float bq = (l15 < 4) ? bqk[l15] : 0.f;
    __syncthreads();   // the only barrier

    for (int unit = blockIdx.x * 8 + wv; unit < NU2_; unit += 256 * 8) {
        const int P0w = unit * 16;
        const int b = P0w / (N_ * N_);
        const int rem = P0w - b * (N_ * N_);
        const int ii = rem / N_;
        const int j0 = rem - ii * N_;
        const long bi = (long)(b * N_ + ii);
        const float cix = coors[(b * N_ + ii) * 3 + 0];
        const float ciy = coors[(b * N_ + ii) * 3 + 1];
        const float ciz = coors[(b * N_ + ii) * 3 + 2];
        float tt, uu;
        {
            int j = j0 + l15;
            float dx = cix - coors[(b * N_ + j) * 3 + 0];
            float dy = ciy - coors[(b * N_ + j) * 3 + 1];
            float dz = ciz - coors[(b * N_ + j) * 3 + 2];
            float d = sqrtf(dx * dx + dy * dy + dz * dz);
            float var = (d * d) * A2 + 2.f * d * AD + D2;
            float inv = rsqrtf(var + 1e-5f);
            tt = d * inv; uu = inv;
        }
        // layer0 directly into A-fragments
        v8h A[4];
        #pragma unroll
        for (int kt = 0; kt < 4; kt++) {
            int base = kt * 32 + quad * 8;
            v8h av;
            #pragma unroll
            for (int jj = 0; jj < 8; jj++) {
                float y = tt * PQR[base + jj] + uu * PQR[128 + base + jj] + PQR[256 + base + jj];
                av[jj] = (_Float16)(y / (1.f + __expf(-y)));
            }
            A[kt] = av;
        }
        // ---- layer1 ----
        v4f acc[8];
        #pragma unroll
        for (int nt = 0; nt < 8; nt++) {
            v4f ci = {b1r[nt], b1r[nt], b1r[nt], b1r[nt]};
            acc[nt] = ci;
        }
        #pragma unroll
        for (int kt = 0; kt < 4; kt++) {
            #pragma unroll
            for (int nt = 0; nt < 8; nt++) {
                v8h Bv = *(const v8h*)&W1T[(nt * 16 + l15) * 136 + kt * 32 + quad * 8];
                acc[nt] = MFMA16(A[kt], Bv, acc[nt]);
            }
        }
        LNAPPLY(0, 128)
        // ---- layer2 ----
        #pragma unroll
        for (int kt = 0; kt < 4; kt++)
            A[kt] = *(const v8h*)&myslice[l15 * 136 + kt * 32 + quad * 8];
        #pragma unroll
        for (int nt = 0; nt < 8; nt++) {
            v4f ci = {b2r[nt], b2r[nt], b2r[nt], b2r[nt]};
            acc[nt] = ci;
        }
        #pragma unroll
        for (int kt = 0; kt < 4; kt++) {
            #pragma unroll
            for (int nt = 0; nt < 8; nt++) {
                v8h Bv = *(const v8h*)&W2T[(nt * 16 + l15) * 136 + kt * 32 + quad * 8];
                acc[nt] = MFMA16(A[kt], Bv, acc[nt]);
            }
        }
        LNAPPLY(256, 384)
        // ---- pT store: transposed [b,i,c,j], 2 channels/lane, 16B stores ----
        #pragma unroll
        for (int cc = 0; cc < 2; cc++) {
            int c = lane + cc * 64;
            v8h lo, hi;
            #pragma unroll
            for (int k = 0; k < 8; k++) {
                lo[k] = myslice[k * 136 + c];
                hi[k] = myslice[(k + 8) * 136 + c];
            }
            _Float16* dst = pT + (bi * PD_ + c) * N_ + j0;
            *(v8h*)dst = lo;
            *(v8h*)(dst + 8) = hi;
        }
        // ---- qk_pos = p @ wqk + bqk ----
        {
            v4f c = {0.f, 0.f, 0.f, 0.f};
            #pragma unroll
            for (int kt = 0; kt < 4; kt++) {
                v8h av = *(const v8h*)&myslice[l15 * 136 + kt * 32 + quad * 8];
                v8h wq = *(const v8h*)&wqT[l15 * 136 + kt * 32 + quad * 8];
                c = MFMA16(av, wq, c);
            }
            if (l15 < 4) {
                #pragma unroll
                for (int rg2 = 0; rg2 < 4; rg2++) {
                    int row = quad * 4 + rg2;
                    qkpos[(long)(P0w + row) * 4 + l15] = c[rg2] + bq;
                }
            }
        }
    }
}

// ---------- K2b: qk = q @ k^T via MFMA, accumulated into qkpos ----------
__global__ __launch_bounds__(64) void eq_k2b(
    const _Float16* __restrict__ qh, const _Float16* __restrict__ kh,
    float* __restrict__ qkpos) {
    const int blk = blockIdx.x;
    const int bh = blk / 48;
    const int rest = blk - bh * 48;
    const int it = rest >> 1, nh = rest & 1;
    const int b = bh >> 2, h = bh & 3;
    const int i0 = it * 16;
    const int t = threadIdx.x;
    const int l15 = t & 15, quad = t >> 4;

    v8h A0 = *(const v8h*)&qh[((long)(bh * N_) + i0 + l15) * DH_ + quad * 8];
    v8h A1 = *(const v8h*)&qh[((long)(bh * N_) + i0 + l15) * DH_ + 32 + quad * 8];
    #pragma unroll 1
    for (int nt = 0; nt < 12; nt++) {
        int j0 = nh * 192 + nt * 16;
        v8h B0 = *(const v8h*)&kh[((long)(bh * N_) + j0 + l15) * DH_ + quad * 8];
        v8h B1 = *(const v8h*)&kh[((long)(bh * N_) + j0 + l15) * DH_ + 32 + quad * 8];
        v4f c = {0.f, 0.f, 0.f, 0.f};
        c = MFMA16(A0, B0, c);
        c = MFMA16(A1, B1, c);
        #pragma unroll
        for (int rg2 = 0; rg2 < 4; rg2++) {
            int i = i0 + quad * 4 + rg2;
            int j = j0 + l15;
            long idx = (((long)(b * N_ + i)) * N_ + j) * 4 + h;
            qkpos[idx] += c[rg2];
        }
    }
}

// ---------- K3M: fused edge-MLP/softmax/coor-branch/ap(MFMA)/attn@v/out-proj ----------
__global__ __launch_bounds__(384) void eq_k3m(
    const float* __restrict__ edges, const float* __restrict__ qkpos,
    const _Float16* __restrict__ pT, const float* __restrict__ v,
    const float* __restrict__ coors,
    const float* __restrict__ w_e1, const float* __restrict__ w_e2,
    const float* __restrict__ w_c, const float* __restrict__ w_cg,
    const float* __restrict__ b_cg, const float* __restrict__ w_th,
    const float* __restrict__ cscale, const float* __restrict__ ccomb,
    const float* __restrict__ og, const float* __restrict__ rg,
    const float* __restrict__ w_vpos, const float* __restrict__ b_vpos,
    const float* __restrict__ w_out, const float* __restrict__ b_out,
    float* __restrict__ out0, float* __restrict__ out1) {
    int row = blockIdx.x;           // b*N + i
    int b = row / N_, i = row - b * N_;
    int j = threadIdx.x;            // 0..383
    __shared__ float we1[20 * 40];
    __shared__ float we2[40 * 4];
    __shared__ float wcs[16], wcgs[16], bcgs[4], wths[16];
    __shared__ float attnS[4 * N_];
    __shared__ float apS[2 * 4 * PD_];
    __shared__ float nodeS[256];
    __shared__ float4 red4[16];

    for (int idx = j; idx < 800; idx += 384) we1[idx] = w_e1[idx];
    if (j < 160) we2[j] = w_e2[j];
    if (j < 16) { wcs[j] = w_c[j]; wcgs[j] = w_cg[j]; wths[j] = w_th[j]; }
    if (j < 4) bcgs[j] = b_cg[j];
    __syncthreads();

    // ---- phase A: scores (qk + pos, precomputed) + edge MLP ----
    long pair = ((long)row) * N_ + j;
    float in20[20];
    {
        float4 qp = *(const float4*)(qkpos + pair * 4);
        in20[0] = qp.x; in20[1] = qp.y; in20[2] = qp.z; in20[3] = qp.w;
    }
    const float4* ep = (const float4*)(edges + pair * ED_);
    float4 e0 = ep[0], e1 = ep[1], e2 = ep[2], e3 = ep[3];
    in20[4] = e0.x;  in20[5] = e0.y;  in20[6] = e0.z;  in20[7] = e0.w;
    in20[8] = e1.x;  in20[9] = e1.y;  in20[10] = e1.z; in20[11] = e1.w;
    in20[12] = e2.x; in20[13] = e2.y; in20[14] = e2.z; in20[15] = e2.w;
    in20[16] = e3.x; in20[17] = e3.y; in20[18] = e3.z; in20[19] = e3.w;

    float c0 = 0, c1 = 0, c2 = 0, c3 = 0;
    #pragma unroll 1
    for (int oc = 0; oc < 5; oc++) {
        float a8[8] = {0.f, 0.f, 0.f, 0.f, 0.f, 0.f, 0.f, 0.f};
        #pragma unroll
        for (int c = 0; c < 20; c++) {
            float xc = in20[c];
            float4 wa = *(const float4*)&we1[c * 40 + oc * 8];
            float4 wb = *(const float4*)&we1[c * 40 + oc * 8 + 4];
            a8[0] += xc * wa.x; a8[1] += xc * wa.y; a8[2] += xc * wa.z; a8[3] += xc * wa.w;
            a8[4] += xc * wb.x; a8[5] += xc * wb.y; a8[6] += xc * wb.z; a8[7] += xc * wb.w;
        }
        #pragma unroll
        for (int o = 0; o < 8; o++) {
            float gg = gelu_(a8[o]);
            float4 w2v = *(const float4*)&we2[(oc * 8 + o) * 4];
            c0 += gg * w2v.x; c1 += gg * w2v.y; c2 += gg * w2v.z; c3 += gg * w2v.w;
        }
    }
    float cmi[4] = {c0, c1, c2, c3};
    float gc[4], cp[4], rs[4];
    #pragma unroll
    for (int h = 0; h < 4; h++) gc[h] = gelu_(cmi[h]);
    #pragma unroll
    for (int h = 0; h < 4; h++) {
        cp[h] = gc[0] * wcs[h] + gc[1] * wcs[4 + h] + gc[2] * wcs[8 + h] + gc[3] * wcs[12 + h];
        rs[h] = cmi[0] * wcgs[h] + cmi[1] * wcgs[4 + h] + cmi[2] * wcgs[8 + h] + cmi[3] * wcgs[12 + h] + bcgs[h];
    }

    // ---- phase B: softmax over j + talking heads -> attnS ----
    float4 m4 = block_reduce4(make_float4(cmi[0], cmi[1], cmi[2], cmi[3]), true, red4, 0);
    float e[4];
    e[0] = __expf(cmi[0] - m4.x); e[1] = __expf(cmi[1] - m4.y);
    e[2] = __expf(cmi[2] - m4.z); e[3] = __expf(cmi[3] - m4.w);
    float4 l4 = block_reduce4(make_float4(e[0], e[1], e[2], e[3]), false, red4, 1);
    float sm[4] = {e[0] / l4.x, e[1] / l4.y, e[2] / l4.z, e[3] / l4.w};
    #pragma unroll
    for (int h = 0; h < 4; h++)
        attnS[h * N_ + j] = wths[h * 4 + 0] * sm[0] + wths[h * 4 + 1] * sm[1]
                          + wths[h * 4 + 2] * sm[2] + wths[h * 4 + 3] * sm[3];

    // ---- phase C: coordinate branch -> out1 ----
    float dx = coors[(b * N_ + i) * 3 + 0] - coors[(b * N_ + j) * 3 + 0];
    float dy = coors[(b * N_ + i) * 3 + 1] - coors[(b * N_ + j) * 3 + 1];
    float dz = coors[(b * N_ + i) * 3 + 2] - coors[(b * N_ + j) * 3 + 2];
    float nrm = sqrtf(dx * dx + dy * dy + dz * dz);
    float sc = cscale[0] / fmaxf(nrm, 1e-8f);
    float rx = dx * sc, ry = dy * sc, rz = dz * sc;
    float4 cm4 = block_reduce4(make_float4(cp[0], cp[1], cp[2], cp[3]), true, red4, 0);
    float ec[4];
    ec[0] = __expf(cp[0] - cm4.x); ec[1] = __expf(cp[1] - cm4.y);
    ec[2] = __expf(cp[2] - cm4.z); ec[3] = __expf(cp[3] - cm4.w);
    float4 cl4 = block_reduce4(make_float4(ec[0], ec[1], ec[2], ec[3]), false, red4, 1);
    float w[4] = {ec[0] / cl4.x * rs[0], ec[1] / cl4.y * rs[1],
                  ec[2] / cl4.z * rs[2], ec[3] / cl4.w * rs[3]};
    float4 sx4 = block_reduce4(make_float4(w[0] * rx, w[1] * rx, w[2] * rx, w[3] * rx), false, red4, 0);
    float4 sy4 = block_reduce4(make_float4(w[0] * ry, w[1] * ry, w[2] * ry, w[3] * ry), false, red4, 1);
    float4 sz4 = block_reduce4(make_float4(w[0] * rz, w[1] * rz, w[2] * rz, w[3] * rz), false, red4, 0);
    if (j == 0) {
        float f0 = ccomb[0] * rg[(b * H_ + 0) * N_ + i];
        float f1 = ccomb[1] * rg[(b * H_ + 1) * N_ + i];
        float f2 = ccomb[2] * rg[(b * H_ + 2) * N_ + i];
        float f3 = ccomb[3] * rg[(b * H_ + 3) * N_ + i];
        out1[(b * N_ + i) * 3 + 0] = f0 * sx4.x + f1 * sx4.y + f2 * sx4.z + f3 * sx4.w;
        out1[(b * N_ + i) * 3 + 1] = f0 * sy4.x + f1 * sy4.y + f2 * sy4.z + f3 * sy4.w;
        out1[(b * N_ + i) * 3 + 2] = f0 * sz4.x + f1 * sz4.y + f2 * sz4.z + f3 * sz4.w;
    }
    __syncthreads();

    // ---- phase D: waves 0-1 -> ap via MFMA (pT B-frags); threads 128..383 -> attn@v ----
    if (j < 128) {
        const int lane = j & 63, l15d = lane & 15, quadd = lane >> 4;
        const int parity = j >> 6;      // wave 0 or 1: kt halves
        v4f acc[8];
        #pragma unroll
        for (int nt = 0; nt < 8; nt++) { v4f z = {0.f, 0.f, 0.f, 0.f}; acc[nt] = z; }
        #pragma unroll 1
        for (int kth = 0; kth < 6; kth++) {
            int kt = parity * 6 + kth;
            v8h Af;
            #pragma unroll
            for (int jj = 0; jj < 8; jj++) {
                float av = (l15d < 4) ? attnS[l15d * N_ + kt * 32 + quadd * 8 + jj] : 0.f;
                Af[jj] = (_Float16)av;
            }
            #pragma unroll
            for (int nt = 0; nt < 8; nt++) {
                v8h Bv = *(const v8h*)&pT[((long)row * PD_ + nt * 16 + l15d) * N_ + kt * 32 + quadd * 8];
                acc[nt] = MFMA16(Af, Bv, acc[nt]);
            }
        }
        if (quadd == 0) {
            #pragma unroll
            for (int nt = 0; nt < 8; nt++)
                #pragma unroll
                for (int rg2 = 0; rg2 < 4; rg2++)
                    apS[parity * 512 + rg2 * 128 + nt * 16 + l15d] = acc[nt][rg2];
        }
    } else {
        int tt = j - 128, h = tt >> 6, d = tt & 63;
        float acc = 0;
        const float* vp = v + ((long)(b * H_ + h) * N_) * DH_ + d;
        #pragma unroll 8
        for (int jj = 0; jj < N_; jj++) acc += attnS[h * N_ + jj] * vp[(long)jj * DH_];
        nodeS[tt] = acc;
    }
    __syncthreads();

    // ---- phase E: node = (attnv + ap@w_vpos + Sh*b_vpos) * out_gate ----
    float nv = 0;
    if (j < 256) {
        int h = j >> 6, d = j & 63;
        float accp = 0;
        const float* wv = w_vpos + h * DH_ + d;
        #pragma unroll 8
        for (int c = 0; c < PD_; c++)
            accp += (apS[h * 128 + c] + apS[512 + h * 128 + c]) * wv[(long)c * (H_ * DH_)];
        float Sh = wths[h * 4 + 0] + wths[h * 4 + 1] + wths[h * 4 + 2] + wths[h * 4 + 3];
        nv = (nodeS[j] + accp + Sh * b_vpos[h * DH_ + d]) * og[(b * H_ + h) * N_ + i];
    }
    __syncthreads();
    if (j < 256) nodeS[j] = nv;
    __syncthreads();

    // ---- phase F: out0 = node @ w_out + b_out ----
    if (j < 256) {
        float acc = b_out[j];
        #pragma unroll 8
        for (int c = 0; c < 256; c++) acc += nodeS[c] * w_out[(long)c * 256 + j];
        out0[(long)row * 256 + j] = acc;
    }
}

extern "C" void kernel_launch(void* const* d_in, const int* in_sizes, int n_in,
                              void* d_out, int out_size, void* d_ws, size_t ws_size,
                              hipStream_t stream) {
    (void)in_sizes; (void)n_in; (void)out_size; (void)ws_size;
    const float* feats   = (const float*)d_in[0];
    const float* coors   = (const float*)d_in[1];
    const float* edges   = (const float*)d_in[2];
    const float* gamma   = (const float*)d_in[3];
    const float* w_qkv   = (const float*)d_in[4];
    const float* w_gate  = (const float*)d_in[5];
    const float* b_gate  = (const float*)d_in[6];
    const float* w_th    = (const float*)d_in[7];
    const float* w_e1    = (const float*)d_in[8];
    const float* w_e2    = (const float*)d_in[9];
    const float* w_c     = (const float*)d_in[10];
    const float* w_cg    = (const float*)d_in[11];
    const float* b_cg    = (const float*)d_in[12];
    const float* cscale  = (const float*)d_in[13];
    const float* ccomb   = (const float*)d_in[14];
    const float* pb_w0   = (const float*)d_in[15];
    const float* pb_b0   = (const float*)d_in[16];
    const float* pb_g0   = (const float*)d_in[17];
    const float* pb_be0  = (const float*)d_in[18];
    const float* pb_w1   = (const float*)d_in[19];
    const float* pb_b1   = (const float*)d_in[20];
    const float* pb_g1   = (const float*)d_in[21];
    const float* pb_be1  = (const float*)d_in[22];
    const float* pb_w2   = (const float*)d_in[23];
    const float* pb_b2   = (const float*)d_in[24];
    const float* pb_g2   = (const float*)d_in[25];
    const float* pb_be2  = (const float*)d_in[26];
    const float* w_qkpos = (const float*)d_in[27];
    const float* b_qkpos = (const float*)d_in[28];
    const float* w_vpos  = (const float*)d_in[29];
    const float* b_vpos  = (const float*)d_in[30];
    const float* w_out   = (const float*)d_in[31];
    const float* b_out   = (const float*)d_in[32];

    // workspace carve (bytes)
    char* ws = (char*)d_ws;
    _Float16* qh   = (_Float16*)(ws + 0);            // 393216 B
    _Float16* kh   = (_Float16*)(ws + 393216);       // 393216 B
    float* v       = (float*)(ws + 786432);          // 786432 B
    float* og      = (float*)(ws + 1572864);         // 12288 B
    float* rg      = (float*)(ws + 1585152);         // 12288 B
    float* qkpos   = (float*)(ws + 1597440);         // 4718592 B
    _Float16* pT   = (_Float16*)(ws + 6316032);      // 75497472 B

    float* out0 = (float*)d_out;
    float* out1 = out0 + (long)B_ * N_ * DIM_;

    const int K2_LDS = 112384;
    hipFuncSetAttribute((const void*)eq_k2, hipFuncAttributeMaxDynamicSharedMemorySize, K2_LDS);

    eq_k1<<<192, 256, 0, stream>>>(feats, gamma, w_qkv, w_gate, b_gate, qh, kh, v, og, rg);
    eq_k2<<<256, 512, K2_LDS, stream>>>(coors, pb_w0, pb_b0, pb_g0, pb_be0,
                                        pb_w1, pb_b1, pb_g1, pb_be1,
                                        pb_w2, pb_b2, pb_g2, pb_be2,
                                        w_qkpos, b_qkpos, pT, qkpos);
    eq_k2b<<<384, 64, 0, stream>>>(qh, kh, qkpos);
    eq_k3m<<<B_ * N_, 384, 0, stream>>>(edges, qkpos, pT, v, coors,
                                        w_e1, w_e2, w_c, w_cg, b_cg, w_th,
                                        cscale, ccomb, og, rg,
                                        w_vpos, b_vpos, w_out, b_out, out0, out1);
}

// Round 9
// 393.020 us; speedup vs baseline: 2.9290x; 1.0057x over previous
//
#include <hip/hip_runtime.h>
#include <hip/hip_bf16.h>

#define B_   2
#define N_   384
#define DIM_ 256
#define H_   4
#define DH_  64
#define PD_  128
#define ED_  16
#define NU2_ ((B_ * N_ * N_) / 16)   // 18432 wave-units (16 pairs each)

typedef _Float16 v8h __attribute__((ext_vector_type(8)));
typedef float    v4f __attribute__((ext_vector_type(4)));

// fast erf: Abramowitz-Stegun 7.1.26, |err| <= 1.5e-7
__device__ __forceinline__ float erf_fast(float x) {
    float ax = fabsf(x);
    float t = 1.0f / fmaf(0.3275911f, ax, 1.0f);
    float y = t * fmaf(t, fmaf(t, fmaf(t, fmaf(t, 1.061405429f, -1.453152027f),
                                       1.421413741f), -0.284496736f), 0.254829592f);
    float r = 1.0f - y * __expf(-ax * ax);
    return (x < 0.f) ? -r : r;
}
__device__ __forceinline__ float gelu_(float x) {
    return 0.5f * x * (1.0f + erf_fast(x * 0.70710678118654752f));
}

// batched float4 block reduction over 256 threads (4 waves)
__device__ __forceinline__ float4 block_reduce256_f4(float4 v, float4* red) {
    #pragma unroll
    for (int o = 32; o > 0; o >>= 1) {
        v.x += __shfl_xor(v.x, o); v.y += __shfl_xor(v.y, o);
        v.z += __shfl_xor(v.z, o); v.w += __shfl_xor(v.w, o);
    }
    __syncthreads();
    if ((threadIdx.x & 63) == 0) red[threadIdx.x >> 6] = v;
    __syncthreads();
    float4 r = red[0];
    #pragma unroll
    for (int w2 = 1; w2 < 4; w2++) {
        float4 o = red[w2];
        r.x += o.x; r.y += o.y; r.z += o.z; r.w += o.w;
    }
    return r;
}

// batched float4 block reduction over 384 threads (6 waves).
__device__ __forceinline__ float4 block_reduce4(float4 v, bool ismax, float4* red, int slot) {
    #pragma unroll
    for (int o = 32; o > 0; o >>= 1) {
        float x = __shfl_xor(v.x, o), y = __shfl_xor(v.y, o);
        float z = __shfl_xor(v.z, o), w = __shfl_xor(v.w, o);
        if (ismax) { v.x = fmaxf(v.x, x); v.y = fmaxf(v.y, y); v.z = fmaxf(v.z, z); v.w = fmaxf(v.w, w); }
        else       { v.x += x; v.y += y; v.z += z; v.w += w; }
    }
    if ((threadIdx.x & 63) == 0) red[slot * 8 + (threadIdx.x >> 6)] = v;
    __syncthreads();
    float4 r = red[slot * 8];
    #pragma unroll
    for (int w2 = 1; w2 < 6; w2++) {
        float4 o = red[slot * 8 + w2];
        if (ismax) { r.x = fmaxf(r.x, o.x); r.y = fmaxf(r.y, o.y); r.z = fmaxf(r.z, o.z); r.w = fmaxf(r.w, o.w); }
        else       { r.x += o.x; r.y += o.y; r.z += o.z; r.w += o.w; }
    }
    return r;
}

// ---------- K1: LayerNorm + QKV (4 rows/block, f16 q/k out) + gates ----------
__global__ __launch_bounds__(256) void eq_k1(
    const float* __restrict__ feats, const float* __restrict__ gamma,
    const float* __restrict__ w_qkv, const float* __restrict__ w_gate,
    const float* __restrict__ b_gate,
    _Float16* __restrict__ qh, _Float16* __restrict__ kh, float* __restrict__ v,
    float* __restrict__ og, float* __restrict__ rg) {
    const int r0 = blockIdx.x * 4;
    const int b = r0 / N_;
    const int t = threadIdx.x;
    __shared__ float xs[4][DIM_];
    __shared__ float4 red4k[4];
    float4 f;
    f.x = feats[(long)(r0 + 0) * DIM_ + t];
    f.y = feats[(long)(r0 + 1) * DIM_ + t];
    f.z = feats[(long)(r0 + 2) * DIM_ + t];
    f.w = feats[(long)(r0 + 3) * DIM_ + t];
    float4 s = block_reduce256_f4(f, red4k);
    float4 mean = make_float4(s.x * (1.f/DIM_), s.y * (1.f/DIM_), s.z * (1.f/DIM_), s.w * (1.f/DIM_));
    float4 d = make_float4(f.x - mean.x, f.y - mean.y, f.z - mean.z, f.w - mean.w);
    float4 vr = block_reduce256_f4(make_float4(d.x*d.x, d.y*d.y, d.z*d.z, d.w*d.w), red4k);
    float g = gamma[t];
    xs[0][t] = d.x * rsqrtf(vr.x * (1.f/DIM_) + 1e-5f) * g;
    xs[1][t] = d.y * rsqrtf(vr.y * (1.f/DIM_) + 1e-5f) * g;
    xs[2][t] = d.z * rsqrtf(vr.z * (1.f/DIM_) + 1e-5f) * g;
    xs[3][t] = d.w * rsqrtf(vr.w * (1.f/DIM_) + 1e-5f) * g;
    __syncthreads();
    float acc[12];
    #pragma unroll
    for (int k = 0; k < 12; k++) acc[k] = 0.f;
    for (int c = 0; c < DIM_; c++) {
        const float* wr = w_qkv + (long)c * 768;
        float w0 = wr[t], w1 = wr[t + 256], w2 = wr[t + 512];
        #pragma unroll
        for (int r = 0; r < 4; r++) {
            float xc = xs[r][c];
            acc[r * 3 + 0] += xc * w0;
            acc[r * 3 + 1] += xc * w1;
            acc[r * 3 + 2] += xc * w2;
        }
    }
    int h = t >> 6, dd = t & 63;
    #pragma unroll
    for (int r = 0; r < 4; r++) {
        int n = r0 + r - b * N_;
        long idx = ((long)(b * H_ + h) * N_ + n) * DH_ + dd;
        qh[idx] = (_Float16)(acc[r * 3 + 0] * 0.125f);     // dh^-0.5 pre-applied
        kh[idx] = (_Float16)(acc[r * 3 + 1]);
        v[idx]  = acc[r * 3 + 2];
    }
    if (t < 32) {
        int rr = t >> 3, gg = t & 7;
        float a = b_gate[gg];
        for (int c = 0; c < DIM_; c++) a += xs[rr][c] * w_gate[c * 8 + gg];
        float gv = 1.0f / (1.0f + __expf(-a));
        int n = r0 + rr - b * N_;
        if (gg < 4) og[(b * H_ + gg) * N_ + n] = gv;
        else        rg[(b * H_ + (gg - 4)) * N_ + n] = gv;
    }
}

// ---------- K2: position-bias MLP, wave-independent MFMA (unchanged from R8) ----------
#define MFMA16(a, b, c) __builtin_amdgcn_mfma_f32_16x16x32_f16(a, b, c, 0, 0, 0)

#define LNAPPLY(GOFF_, BOFF_)                                                     \
{                                                                                  \
    float gv[8], bev[8];                                                           \
    _Pragma("unroll")                                                              \
    for (int nt = 0; nt < 8; nt++) {                                               \
        gv[nt]  = GB[(GOFF_) + nt * 16 + l15];                                     \
        bev[nt] = GB[(BOFF_) + nt * 16 + l15];                                     \
    }                                                                              \
    _Pragma("unroll")                                                              \
    for (int rg2 = 0; rg2 < 4; rg2++) {                                            \
        float s = 0.f, sq = 0.f;                                                   \
        _Pragma("unroll")                                                          \
        for (int nt = 0; nt < 8; nt++) {                                           \
            float v0 = acc[nt][rg2]; s += v0; sq += v0 * v0;                       \
        }                                                                          \
        s += __shfl_xor(s, 1); sq += __shfl_xor(sq, 1);                            \
        s += __shfl_xor(s, 2); sq += __shfl_xor(sq, 2);                            \
        s += __shfl_xor(s, 4); sq += __shfl_xor(sq, 4);                            \
        s += __shfl_xor(s, 8); sq += __shfl_xor(sq, 8);                            \
        float mean = s * (1.f / 128.f);                                            \
        float inv = rsqrtf(sq * (1.f / 128.f) - mean * mean + 1e-5f);              \
        int row2 = quad * 4 + rg2;                                                 \
        _Pragma("unroll")                                                          \
        for (int nt = 0; nt < 8; nt++) {                                           \
            float y = (acc[nt][rg2] - mean) * inv * gv[nt] + bev[nt];              \
            y = y / (1.f + __expf(-y));                                            \
            myslice[row2 * 136 + nt * 16 + l15] = (_Float16)y;                     \
        }                                                                          \
    }                                                                              \
}

__global__ __launch_bounds__(512) __attribute__((amdgpu_waves_per_eu(2, 2)))
void eq_k2(
    const float* __restrict__ coors,
    const float* __restrict__ w0, const float* __restrict__ b0,
    const float* __restrict__ g0, const float* __restrict__ be0,
    const float* __restrict__ W1g, const float* __restrict__ b1,
    const float* __restrict__ g1, const float* __restrict__ be1,
    const float* __restrict__ W2g, const float* __restrict__ b2,
    const float* __restrict__ g2, const float* __restrict__ be2,
    const float* __restrict__ wqk, const float* __restrict__ bqk,
    _Float16* __restrict__ pT, float* __restrict__ qkpos) {

    extern __shared__ char smem[];
    _Float16* W1T    = (_Float16*)smem;                   // 128x136 = 34816 B
    _Float16* W2T    = (_Float16*)(smem + 34816);         // 34816 B
    _Float16* slices = (_Float16*)(smem + 69632);         // 8 x 16x136 = 34816 B
    _Float16* wqT    = (_Float16*)(smem + 104448);        // 16x136 = 4352 B
    float*    PQR    = (float*)(smem + 108800);           // 1536 B
    float*    GB     = (float*)(smem + 110336);           // 2048 B

    const int t = threadIdx.x;
    const int lane = t & 63, wv = t >> 6;
    const int l15 = lane & 15, quad = lane >> 4;
    _Float16* myslice = slices + wv * (16 * 136);

    for (int idx = t; idx < 16384; idx += 512) {
        int k = idx >> 7, n = idx & 127;
        W1T[n * 136 + k] = (_Float16)W1g[idx];
        W2T[n * 136 + k] = (_Float16)W2g[idx];
    }
    for (int idx = t; idx < 2048; idx += 512) {
        int n = idx >> 7, k = idx & 127;
        wqT[n * 136 + k] = (n < 4) ? (_Float16)wqk[k * 4 + n] : (_Float16)0.f;
    }
    float Sw = 0, Sb = 0, Sww = 0, Swb = 0, Sbb = 0;
    for (int c = 0; c < 128; c++) {
        float w = w0[c], bb2v = b0[c];
        Sw += w; Sb += bb2v; Sww += w * w; Swb += w * bb2v; Sbb += bb2v * bb2v;
    }
    const float mw = Sw * (1.f / 128.f), mbb = Sb * (1.f / 128.f);
    const float A2 = Sww * (1.f / 128.f) - mw * mw;
    const float AD = Swb * (1.f / 128.f) - mw * mbb;
    const float D2 = Sbb * (1.f / 128.f) - mbb * mbb;
    if (t < 128) {
        PQR[t]       = (w0[t] - mw) * g0[t];
        PQR[128 + t] = (b0[t] - mbb) * g0[t];
        PQR[256 + t] = be0[t];
        GB[t]        = g1[t];
        GB[128 + t]  = be1[t];
        GB[256 + t]  = g2[t];
        GB[384 + t]  = be2[t];
    }
    float b1r[8], b2r[8];
    #pragma unroll
    for (int nt = 0; nt < 8; nt++) {
        int c = nt * 16 + l15;
        b1r[nt] = b1[c]; b2r[nt] = b2[c];
    }
    const float bq = (l15 < 4) ? bqk[l15] : 0.f;
    __syncthreads();

    for (int unit = blockIdx.x * 8 + wv; unit < NU2_; unit += 256 * 8) {
        const int P0w = unit * 16;
        const int b = P0w / (N_ * N_);
        const int rem = P0w - b * (N_ * N_);
        const int ii = rem / N_;
        const int j0 = rem - ii * N_;
        const long bi = (long)(b * N_ + ii);
        const float cix = coors[(b * N_ + ii) * 3 + 0];
        const float ciy = coors[(b * N_ + ii) * 3 + 1];
        const float ciz = coors[(b * N_ + ii) * 3 + 2];
        float tt, uu;
        {
            int j = j0 + l15;
            float dx = cix - coors[(b * N_ + j) * 3 + 0];
            float dy = ciy - coors[(b * N_ + j) * 3 + 1];
            float dz = ciz - coors[(b * N_ + j) * 3 + 2];
            float d = sqrtf(dx * dx + dy * dy + dz * dz);
            float var = (d * d) * A2 + 2.f * d * AD + D2;
            float inv = rsqrtf(var + 1e-5f);
            tt = d * inv; uu = inv;
        }
        v8h A[4];
        #pragma unroll
        for (int kt = 0; kt < 4; kt++) {
            int base = kt * 32 + quad * 8;
            v8h av;
            #pragma unroll
            for (int jj = 0; jj < 8; jj++) {
                float y = tt * PQR[base + jj] + uu * PQR[128 + base + jj] + PQR[256 + base + jj];
                av[jj] = (_Float16)(y / (1.f + __expf(-y)));
            }
            A[kt] = av;
        }
        v4f acc[8];
        #pragma unroll
        for (int nt = 0; nt < 8; nt++) {
            v4f ci = {b1r[nt], b1r[nt], b1r[nt], b1r[nt]};
            acc[nt] = ci;
        }
        #pragma unroll
        for (int kt = 0; kt < 4; kt++) {
            #pragma unroll
            for (int nt = 0; nt < 8; nt++) {
                v8h Bv = *(const v8h*)&W1T[(nt * 16 + l15) * 136 + kt * 32 + quad * 8];
                acc[nt] = MFMA16(A[kt], Bv, acc[nt]);
            }
        }
        LNAPPLY(0, 128)
        #pragma unroll
        for (int kt = 0; kt < 4; kt++)
            A[kt] = *(const v8h*)&myslice[l15 * 136 + kt * 32 + quad * 8];
        #pragma unroll
        for (int nt = 0; nt < 8; nt++) {
            v4f ci = {b2r[nt], b2r[nt], b2r[nt], b2r[nt]};
            acc[nt] = ci;
        }
        #pragma unroll
        for (int kt = 0; kt < 4; kt++) {
            #pragma unroll
            for (int nt = 0; nt < 8; nt++) {
                v8h Bv = *(const v8h*)&W2T[(nt * 16 + l15) * 136 + kt * 32 + quad * 8];
                acc[nt] = MFMA16(A[kt], Bv, acc[nt]);
            }
        }
        LNAPPLY(256, 384)
        #pragma unroll
        for (int cc = 0; cc < 2; cc++) {
            int c = lane + cc * 64;
            v8h lo, hi;
            #pragma unroll
            for (int k = 0; k < 8; k++) {
                lo[k] = myslice[k * 136 + c];
                hi[k] = myslice[(k + 8) * 136 + c];
            }
            _Float16* dst = pT + (bi * PD_ + c) * N_ + j0;
            *(v8h*)dst = lo;
            *(v8h*)(dst + 8) = hi;
        }
        {
            v4f c = {0.f, 0.f, 0.f, 0.f};
            #pragma unroll
            for (int kt = 0; kt < 4; kt++) {
                v8h av = *(const v8h*)&myslice[l15 * 136 + kt * 32 + quad * 8];
                v8h wq = *(const v8h*)&wqT[l15 * 136 + kt * 32 + quad * 8];
                c = MFMA16(av, wq, c);
            }
            if (l15 < 4) {
                #pragma unroll
                for (int rg2 = 0; rg2 < 4; rg2++) {
                    int row = quad * 4 + rg2;
                    qkpos[(long)(P0w + row) * 4 + l15] = c[rg2] + bq;
                }
            }
        }
    }
}

// ---------- K2b: qk = q @ k^T via MFMA -> own buffer (no RMW) ----------
__global__ __launch_bounds__(64) void eq_k2b(
    const _Float16* __restrict__ qh, const _Float16* __restrict__ kh,
    float* __restrict__ qkq) {
    const int blk = blockIdx.x;
    const int bh = blk / 48;
    const int rest = blk - bh * 48;
    const int it = rest >> 1, nh = rest & 1;
    const int b = bh >> 2, h = bh & 3;
    const int i0 = it * 16;
    const int t = threadIdx.x;
    const int l15 = t & 15, quad = t >> 4;

    v8h A0 = *(const v8h*)&qh[((long)(bh * N_) + i0 + l15) * DH_ + quad * 8];
    v8h A1 = *(const v8h*)&qh[((long)(bh * N_) + i0 + l15) * DH_ + 32 + quad * 8];
    #pragma unroll 1
    for (int nt = 0; nt < 12; nt++) {
        int j0 = nh * 192 + nt * 16;
        v8h B0 = *(const v8h*)&kh[((long)(bh * N_) + j0 + l15) * DH_ + quad * 8];
        v8h B1 = *(const v8h*)&kh[((long)(bh * N_) + j0 + l15) * DH_ + 32 + quad * 8];
        v4f c = {0.f, 0.f, 0.f, 0.f};
        c = MFMA16(A0, B0, c);
        c = MFMA16(A1, B1, c);
        #pragma unroll
        for (int rg2 = 0; rg2 < 4; rg2++) {
            int i = i0 + quad * 4 + rg2;
            int j = j0 + l15;
            long idx = (((long)(b * N_ + i)) * N_ + j) * 4 + h;
            qkq[idx] = c[rg2];          // plain store, no RMW
        }
    }
}

// ---------- K3M: fused edge-MLP/softmax/coor-branch/ap(MFMA)/attn@v/out-proj ----------
__global__ __launch_bounds__(384) void eq_k3m(
    const float* __restrict__ edges, const float* __restrict__ qkpos,
    const float* __restrict__ qkq,
    const _Float16* __restrict__ pT, const float* __restrict__ v,
    const float* __restrict__ coors,
    const float* __restrict__ w_e1, const float* __restrict__ w_e2,
    const float* __restrict__ w_c, const float* __restrict__ w_cg,
    const float* __restrict__ b_cg, const float* __restrict__ w_th,
    const float* __restrict__ cscale, const float* __restrict__ ccomb,
    const float* __restrict__ og, const float* __restrict__ rg,
    const float* __restrict__ w_vpos, const float* __restrict__ b_vpos,
    const float* __restrict__ w_out, const float* __restrict__ b_out,
    float* __restrict__ out0, float* __restrict__ out1) {
    int row = blockIdx.x;           // b*N + i
    int b = row / N_, i = row - b * N_;
    int j = threadIdx.x;            // 0..383
    __shared__ float we1[20 * 40];
    __shared__ float we2[40 * 4];
    __shared__ float wcs[16], wcgs[16], bcgs[4], wths[16];
    __shared__ float attnS[4 * N_];
    __shared__ float apS[2 * 4 * PD_];
    __shared__ float nodeS[256];
    __shared__ float4 red4[34];     // [0..15] reduce slots, [16..33] reduce12

    for (int idx = j; idx < 800; idx += 384) we1[idx] = w_e1[idx];
    if (j < 160) we2[j] = w_e2[j];
    if (j < 16) { wcs[j] = w_c[j]; wcgs[j] = w_cg[j]; wths[j] = w_th[j]; }
    if (j < 4) bcgs[j] = b_cg[j];
    __syncthreads();

    // ---- phase A: scores (pos + qk) + edge MLP ----
    long pair = ((long)row) * N_ + j;
    float in20[20];
    {
        float4 qp = *(const float4*)(qkpos + pair * 4);
        float4 qq = *(const float4*)(qkq + pair * 4);
        in20[0] = qp.x + qq.x; in20[1] = qp.y + qq.y;
        in20[2] = qp.z + qq.z; in20[3] = qp.w + qq.w;
    }
    const float4* ep = (const float4*)(edges + pair * ED_);
    float4 e0 = ep[0], e1 = ep[1], e2 = ep[2], e3 = ep[3];
    in20[4] = e0.x;  in20[5] = e0.y;  in20[6] = e0.z;  in20[7] = e0.w;
    in20[8] = e1.x;  in20[9] = e1.y;  in20[10] = e1.z; in20[11] = e1.w;
    in20[12] = e2.x; in20[13] = e2.y; in20[14] = e2.z; in20[15] = e2.w;
    in20[16] = e3.x; in20[17] = e3.y; in20[18] = e3.z; in20[19] = e3.w;

    float c0 = 0, c1 = 0, c2 = 0, c3 = 0;
    #pragma unroll 1
    for (int oc = 0; oc < 5; oc++) {
        float a8[8] = {0.f, 0.f, 0.f, 0.f, 0.f, 0.f, 0.f, 0.f};
        #pragma unroll
        for (int c = 0; c < 20; c++) {
            float xc = in20[c];
            float4 wa = *(const float4*)&we1[c * 40 + oc * 8];
            float4 wb = *(const float4*)&we1[c * 40 + oc * 8 + 4];
            a8[0] += xc * wa.x; a8[1] += xc * wa.y; a8[2] += xc * wa.z; a8[3] += xc * wa.w;
            a8[4] += xc * wb.x; a8[5] += xc * wb.y; a8[6] += xc * wb.z; a8[7] += xc * wb.w;
        }
        #pragma unroll
        for (int o = 0; o < 8; o++) {
            float gg = gelu_(a8[o]);
            float4 w2v = *(const float4*)&we2[(oc * 8 + o) * 4];
            c0 += gg * w2v.x; c1 += gg * w2v.y; c2 += gg * w2v.z; c3 += gg * w2v.w;
        }
    }
    float cmi[4] = {c0, c1, c2, c3};
    float gc[4], cp[4], rs[4];
    #pragma unroll
    for (int h = 0; h < 4; h++) gc[h] = gelu_(cmi[h]);
    #pragma unroll
    for (int h = 0; h < 4; h++) {
        cp[h] = gc[0] * wcs[h] + gc[1] * wcs[4 + h] + gc[2] * wcs[8 + h] + gc[3] * wcs[12 + h];
        rs[h] = cmi[0] * wcgs[h] + cmi[1] * wcgs[4 + h] + cmi[2] * wcgs[8 + h] + cmi[3] * wcgs[12 + h] + bcgs[h];
    }

    // ---- phase B: softmax over j + talking heads -> attnS ----
    float4 m4 = block_reduce4(make_float4(cmi[0], cmi[1], cmi[2], cmi[3]), true, red4, 0);
    float e[4];
    e[0] = __expf(cmi[0] - m4.x); e[1] = __expf(cmi[1] - m4.y);
    e[2] = __expf(cmi[2] - m4.z); e[3] = __expf(cmi[3] - m4.w);
    float4 l4 = block_reduce4(make_float4(e[0], e[1], e[2], e[3]), false, red4, 1);
    float sm[4] = {e[0] / l4.x, e[1] / l4.y, e[2] / l4.z, e[3] / l4.w};
    #pragma unroll
    for (int h = 0; h < 4; h++)
        attnS[h * N_ + j] = wths[h * 4 + 0] * sm[0] + wths[h * 4 + 1] * sm[1]
                          + wths[h * 4 + 2] * sm[2] + wths[h * 4 + 3] * sm[3];

    // ---- phase C: coordinate branch -> out1 ----
    float dx = coors[(b * N_ + i) * 3 + 0] - coors[(b * N_ + j) * 3 + 0];
    float dy = coors[(b * N_ + i) * 3 + 1] - coors[(b * N_ + j) * 3 + 1];
    float dz = coors[(b * N_ + i) * 3 + 2] - coors[(b * N_ + j) * 3 + 2];
    float nrm = sqrtf(dx * dx + dy * dy + dz * dz);
    float sc = cscale[0] / fmaxf(nrm, 1e-8f);
    float rx = dx * sc, ry = dy * sc, rz = dz * sc;
    float4 cm4 = block_reduce4(make_float4(cp[0], cp[1], cp[2], cp[3]), true, red4, 0);
    float ec[4];
    ec[0] = __expf(cp[0] - cm4.x); ec[1] = __expf(cp[1] - cm4.y);
    ec[2] = __expf(cp[2] - cm4.z); ec[3] = __expf(cp[3] - cm4.w);
    float4 cl4 = block_reduce4(make_float4(ec[0], ec[1], ec[2], ec[3]), false, red4, 1);
    float w[4] = {ec[0] / cl4.x * rs[0], ec[1] / cl4.y * rs[1],
                  ec[2] / cl4.z * rs[2], ec[3] / cl4.w * rs[3]};
    // 12-value butterfly + ONE barrier (also serves as attnS-ready barrier)
    float rv[12];
    #pragma unroll
    for (int h = 0; h < 4; h++) { rv[h] = w[h] * rx; rv[4 + h] = w[h] * ry; rv[8 + h] = w[h] * rz; }
    #pragma unroll
    for (int o = 32; o > 0; o >>= 1) {
        #pragma unroll
        for (int k = 0; k < 12; k++) rv[k] += __shfl_xor(rv[k], o);
    }
    if ((j & 63) == 0) {
        int wid = j >> 6;
        red4[16 + wid * 3 + 0] = make_float4(rv[0], rv[1], rv[2], rv[3]);
        red4[16 + wid * 3 + 1] = make_float4(rv[4], rv[5], rv[6], rv[7]);
        red4[16 + wid * 3 + 2] = make_float4(rv[8], rv[9], rv[10], rv[11]);
    }
    __syncthreads();    // attnS + reduce12 ready
    if (j == 0) {
        float4 sx4 = red4[16], sy4 = red4[17], sz4 = red4[18];
        #pragma unroll
        for (int w2 = 1; w2 < 6; w2++) {
            float4 ax = red4[16 + w2 * 3 + 0], ay = red4[16 + w2 * 3 + 1], az = red4[16 + w2 * 3 + 2];
            sx4.x += ax.x; sx4.y += ax.y; sx4.z += ax.z; sx4.w += ax.w;
            sy4.x += ay.x; sy4.y += ay.y; sy4.z += ay.z; sy4.w += ay.w;
            sz4.x += az.x; sz4.y += az.y; sz4.z += az.z; sz4.w += az.w;
        }
        float f0 = ccomb[0] * rg[(b * H_ + 0) * N_ + i];
        float f1 = ccomb[1] * rg[(b * H_ + 1) * N_ + i];
        float f2 = ccomb[2] * rg[(b * H_ + 2) * N_ + i];
        float f3 = ccomb[3] * rg[(b * H_ + 3) * N_ + i];
        out1[(b * N_ + i) * 3 + 0] = f0 * sx4.x + f1 * sx4.y + f2 * sx4.z + f3 * sx4.w;
        out1[(b * N_ + i) * 3 + 1] = f0 * sy4.x + f1 * sy4.y + f2 * sy4.z + f3 * sy4.w;
        out1[(b * N_ + i) * 3 + 2] = f0 * sz4.x + f1 * sz4.y + f2 * sz4.z + f3 * sz4.w;
    }

    // ---- phase D: waves 0-1 -> ap via MFMA; threads 128..383 -> attn@v ----
    if (j < 128) {
        const int lane = j & 63, l15d = lane & 15, quadd = lane >> 4;
        const int parity = j >> 6;
        const int hh = l15d & 3;
        const float msk = (l15d < 4) ? 1.f : 0.f;
        v4f acc[8];
        #pragma unroll
        for (int nt = 0; nt < 8; nt++) { v4f z = {0.f, 0.f, 0.f, 0.f}; acc[nt] = z; }
        #pragma unroll 2
        for (int kth = 0; kth < 6; kth++) {
            int kt = parity * 6 + kth;
            float4 a0 = *(const float4*)&attnS[hh * N_ + kt * 32 + quadd * 8];
            float4 a1 = *(const float4*)&attnS[hh * N_ + kt * 32 + quadd * 8 + 4];
            v8h Af;
            Af[0] = (_Float16)(a0.x * msk); Af[1] = (_Float16)(a0.y * msk);
            Af[2] = (_Float16)(a0.z * msk); Af[3] = (_Float16)(a0.w * msk);
            Af[4] = (_Float16)(a1.x * msk); Af[5] = (_Float16)(a1.y * msk);
            Af[6] = (_Float16)(a1.z * msk); Af[7] = (_Float16)(a1.w * msk);
            #pragma unroll
            for (int nt = 0; nt < 8; nt++) {
                v8h Bv = *(const v8h*)&pT[((long)row * PD_ + nt * 16 + l15d) * N_ + kt * 32 + quadd * 8];
                acc[nt] = MFMA16(Af, Bv, acc[nt]);
            }
        }
        if (quadd == 0) {
            #pragma unroll
            for (int nt = 0; nt < 8; nt++)
                #pragma unroll
                for (int rg2 = 0; rg2 < 4; rg2++)
                    apS[parity * 512 + rg2 * 128 + nt * 16 + l15d] = acc[nt][rg2];
        }
    } else {
        int tt = j - 128, h = tt >> 6, d = tt & 63;
        float acc = 0;
        const float* vp = v + ((long)(b * H_ + h) * N_) * DH_ + d;
        #pragma unroll 8
        for (int jj = 0; jj < N_; jj++) acc += attnS[h * N_ + jj] * vp[(long)jj * DH_];
        nodeS[tt] = acc;
    }
    __syncthreads();

    // ---- phase E: node = (attnv + ap@w_vpos + Sh*b_vpos) * out_gate ----
    float nv = 0;
    if (j < 256) {
        int h = j >> 6, d = j & 63;
        float accp = 0;
        const float* wv = w_vpos + h * DH_ + d;
        #pragma unroll 8
        for (int c = 0; c < PD_; c++)
            accp += (apS[h * 128 + c] + apS[512 + h * 128 + c]) * wv[(long)c * (H_ * DH_)];
        float Sh = wths[h * 4 + 0] + wths[h * 4 + 1] + wths[h * 4 + 2] + wths[h * 4 + 3];
        nv = (nodeS[j] + accp + Sh * b_vpos[h * DH_ + d]) * og[(b * H_ + h) * N_ + i];
    }
    __syncthreads();
    if (j < 256) nodeS[j] = nv;
    __syncthreads();

    // ---- phase F: out0 = node @ w_out + b_out (float4 nodeS, pipelined) ----
    if (j < 256) {
        float acc = b_out[j];
        const float* wo = w_out + j;
        #pragma unroll 4
        for (int c4 = 0; c4 < 64; c4++) {
            float4 nv4 = *(const float4*)&nodeS[c4 * 4];
            acc += nv4.x * wo[(long)(c4 * 4 + 0) * 256]
                 + nv4.y * wo[(long)(c4 * 4 + 1) * 256]
                 + nv4.z * wo[(long)(c4 * 4 + 2) * 256]
                 + nv4.w * wo[(long)(c4 * 4 + 3) * 256];
        }
        out0[(long)row * 256 + j] = acc;
    }
}

extern "C" void kernel_launch(void* const* d_in, const int* in_sizes, int n_in,
                              void* d_out, int out_size, void* d_ws, size_t ws_size,
                              hipStream_t stream) {
    (void)in_sizes; (void)n_in; (void)out_size; (void)ws_size;
    const float* feats   = (const float*)d_in[0];
    const float* coors   = (const float*)d_in[1];
    const float* edges   = (const float*)d_in[2];
    const float* gamma   = (const float*)d_in[3];
    const float* w_qkv   = (const float*)d_in[4];
    const float* w_gate  = (const float*)d_in[5];
    const float* b_gate  = (const float*)d_in[6];
    const float* w_th    = (const float*)d_in[7];
    const float* w_e1    = (const float*)d_in[8];
    const float* w_e2    = (const float*)d_in[9];
    const float* w_c     = (const float*)d_in[10];
    const float* w_cg    = (const float*)d_in[11];
    const float* b_cg    = (const float*)d_in[12];
    const float* cscale  = (const float*)d_in[13];
    const float* ccomb   = (const float*)d_in[14];
    const float* pb_w0   = (const float*)d_in[15];
    const float* pb_b0   = (const float*)d_in[16];
    const float* pb_g0   = (const float*)d_in[17];
    const float* pb_be0  = (const float*)d_in[18];
    const float* pb_w1   = (const float*)d_in[19];
    const float* pb_b1   = (const float*)d_in[20];
    const float* pb_g1   = (const float*)d_in[21];
    const float* pb_be1  = (const float*)d_in[22];
    const float* pb_w2   = (const float*)d_in[23];
    const float* pb_b2   = (const float*)d_in[24];
    const float* pb_g2   = (const float*)d_in[25];
    const float* pb_be2  = (const float*)d_in[26];
    const float* w_qkpos = (const float*)d_in[27];
    const float* b_qkpos = (const float*)d_in[28];
    const float* w_vpos  = (const float*)d_in[29];
    const float* b_vpos  = (const float*)d_in[30];
    const float* w_out   = (const float*)d_in[31];
    const float* b_out   = (const float*)d_in[32];

    // workspace carve (bytes)
    char* ws = (char*)d_ws;
    _Float16* qh   = (_Float16*)(ws + 0);            // 393216 B
    _Float16* kh   = (_Float16*)(ws + 393216);       // 393216 B
    float* v       = (float*)(ws + 786432);          // 786432 B
    float* og      = (float*)(ws + 1572864);         // 12288 B
    float* rg      = (float*)(ws + 1585152);         // 12288 B
    float* qkpos   = (float*)(ws + 1597440);         // 4718592 B
    _Float16* pT   = (_Float16*)(ws + 6316032);      // 75497472 B
    float* qkq     = (float*)(ws + 81813504);        // 4718592 B

    float* out0 = (float*)d_out;
    float* out1 = out0 + (long)B_ * N_ * DIM_;

    const int K2_LDS = 112384;
    hipFuncSetAttribute((const void*)eq_k2, hipFuncAttributeMaxDynamicSharedMemorySize, K2_LDS);

    eq_k1<<<192, 256, 0, stream>>>(feats, gamma, w_qkv, w_gate, b_gate, qh, kh, v, og, rg);
    eq_k2<<<256, 512, K2_LDS, stream>>>(coors, pb_w0, pb_b0, pb_g0, pb_be0,
                                        pb_w1, pb_b1, pb_g1, pb_be1,
                                        pb_w2, pb_b2, pb_g2, pb_be2,
                                        w_qkpos, b_qkpos, pT, qkpos);
    eq_k2b<<<384, 64, 0, stream>>>(qh, kh, qkq);
    eq_k3m<<<B_ * N_, 384, 0, stream>>>(edges, qkpos, qkq, pT, v, coors,
                                        w_e1, w_e2, w_c, w_cg, b_cg, w_th,
                                        cscale, ccomb, og, rg,
                                        w_vpos, b_vpos, w_out, b_out, out0, out1);
}

// Round 10
// 366.459 us; speedup vs baseline: 3.1413x; 1.0725x over previous
//
#include <hip/hip_runtime.h>
#include <hip/hip_bf16.h>

#define B_   2
#define N_   384
#define DIM_ 256
#define H_   4
#define DH_  64
#define PD_  128
#define ED_  16
#define NU2_ ((B_ * N_ * N_) / 16)   // 18432 wave-units (16 pairs each)

typedef _Float16 v8h __attribute__((ext_vector_type(8)));
typedef float    v4f __attribute__((ext_vector_type(4)));

// fast erf: Abramowitz-Stegun 7.1.26, |err| <= 1.5e-7
__device__ __forceinline__ float erf_fast(float x) {
    float ax = fabsf(x);
    float t = 1.0f / fmaf(0.3275911f, ax, 1.0f);
    float y = t * fmaf(t, fmaf(t, fmaf(t, fmaf(t, 1.061405429f, -1.453152027f),
                                       1.421413741f), -0.284496736f), 0.254829592f);
    float r = 1.0f - y * __expf(-ax * ax);
    return (x < 0.f) ? -r : r;
}
__device__ __forceinline__ float gelu_(float x) {
    return 0.5f * x * (1.0f + erf_fast(x * 0.70710678118654752f));
}

// batched float4 block reduction over 256 threads (4 waves)
__device__ __forceinline__ float4 block_reduce256_f4(float4 v, float4* red) {
    #pragma unroll
    for (int o = 32; o > 0; o >>= 1) {
        v.x += __shfl_xor(v.x, o); v.y += __shfl_xor(v.y, o);
        v.z += __shfl_xor(v.z, o); v.w += __shfl_xor(v.w, o);
    }
    __syncthreads();
    if ((threadIdx.x & 63) == 0) red[threadIdx.x >> 6] = v;
    __syncthreads();
    float4 r = red[0];
    #pragma unroll
    for (int w2 = 1; w2 < 4; w2++) {
        float4 o = red[w2];
        r.x += o.x; r.y += o.y; r.z += o.z; r.w += o.w;
    }
    return r;
}

// batched float4 block reduction over 384 threads (6 waves).
__device__ __forceinline__ float4 block_reduce4(float4 v, bool ismax, float4* red, int slot) {
    #pragma unroll
    for (int o = 32; o > 0; o >>= 1) {
        float x = __shfl_xor(v.x, o), y = __shfl_xor(v.y, o);
        float z = __shfl_xor(v.z, o), w = __shfl_xor(v.w, o);
        if (ismax) { v.x = fmaxf(v.x, x); v.y = fmaxf(v.y, y); v.z = fmaxf(v.z, z); v.w = fmaxf(v.w, w); }
        else       { v.x += x; v.y += y; v.z += z; v.w += w; }
    }
    if ((threadIdx.x & 63) == 0) red[slot * 8 + (threadIdx.x >> 6)] = v;
    __syncthreads();
    float4 r = red[slot * 8];
    #pragma unroll
    for (int w2 = 1; w2 < 6; w2++) {
        float4 o = red[slot * 8 + w2];
        if (ismax) { r.x = fmaxf(r.x, o.x); r.y = fmaxf(r.y, o.y); r.z = fmaxf(r.z, o.z); r.w = fmaxf(r.w, o.w); }
        else       { r.x += o.x; r.y += o.y; r.z += o.z; r.w += o.w; }
    }
    return r;
}

// ---------- K1: LayerNorm + QKV (4 rows/block, f16 q/k out) + gates ----------
__global__ __launch_bounds__(256) void eq_k1(
    const float* __restrict__ feats, const float* __restrict__ gamma,
    const float* __restrict__ w_qkv, const float* __restrict__ w_gate,
    const float* __restrict__ b_gate,
    _Float16* __restrict__ qh, _Float16* __restrict__ kh, float* __restrict__ v,
    float* __restrict__ og, float* __restrict__ rg) {
    const int r0 = blockIdx.x * 4;
    const int b = r0 / N_;
    const int t = threadIdx.x;
    __shared__ float xs[4][DIM_];
    __shared__ float4 red4k[4];
    float4 f;
    f.x = feats[(long)(r0 + 0) * DIM_ + t];
    f.y = feats[(long)(r0 + 1) * DIM_ + t];
    f.z = feats[(long)(r0 + 2) * DIM_ + t];
    f.w = feats[(long)(r0 + 3) * DIM_ + t];
    float4 s = block_reduce256_f4(f, red4k);
    float4 mean = make_float4(s.x * (1.f/DIM_), s.y * (1.f/DIM_), s.z * (1.f/DIM_), s.w * (1.f/DIM_));
    float4 d = make_float4(f.x - mean.x, f.y - mean.y, f.z - mean.z, f.w - mean.w);
    float4 vr = block_reduce256_f4(make_float4(d.x*d.x, d.y*d.y, d.z*d.z, d.w*d.w), red4k);
    float g = gamma[t];
    xs[0][t] = d.x * rsqrtf(vr.x * (1.f/DIM_) + 1e-5f) * g;
    xs[1][t] = d.y * rsqrtf(vr.y * (1.f/DIM_) + 1e-5f) * g;
    xs[2][t] = d.z * rsqrtf(vr.z * (1.f/DIM_) + 1e-5f) * g;
    xs[3][t] = d.w * rsqrtf(vr.w * (1.f/DIM_) + 1e-5f) * g;
    __syncthreads();
    float acc[12];
    #pragma unroll
    for (int k = 0; k < 12; k++) acc[k] = 0.f;
    for (int c = 0; c < DIM_; c++) {
        const float* wr = w_qkv + (long)c * 768;
        float w0 = wr[t], w1 = wr[t + 256], w2 = wr[t + 512];
        #pragma unroll
        for (int r = 0; r < 4; r++) {
            float xc = xs[r][c];
            acc[r * 3 + 0] += xc * w0;
            acc[r * 3 + 1] += xc * w1;
            acc[r * 3 + 2] += xc * w2;
        }
    }
    int h = t >> 6, dd = t & 63;
    #pragma unroll
    for (int r = 0; r < 4; r++) {
        int n = r0 + r - b * N_;
        long idx = ((long)(b * H_ + h) * N_ + n) * DH_ + dd;
        qh[idx] = (_Float16)(acc[r * 3 + 0] * 0.125f);     // dh^-0.5 pre-applied
        kh[idx] = (_Float16)(acc[r * 3 + 1]);
        v[idx]  = acc[r * 3 + 2];
    }
    if (t < 32) {
        int rr = t >> 3, gg = t & 7;
        float a = b_gate[gg];
        for (int c = 0; c < DIM_; c++) a += xs[rr][c] * w_gate[c * 8 + gg];
        float gv = 1.0f / (1.0f + __expf(-a));
        int n = r0 + rr - b * N_;
        if (gg < 4) og[(b * H_ + gg) * N_ + n] = gv;
        else        rg[(b * H_ + (gg - 4)) * N_ + n] = gv;
    }
}

// ---------- K2: position-bias MLP (MFMA) + fused qk tiles ----------
// pT layout: [bi][jtile(24)][c(128)][j16(16)] f16 — each wave-unit writes one
// contiguous 4KB chunk (coalesced); K3M B-frag loads stay coalesced.
#define MFMA16(a, b, c) __builtin_amdgcn_mfma_f32_16x16x32_f16(a, b, c, 0, 0, 0)

#define LNAPPLY(GOFF_, BOFF_)                                                     \
{                                                                                  \
    float gv[8], bev[8];                                                           \
    _Pragma("unroll")                                                              \
    for (int nt = 0; nt < 8; nt++) {                                               \
        gv[nt]  = GB[(GOFF_) + nt * 16 + l15];                                     \
        bev[nt] = GB[(BOFF_) + nt * 16 + l15];                                     \
    }                                                                              \
    _Pragma("unroll")                                                              \
    for (int rg2 = 0; rg2 < 4; rg2++) {                                            \
        float s = 0.f, sq = 0.f;                                                   \
        _Pragma("unroll")                                                          \
        for (int nt = 0; nt < 8; nt++) {                                           \
            float v0 = acc[nt][rg2]; s += v0; sq += v0 * v0;                       \
        }                                                                          \
        s += __shfl_xor(s, 1); sq += __shfl_xor(sq, 1);                            \
        s += __shfl_xor(s, 2); sq += __shfl_xor(sq, 2);                            \
        s += __shfl_xor(s, 4); sq += __shfl_xor(sq, 4);                            \
        s += __shfl_xor(s, 8); sq += __shfl_xor(sq, 8);                            \
        float mean = s * (1.f / 128.f);                                            \
        float inv = rsqrtf(sq * (1.f / 128.f) - mean * mean + 1e-5f);              \
        int row2 = quad * 4 + rg2;                                                 \
        _Pragma("unroll")                                                          \
        for (int nt = 0; nt < 8; nt++) {                                           \
            float y = (acc[nt][rg2] - mean) * inv * gv[nt] + bev[nt];              \
            y = y / (1.f + __expf(-y));                                            \
            myslice[row2 * 136 + nt * 16 + l15] = (_Float16)y;                     \
        }                                                                          \
    }                                                                              \
}

__global__ __launch_bounds__(512) __attribute__((amdgpu_waves_per_eu(2, 2)))
void eq_k2(
    const float* __restrict__ coors,
    const float* __restrict__ w0, const float* __restrict__ b0,
    const float* __restrict__ g0, const float* __restrict__ be0,
    const float* __restrict__ W1g, const float* __restrict__ b1,
    const float* __restrict__ g1, const float* __restrict__ be1,
    const float* __restrict__ W2g, const float* __restrict__ b2,
    const float* __restrict__ g2, const float* __restrict__ be2,
    const float* __restrict__ wqk, const float* __restrict__ bqk,
    const _Float16* __restrict__ qh, const _Float16* __restrict__ kh,
    _Float16* __restrict__ pT, float* __restrict__ qkpos,
    float* __restrict__ qkq) {

    extern __shared__ char smem[];
    _Float16* W1T    = (_Float16*)smem;                   // 128x136 = 34816 B
    _Float16* W2T    = (_Float16*)(smem + 34816);         // 34816 B
    _Float16* slices = (_Float16*)(smem + 69632);         // 8 x 16x136 = 34816 B
    _Float16* wqT    = (_Float16*)(smem + 104448);        // 16x136 = 4352 B
    float*    PQR    = (float*)(smem + 108800);           // 1536 B
    float*    GB     = (float*)(smem + 110336);           // 2048 B

    const int t = threadIdx.x;
    const int lane = t & 63, wv = t >> 6;
    const int l15 = lane & 15, quad = lane >> 4;
    _Float16* myslice = slices + wv * (16 * 136);

    for (int idx = t; idx < 16384; idx += 512) {
        int k = idx >> 7, n = idx & 127;
        W1T[n * 136 + k] = (_Float16)W1g[idx];
        W2T[n * 136 + k] = (_Float16)W2g[idx];
    }
    for (int idx = t; idx < 2048; idx += 512) {
        int n = idx >> 7, k = idx & 127;
        wqT[n * 136 + k] = (n < 4) ? (_Float16)wqk[k * 4 + n] : (_Float16)0.f;
    }
    float Sw = 0, Sb = 0, Sww = 0, Swb = 0, Sbb = 0;
    for (int c = 0; c < 128; c++) {
        float w = w0[c], bb2v = b0[c];
        Sw += w; Sb += bb2v; Sww += w * w; Swb += w * bb2v; Sbb += bb2v * bb2v;
    }
    const float mw = Sw * (1.f / 128.f), mbb = Sb * (1.f / 128.f);
    const float A2 = Sww * (1.f / 128.f) - mw * mw;
    const float AD = Swb * (1.f / 128.f) - mw * mbb;
    const float D2 = Sbb * (1.f / 128.f) - mbb * mbb;
    if (t < 128) {
        PQR[t]       = (w0[t] - mw) * g0[t];
        PQR[128 + t] = (b0[t] - mbb) * g0[t];
        PQR[256 + t] = be0[t];
        GB[t]        = g1[t];
        GB[128 + t]  = be1[t];
        GB[256 + t]  = g2[t];
        GB[384 + t]  = be2[t];
    }
    float b1r[8], b2r[8];
    #pragma unroll
    for (int nt = 0; nt < 8; nt++) {
        int c = nt * 16 + l15;
        b1r[nt] = b1[c]; b2r[nt] = b2[c];
    }
    const float bqv = (l15 < 4) ? bqk[l15] : 0.f;
    __syncthreads();

    for (int unit = blockIdx.x * 8 + wv; unit < NU2_; unit += 256 * 8) {
        const int P0w = unit * 16;
        const int b = P0w / (N_ * N_);
        const int rem = P0w - b * (N_ * N_);
        const int ii = rem / N_;
        const int j0 = rem - ii * N_;
        const long bi = (long)(b * N_ + ii);
        const float cix = coors[(b * N_ + ii) * 3 + 0];
        const float ciy = coors[(b * N_ + ii) * 3 + 1];
        const float ciz = coors[(b * N_ + ii) * 3 + 2];
        float tt, uu;
        {
            int j = j0 + l15;
            float dx = cix - coors[(b * N_ + j) * 3 + 0];
            float dy = ciy - coors[(b * N_ + j) * 3 + 1];
            float dz = ciz - coors[(b * N_ + j) * 3 + 2];
            float d = sqrtf(dx * dx + dy * dy + dz * dz);
            float var = (d * d) * A2 + 2.f * d * AD + D2;
            float inv = rsqrtf(var + 1e-5f);
            tt = d * inv; uu = inv;
        }
        v8h A[4];
        #pragma unroll
        for (int kt = 0; kt < 4; kt++) {
            int base = kt * 32 + quad * 8;
            v8h av;
            #pragma unroll
            for (int jj = 0; jj < 8; jj++) {
                float y = tt * PQR[base + jj] + uu * PQR[128 + base + jj] + PQR[256 + base + jj];
                av[jj] = (_Float16)(y / (1.f + __expf(-y)));
            }
            A[kt] = av;
        }
        v4f acc[8];
        #pragma unroll
        for (int nt = 0; nt < 8; nt++) {
            v4f ci = {b1r[nt], b1r[nt], b1r[nt], b1r[nt]};
            acc[nt] = ci;
        }
        #pragma unroll
        for (int kt = 0; kt < 4; kt++) {
            #pragma unroll
            for (int nt = 0; nt < 8; nt++) {
                v8h Bv = *(const v8h*)&W1T[(nt * 16 + l15) * 136 + kt * 32 + quad * 8];
                acc[nt] = MFMA16(A[kt], Bv, acc[nt]);
            }
        }
        LNAPPLY(0, 128)
        #pragma unroll
        for (int kt = 0; kt < 4; kt++)
            A[kt] = *(const v8h*)&myslice[l15 * 136 + kt * 32 + quad * 8];
        #pragma unroll
        for (int nt = 0; nt < 8; nt++) {
            v4f ci = {b2r[nt], b2r[nt], b2r[nt], b2r[nt]};
            acc[nt] = ci;
        }
        #pragma unroll
        for (int kt = 0; kt < 4; kt++) {
            #pragma unroll
            for (int nt = 0; nt < 8; nt++) {
                v8h Bv = *(const v8h*)&W2T[(nt * 16 + l15) * 136 + kt * 32 + quad * 8];
                acc[nt] = MFMA16(A[kt], Bv, acc[nt]);
            }
        }
        LNAPPLY(256, 384)
        // ---- pT store: contiguous 4KB chunk [c][j16] (coalesced) ----
        {
            _Float16* chunk = pT + (((long)bi * 24 + (j0 >> 4)) << 11);  // *2048
            #pragma unroll
            for (int cc = 0; cc < 2; cc++) {
                int c = lane + cc * 64;
                v8h lo, hi;
                #pragma unroll
                for (int k = 0; k < 8; k++) {
                    lo[k] = myslice[k * 136 + c];
                    hi[k] = myslice[(k + 8) * 136 + c];
                }
                *(v8h*)(chunk + c * 16)     = lo;
                *(v8h*)(chunk + c * 16 + 8) = hi;
            }
        }
        // ---- qk_pos = p @ wqk + bqk ----
        {
            v4f c = {0.f, 0.f, 0.f, 0.f};
            #pragma unroll
            for (int kt = 0; kt < 4; kt++) {
                v8h av = *(const v8h*)&myslice[l15 * 136 + kt * 32 + quad * 8];
                v8h wq = *(const v8h*)&wqT[l15 * 136 + kt * 32 + quad * 8];
                c = MFMA16(av, wq, c);
            }
            if (l15 < 4) {
                #pragma unroll
                for (int rg2 = 0; rg2 < 4; rg2++) {
                    int row = quad * 4 + rg2;
                    qkpos[(long)(P0w + row) * 4 + l15] = c[rg2] + bqv;
                }
            }
        }
    }

    // ---- fused former K2b: first 384 waves each do one 16x384 qk tile ----
    {
        int gw = blockIdx.x * 8 + wv;
        if (gw < 384) {
            const int bh = gw / 48;
            const int rest = gw - bh * 48;
            const int it = rest >> 1, nh = rest & 1;
            const int bb = bh >> 2, hh = bh & 3;
            const int i0 = it * 16;
            v8h A0 = *(const v8h*)&qh[((long)(bh * N_) + i0 + l15) * DH_ + quad * 8];
            v8h A1 = *(const v8h*)&qh[((long)(bh * N_) + i0 + l15) * DH_ + 32 + quad * 8];
            #pragma unroll 1
            for (int nt = 0; nt < 12; nt++) {
                int jq0 = nh * 192 + nt * 16;
                v8h B0 = *(const v8h*)&kh[((long)(bh * N_) + jq0 + l15) * DH_ + quad * 8];
                v8h B1 = *(const v8h*)&kh[((long)(bh * N_) + jq0 + l15) * DH_ + 32 + quad * 8];
                v4f c = {0.f, 0.f, 0.f, 0.f};
                c = MFMA16(A0, B0, c);
                c = MFMA16(A1, B1, c);
                #pragma unroll
                for (int rg2 = 0; rg2 < 4; rg2++) {
                    int i = i0 + quad * 4 + rg2;
                    int j = jq0 + l15;
                    long idx = (((long)(bb * N_ + i)) * N_ + j) * 4 + hh;
                    qkq[idx] = c[rg2];
                }
            }
        }
    }
}

// ---------- K3M: fused edge-MLP/softmax/coor-branch/ap(MFMA)/attn@v/out-proj ----------
__global__ __launch_bounds__(384) void eq_k3m(
    const float* __restrict__ edges, const float* __restrict__ qkpos,
    const float* __restrict__ qkq,
    const _Float16* __restrict__ pT, const float* __restrict__ v,
    const float* __restrict__ coors,
    const float* __restrict__ w_e1, const float* __restrict__ w_e2,
    const float* __restrict__ w_c, const float* __restrict__ w_cg,
    const float* __restrict__ b_cg, const float* __restrict__ w_th,
    const float* __restrict__ cscale, const float* __restrict__ ccomb,
    const float* __restrict__ og, const float* __restrict__ rg,
    const float* __restrict__ w_vpos, const float* __restrict__ b_vpos,
    const float* __restrict__ w_out, const float* __restrict__ b_out,
    float* __restrict__ out0, float* __restrict__ out1) {
    int row = blockIdx.x;           // b*N + i
    int b = row / N_, i = row - b * N_;
    int j = threadIdx.x;            // 0..383
    __shared__ float we1[20 * 40];
    __shared__ float we2[40 * 4];
    __shared__ float wcs[16], wcgs[16], bcgs[4], wths[16];
    __shared__ float attnS[4 * N_];
    __shared__ float apS[2 * 4 * PD_];
    __shared__ float nodeS[256];
    __shared__ float4 red4[34];     // [0..15] reduce slots, [16..33] reduce12

    for (int idx = j; idx < 800; idx += 384) we1[idx] = w_e1[idx];
    if (j < 160) we2[j] = w_e2[j];
    if (j < 16) { wcs[j] = w_c[j]; wcgs[j] = w_cg[j]; wths[j] = w_th[j]; }
    if (j < 4) bcgs[j] = b_cg[j];
    __syncthreads();

    // ---- phase A: scores (pos + qk) + edge MLP ----
    long pair = ((long)row) * N_ + j;
    float in20[20];
    {
        float4 qp = *(const float4*)(qkpos + pair * 4);
        float4 qq = *(const float4*)(qkq + pair * 4);
        in20[0] = qp.x + qq.x; in20[1] = qp.y + qq.y;
        in20[2] = qp.z + qq.z; in20[3] = qp.w + qq.w;
    }
    const float4* ep = (const float4*)(edges + pair * ED_);
    float4 e0 = ep[0], e1 = ep[1], e2 = ep[2], e3 = ep[3];
    in20[4] = e0.x;  in20[5] = e0.y;  in20[6] = e0.z;  in20[7] = e0.w;
    in20[8] = e1.x;  in20[9] = e1.y;  in20[10] = e1.z; in20[11] = e1.w;
    in20[12] = e2.x; in20[13] = e2.y; in20[14] = e2.z; in20[15] = e2.w;
    in20[16] = e3.x; in20[17] = e3.y; in20[18] = e3.z; in20[19] = e3.w;

    float c0 = 0, c1 = 0, c2 = 0, c3 = 0;
    #pragma unroll 1
    for (int oc = 0; oc < 5; oc++) {
        float a8[8] = {0.f, 0.f, 0.f, 0.f, 0.f, 0.f, 0.f, 0.f};
        #pragma unroll
        for (int c = 0; c < 20; c++) {
            float xc = in20[c];
            float4 wa = *(const float4*)&we1[c * 40 + oc * 8];
            float4 wb = *(const float4*)&we1[c * 40 + oc * 8 + 4];
            a8[0] += xc * wa.x; a8[1] += xc * wa.y; a8[2] += xc * wa.z; a8[3] += xc * wa.w;
            a8[4] += xc * wb.x; a8[5] += xc * wb.y; a8[6] += xc * wb.z; a8[7] += xc * wb.w;
        }
        #pragma unroll
        for (int o = 0; o < 8; o++) {
            float gg = gelu_(a8[o]);
            float4 w2v = *(const float4*)&we2[(oc * 8 + o) * 4];
            c0 += gg * w2v.x; c1 += gg * w2v.y; c2 += gg * w2v.z; c3 += gg * w2v.w;
        }
    }
    float cmi[4] = {c0, c1, c2, c3};
    float gc[4], cp[4], rs[4];
    #pragma unroll
    for (int h = 0; h < 4; h++) gc[h] = gelu_(cmi[h]);
    #pragma unroll
    for (int h = 0; h < 4; h++) {
        cp[h] = gc[0] * wcs[h] + gc[1] * wcs[4 + h] + gc[2] * wcs[8 + h] + gc[3] * wcs[12 + h];
        rs[h] = cmi[0] * wcgs[h] + cmi[1] * wcgs[4 + h] + cmi[2] * wcgs[8 + h] + cmi[3] * wcgs[12 + h] + bcgs[h];
    }

    // ---- phase B: softmax over j + talking heads -> attnS ----
    float4 m4 = block_reduce4(make_float4(cmi[0], cmi[1], cmi[2], cmi[3]), true, red4, 0);
    float e[4];
    e[0] = __expf(cmi[0] - m4.x); e[1] = __expf(cmi[1] - m4.y);
    e[2] = __expf(cmi[2] - m4.z); e[3] = __expf(cmi[3] - m4.w);
    float4 l4 = block_reduce4(make_float4(e[0], e[1], e[2], e[3]), false, red4, 1);
    float sm[4] = {e[0] / l4.x, e[1] / l4.y, e[2] / l4.z, e[3] / l4.w};
    #pragma unroll
    for (int h = 0; h < 4; h++)
        attnS[h * N_ + j] = wths[h * 4 + 0] * sm[0] + wths[h * 4 + 1] * sm[1]
                          + wths[h * 4 + 2] * sm[2] + wths[h * 4 + 3] * sm[3];

    // ---- phase C: coordinate branch -> out1 ----
    float dx = coors[(b * N_ + i) * 3 + 0] - coors[(b * N_ + j) * 3 + 0];
    float dy = coors[(b * N_ + i) * 3 + 1] - coors[(b * N_ + j) * 3 + 1];
    float dz = coors[(b * N_ + i) * 3 + 2] - coors[(b * N_ + j) * 3 + 2];
    float nrm = sqrtf(dx * dx + dy * dy + dz * dz);
    float sc = cscale[0] / fmaxf(nrm, 1e-8f);
    float rx = dx * sc, ry = dy * sc, rz = dz * sc;
    float4 cm4 = block_reduce4(make_float4(cp[0], cp[1], cp[2], cp[3]), true, red4, 0);
    float ec[4];
    ec[0] = __expf(cp[0] - cm4.x); ec[1] = __expf(cp[1] - cm4.y);
    ec[2] = __expf(cp[2] - cm4.z); ec[3] = __expf(cp[3] - cm4.w);
    float4 cl4 = block_reduce4(make_float4(ec[0], ec[1], ec[2], ec[3]), false, red4, 1);
    float w[4] = {ec[0] / cl4.x * rs[0], ec[1] / cl4.y * rs[1],
                  ec[2] / cl4.z * rs[2], ec[3] / cl4.w * rs[3]};
    float rv[12];
    #pragma unroll
    for (int h = 0; h < 4; h++) { rv[h] = w[h] * rx; rv[4 + h] = w[h] * ry; rv[8 + h] = w[h] * rz; }
    #pragma unroll
    for (int o = 32; o > 0; o >>= 1) {
        #pragma unroll
        for (int k = 0; k < 12; k++) rv[k] += __shfl_xor(rv[k], o);
    }
    if ((j & 63) == 0) {
        int wid = j >> 6;
        red4[16 + wid * 3 + 0] = make_float4(rv[0], rv[1], rv[2], rv[3]);
        red4[16 + wid * 3 + 1] = make_float4(rv[4], rv[5], rv[6], rv[7]);
        red4[16 + wid * 3 + 2] = make_float4(rv[8], rv[9], rv[10], rv[11]);
    }
    __syncthreads();    // attnS + reduce12 ready
    if (j == 0) {
        float4 sx4 = red4[16], sy4 = red4[17], sz4 = red4[18];
        #pragma unroll
        for (int w2 = 1; w2 < 6; w2++) {
            float4 ax = red4[16 + w2 * 3 + 0], ay = red4[16 + w2 * 3 + 1], az = red4[16 + w2 * 3 + 2];
            sx4.x += ax.x; sx4.y += ax.y; sx4.z += ax.z; sx4.w += ax.w;
            sy4.x += ay.x; sy4.y += ay.y; sy4.z += ay.z; sy4.w += ay.w;
            sz4.x += az.x; sz4.y += az.y; sz4.z += az.z; sz4.w += az.w;
        }
        float f0 = ccomb[0] * rg[(b * H_ + 0) * N_ + i];
        float f1 = ccomb[1] * rg[(b * H_ + 1) * N_ + i];
        float f2 = ccomb[2] * rg[(b * H_ + 2) * N_ + i];
        float f3 = ccomb[3] * rg[(b * H_ + 3) * N_ + i];
        out1[(b * N_ + i) * 3 + 0] = f0 * sx4.x + f1 * sx4.y + f2 * sx4.z + f3 * sx4.w;
        out1[(b * N_ + i) * 3 + 1] = f0 * sy4.x + f1 * sy4.y + f2 * sy4.z + f3 * sy4.w;
        out1[(b * N_ + i) * 3 + 2] = f0 * sz4.x + f1 * sz4.y + f2 * sz4.z + f3 * sz4.w;
    }

    // ---- phase D: waves 0-1 -> ap via MFMA; threads 128..383 -> attn@v ----
    if (j < 128) {
        const int lane = j & 63, l15d = lane & 15, quadd = lane >> 4;
        const int parity = j >> 6;
        const int hh = l15d & 3;
        const float msk = (l15d < 4) ? 1.f : 0.f;
        v4f acc[8];
        #pragma unroll
        for (int nt = 0; nt < 8; nt++) { v4f z = {0.f, 0.f, 0.f, 0.f}; acc[nt] = z; }
        #pragma unroll 2
        for (int kth = 0; kth < 6; kth++) {
            int kt = parity * 6 + kth;
            float4 a0 = *(const float4*)&attnS[hh * N_ + kt * 32 + quadd * 8];
            float4 a1 = *(const float4*)&attnS[hh * N_ + kt * 32 + quadd * 8 + 4];
            v8h Af;
            Af[0] = (_Float16)(a0.x * msk); Af[1] = (_Float16)(a0.y * msk);
            Af[2] = (_Float16)(a0.z * msk); Af[3] = (_Float16)(a0.w * msk);
            Af[4] = (_Float16)(a1.x * msk); Af[5] = (_Float16)(a1.y * msk);
            Af[6] = (_Float16)(a1.z * msk); Af[7] = (_Float16)(a1.w * msk);
            // pT chunk layout: [bi][jt][c][16]; jt = kt*2 + (quadd>>1), off = (quadd&1)*8
            const _Float16* chunkp = pT + (((long)row * 24 + kt * 2 + (quadd >> 1)) << 11)
                                        + ((quadd & 1) << 3);
            #pragma unroll
            for (int nt = 0; nt < 8; nt++) {
                v8h Bv = *(const v8h*)&chunkp[(nt * 16 + l15d) * 16];
                acc[nt] = MFMA16(Af, Bv, acc[nt]);
            }
        }
        if (quadd == 0) {
            #pragma unroll
            for (int nt = 0; nt < 8; nt++)
                #pragma unroll
                for (int rg2 = 0; rg2 < 4; rg2++)
                    apS[parity * 512 + rg2 * 128 + nt * 16 + l15d] = acc[nt][rg2];
        }
    } else {
        int tt = j - 128, h = tt >> 6, d = tt & 63;
        float acc = 0;
        const float* vp = v + ((long)(b * H_ + h) * N_) * DH_ + d;
        #pragma unroll 16
        for (int jj = 0; jj < N_; jj++) acc += attnS[h * N_ + jj] * vp[(long)jj * DH_];
        nodeS[tt] = acc;
    }
    __syncthreads();

    // ---- phase E: node = (attnv + ap@w_vpos + Sh*b_vpos) * out_gate ----
    float nv = 0;
    if (j < 256) {
        int h = j >> 6, d = j & 63;
        float accp = 0;
        const float* wv = w_vpos + h * DH_ + d;
        #pragma unroll 8
        for (int c = 0; c < PD_; c++)
            accp += (apS[h * 128 + c] + apS[512 + h * 128 + c]) * wv[(long)c * (H_ * DH_)];
        float Sh = wths[h * 4 + 0] + wths[h * 4 + 1] + wths[h * 4 + 2] + wths[h * 4 + 3];
        nv = (nodeS[j] + accp + Sh * b_vpos[h * DH_ + d]) * og[(b * H_ + h) * N_ + i];
    }
    __syncthreads();
    if (j < 256) nodeS[j] = nv;
    __syncthreads();

    // ---- phase F: out0 = node @ w_out + b_out ----
    if (j < 256) {
        float acc = b_out[j];
        const float* wo = w_out + j;
        #pragma unroll 4
        for (int c4 = 0; c4 < 64; c4++) {
            float4 nv4 = *(const float4*)&nodeS[c4 * 4];
            acc += nv4.x * wo[(long)(c4 * 4 + 0) * 256]
                 + nv4.y * wo[(long)(c4 * 4 + 1) * 256]
                 + nv4.z * wo[(long)(c4 * 4 + 2) * 256]
                 + nv4.w * wo[(long)(c4 * 4 + 3) * 256];
        }
        out0[(long)row * 256 + j] = acc;
    }
}

extern "C" void kernel_launch(void* const* d_in, const int* in_sizes, int n_in,
                              void* d_out, int out_size, void* d_ws, size_t ws_size,
                              hipStream_t stream) {
    (void)in_sizes; (void)n_in; (void)out_size; (void)ws_size;
    const float* feats   = (const float*)d_in[0];
    const float* coors   = (const float*)d_in[1];
    const float* edges   = (const float*)d_in[2];
    const float* gamma   = (const float*)d_in[3];
    const float* w_qkv   = (const float*)d_in[4];
    const float* w_gate  = (const float*)d_in[5];
    const float* b_gate  = (const float*)d_in[6];
    const float* w_th    = (const float*)d_in[7];
    const float* w_e1    = (const float*)d_in[8];
    const float* w_e2    = (const float*)d_in[9];
    const float* w_c     = (const float*)d_in[10];
    const float* w_cg    = (const float*)d_in[11];
    const float* b_cg    = (const float*)d_in[12];
    const float* cscale  = (const float*)d_in[13];
    const float* ccomb   = (const float*)d_in[14];
    const float* pb_w0   = (const float*)d_in[15];
    const float* pb_b0   = (const float*)d_in[16];
    const float* pb_g0   = (const float*)d_in[17];
    const float* pb_be0  = (const float*)d_in[18];
    const float* pb_w1   = (const float*)d_in[19];
    const float* pb_b1   = (const float*)d_in[20];
    const float* pb_g1   = (const float*)d_in[21];
    const float* pb_be1  = (const float*)d_in[22];
    const float* pb_w2   = (const float*)d_in[23];
    const float* pb_b2   = (const float*)d_in[24];
    const float* pb_g2   = (const float*)d_in[25];
    const float* pb_be2  = (const float*)d_in[26];
    const float* w_qkpos = (const float*)d_in[27];
    const float* b_qkpos = (const float*)d_in[28];
    const float* w_vpos  = (const float*)d_in[29];
    const float* b_vpos  = (const float*)d_in[30];
    const float* w_out   = (const float*)d_in[31];
    const float* b_out   = (const float*)d_in[32];

    // workspace carve (bytes)
    char* ws = (char*)d_ws;
    _Float16* qh   = (_Float16*)(ws + 0);            // 393216 B
    _Float16* kh   = (_Float16*)(ws + 393216);       // 393216 B
    float* v       = (float*)(ws + 786432);          // 786432 B
    float* og      = (float*)(ws + 1572864);         // 12288 B
    float* rg      = (float*)(ws + 1585152);         // 12288 B
    float* qkpos   = (float*)(ws + 1597440);         // 4718592 B
    _Float16* pT   = (_Float16*)(ws + 6316032);      // 75497472 B (tiled chunks)
    float* qkq     = (float*)(ws + 81813504);        // 4718592 B

    float* out0 = (float*)d_out;
    float* out1 = out0 + (long)B_ * N_ * DIM_;

    const int K2_LDS = 112384;
    hipFuncSetAttribute((const void*)eq_k2, hipFuncAttributeMaxDynamicSharedMemorySize, K2_LDS);

    eq_k1<<<192, 256, 0, stream>>>(feats, gamma, w_qkv, w_gate, b_gate, qh, kh, v, og, rg);
    eq_k2<<<256, 512, K2_LDS, stream>>>(coors, pb_w0, pb_b0, pb_g0, pb_be0,
                                        pb_w1, pb_b1, pb_g1, pb_be1,
                                        pb_w2, pb_b2, pb_g2, pb_be2,
                                        w_qkpos, b_qkpos, qh, kh, pT, qkpos, qkq);
    eq_k3m<<<B_ * N_, 384, 0, stream>>>(edges, qkpos, qkq, pT, v, coors,
                                        w_e1, w_e2, w_c, w_cg, b_cg, w_th,
                                        cscale, ccomb, og, rg,
                                        w_vpos, b_vpos, w_out, b_out, out0, out1);
}

// Round 11
// 338.906 us; speedup vs baseline: 3.3966x; 1.0813x over previous
//
#include <hip/hip_runtime.h>
#include <hip/hip_bf16.h>

#define B_   2
#define N_   384
#define DIM_ 256
#define H_   4
#define DH_  64
#define PD_  128
#define ED_  16
#define NU2_ ((B_ * N_ * N_) / 16)   // 18432 wave-units (16 pairs each)

typedef _Float16 v8h __attribute__((ext_vector_type(8)));
typedef float    v4f __attribute__((ext_vector_type(4)));

__device__ __forceinline__ float rcp_(float x) { return __builtin_amdgcn_rcpf(x); }

// fast erf: Abramowitz-Stegun 7.1.26, |err| <= 1.5e-7 (rcp instead of IEEE div)
__device__ __forceinline__ float erf_fast(float x) {
    float ax = fabsf(x);
    float t = rcp_(fmaf(0.3275911f, ax, 1.0f));
    float y = t * fmaf(t, fmaf(t, fmaf(t, fmaf(t, 1.061405429f, -1.453152027f),
                                       1.421413741f), -0.284496736f), 0.254829592f);
    float r = 1.0f - y * __expf(-ax * ax);
    return (x < 0.f) ? -r : r;
}
__device__ __forceinline__ float gelu_(float x) {
    return 0.5f * x * (1.0f + erf_fast(x * 0.70710678118654752f));
}
__device__ __forceinline__ float silu_(float x) {
    return x * rcp_(1.0f + __expf(-x));
}

// batched float4 block reduction over 256 threads (4 waves)
__device__ __forceinline__ float4 block_reduce256_f4(float4 v, float4* red) {
    #pragma unroll
    for (int o = 32; o > 0; o >>= 1) {
        v.x += __shfl_xor(v.x, o); v.y += __shfl_xor(v.y, o);
        v.z += __shfl_xor(v.z, o); v.w += __shfl_xor(v.w, o);
    }
    __syncthreads();
    if ((threadIdx.x & 63) == 0) red[threadIdx.x >> 6] = v;
    __syncthreads();
    float4 r = red[0];
    #pragma unroll
    for (int w2 = 1; w2 < 4; w2++) {
        float4 o = red[w2];
        r.x += o.x; r.y += o.y; r.z += o.z; r.w += o.w;
    }
    return r;
}

// batched float4 block reduction over 384 threads (6 waves).
__device__ __forceinline__ float4 block_reduce4(float4 v, bool ismax, float4* red, int slot) {
    #pragma unroll
    for (int o = 32; o > 0; o >>= 1) {
        float x = __shfl_xor(v.x, o), y = __shfl_xor(v.y, o);
        float z = __shfl_xor(v.z, o), w = __shfl_xor(v.w, o);
        if (ismax) { v.x = fmaxf(v.x, x); v.y = fmaxf(v.y, y); v.z = fmaxf(v.z, z); v.w = fmaxf(v.w, w); }
        else       { v.x += x; v.y += y; v.z += z; v.w += w; }
    }
    if ((threadIdx.x & 63) == 0) red[slot * 8 + (threadIdx.x >> 6)] = v;
    __syncthreads();
    float4 r = red[slot * 8];
    #pragma unroll
    for (int w2 = 1; w2 < 6; w2++) {
        float4 o = red[slot * 8 + w2];
        if (ismax) { r.x = fmaxf(r.x, o.x); r.y = fmaxf(r.y, o.y); r.z = fmaxf(r.z, o.z); r.w = fmaxf(r.w, o.w); }
        else       { r.x += o.x; r.y += o.y; r.z += o.z; r.w += o.w; }
    }
    return r;
}

// ---------- K1: LayerNorm + QKV (4 rows/block, f16 q/k out) + gates ----------
__global__ __launch_bounds__(256) void eq_k1(
    const float* __restrict__ feats, const float* __restrict__ gamma,
    const float* __restrict__ w_qkv, const float* __restrict__ w_gate,
    const float* __restrict__ b_gate,
    _Float16* __restrict__ qh, _Float16* __restrict__ kh, float* __restrict__ v,
    float* __restrict__ og, float* __restrict__ rg) {
    const int r0 = blockIdx.x * 4;
    const int b = r0 / N_;
    const int t = threadIdx.x;
    __shared__ float xs[4][DIM_];
    __shared__ float4 red4k[4];
    float4 f;
    f.x = feats[(long)(r0 + 0) * DIM_ + t];
    f.y = feats[(long)(r0 + 1) * DIM_ + t];
    f.z = feats[(long)(r0 + 2) * DIM_ + t];
    f.w = feats[(long)(r0 + 3) * DIM_ + t];
    float4 s = block_reduce256_f4(f, red4k);
    float4 mean = make_float4(s.x * (1.f/DIM_), s.y * (1.f/DIM_), s.z * (1.f/DIM_), s.w * (1.f/DIM_));
    float4 d = make_float4(f.x - mean.x, f.y - mean.y, f.z - mean.z, f.w - mean.w);
    float4 vr = block_reduce256_f4(make_float4(d.x*d.x, d.y*d.y, d.z*d.z, d.w*d.w), red4k);
    float g = gamma[t];
    xs[0][t] = d.x * rsqrtf(vr.x * (1.f/DIM_) + 1e-5f) * g;
    xs[1][t] = d.y * rsqrtf(vr.y * (1.f/DIM_) + 1e-5f) * g;
    xs[2][t] = d.z * rsqrtf(vr.z * (1.f/DIM_) + 1e-5f) * g;
    xs[3][t] = d.w * rsqrtf(vr.w * (1.f/DIM_) + 1e-5f) * g;
    __syncthreads();
    float acc[12];
    #pragma unroll
    for (int k = 0; k < 12; k++) acc[k] = 0.f;
    for (int c = 0; c < DIM_; c++) {
        const float* wr = w_qkv + (long)c * 768;
        float w0 = wr[t], w1 = wr[t + 256], w2 = wr[t + 512];
        #pragma unroll
        for (int r = 0; r < 4; r++) {
            float xc = xs[r][c];
            acc[r * 3 + 0] += xc * w0;
            acc[r * 3 + 1] += xc * w1;
            acc[r * 3 + 2] += xc * w2;
        }
    }
    int h = t >> 6, dd = t & 63;
    #pragma unroll
    for (int r = 0; r < 4; r++) {
        int n = r0 + r - b * N_;
        long idx = ((long)(b * H_ + h) * N_ + n) * DH_ + dd;
        qh[idx] = (_Float16)(acc[r * 3 + 0] * 0.125f);     // dh^-0.5 pre-applied
        kh[idx] = (_Float16)(acc[r * 3 + 1]);
        v[idx]  = acc[r * 3 + 2];
    }
    if (t < 32) {
        int rr = t >> 3, gg = t & 7;
        float a = b_gate[gg];
        for (int c = 0; c < DIM_; c++) a += xs[rr][c] * w_gate[c * 8 + gg];
        float gv = rcp_(1.0f + __expf(-a));
        int n = r0 + rr - b * N_;
        if (gg < 4) og[(b * H_ + gg) * N_ + n] = gv;
        else        rg[(b * H_ + (gg - 4)) * N_ + n] = gv;
    }
}

// ---------- K2: position-bias MLP (MFMA) + fused qk tiles ----------
// pT layout: [bi][jtile(24)][c(128)][j16(16)] f16 (coalesced both sides).
// g/be hoisted to registers; silu uses v_rcp; layer0 PQR via float4.
#define MFMA16(a, b, c) __builtin_amdgcn_mfma_f32_16x16x32_f16(a, b, c, 0, 0, 0)

#define LNAPPLY(gr_, ber_)                                                        \
{                                                                                  \
    _Pragma("unroll")                                                              \
    for (int rg2 = 0; rg2 < 4; rg2++) {                                            \
        float s = 0.f, sq = 0.f;                                                   \
        _Pragma("unroll")                                                          \
        for (int nt = 0; nt < 8; nt++) {                                           \
            float v0 = acc[nt][rg2]; s += v0; sq += v0 * v0;                       \
        }                                                                          \
        s += __shfl_xor(s, 1); sq += __shfl_xor(sq, 1);                            \
        s += __shfl_xor(s, 2); sq += __shfl_xor(sq, 2);                            \
        s += __shfl_xor(s, 4); sq += __shfl_xor(sq, 4);                            \
        s += __shfl_xor(s, 8); sq += __shfl_xor(sq, 8);                            \
        float mean = s * (1.f / 128.f);                                            \
        float inv = rsqrtf(sq * (1.f / 128.f) - mean * mean + 1e-5f);              \
        int row2 = quad * 4 + rg2;                                                 \
        _Pragma("unroll")                                                          \
        for (int nt = 0; nt < 8; nt++) {                                           \
            float y = (acc[nt][rg2] - mean) * inv * gr_[nt] + ber_[nt];            \
            myslice[row2 * 136 + nt * 16 + l15] = (_Float16)silu_(y);              \
        }                                                                          \
    }                                                                              \
}

__global__ __launch_bounds__(512) __attribute__((amdgpu_waves_per_eu(2, 2)))
void eq_k2(
    const float* __restrict__ coors,
    const float* __restrict__ w0, const float* __restrict__ b0,
    const float* __restrict__ g0, const float* __restrict__ be0,
    const float* __restrict__ W1g, const float* __restrict__ b1,
    const float* __restrict__ g1, const float* __restrict__ be1,
    const float* __restrict__ W2g, const float* __restrict__ b2,
    const float* __restrict__ g2, const float* __restrict__ be2,
    const float* __restrict__ wqk, const float* __restrict__ bqk,
    const _Float16* __restrict__ qh, const _Float16* __restrict__ kh,
    _Float16* __restrict__ pT, float* __restrict__ qkpos,
    float* __restrict__ qkq) {

    extern __shared__ char smem[];
    _Float16* W1T    = (_Float16*)smem;                   // 128x136 = 34816 B
    _Float16* W2T    = (_Float16*)(smem + 34816);         // 34816 B
    _Float16* slices = (_Float16*)(smem + 69632);         // 8 x 16x136 = 34816 B
    _Float16* wqT    = (_Float16*)(smem + 104448);        // 16x136 = 4352 B
    float*    PQR    = (float*)(smem + 108800);           // 1536 B

    const int t = threadIdx.x;
    const int lane = t & 63, wv = t >> 6;
    const int l15 = lane & 15, quad = lane >> 4;
    _Float16* myslice = slices + wv * (16 * 136);

    for (int idx = t; idx < 16384; idx += 512) {
        int k = idx >> 7, n = idx & 127;
        W1T[n * 136 + k] = (_Float16)W1g[idx];
        W2T[n * 136 + k] = (_Float16)W2g[idx];
    }
    for (int idx = t; idx < 2048; idx += 512) {
        int n = idx >> 7, k = idx & 127;
        wqT[n * 136 + k] = (n < 4) ? (_Float16)wqk[k * 4 + n] : (_Float16)0.f;
    }
    float Sw = 0, Sb = 0, Sww = 0, Swb = 0, Sbb = 0;
    for (int c = 0; c < 128; c++) {
        float w = w0[c], bb2v = b0[c];
        Sw += w; Sb += bb2v; Sww += w * w; Swb += w * bb2v; Sbb += bb2v * bb2v;
    }
    const float mw = Sw * (1.f / 128.f), mbb = Sb * (1.f / 128.f);
    const float A2 = Sww * (1.f / 128.f) - mw * mw;
    const float AD = Swb * (1.f / 128.f) - mw * mbb;
    const float D2 = Sbb * (1.f / 128.f) - mbb * mbb;
    if (t < 128) {
        PQR[t]       = (w0[t] - mw) * g0[t];
        PQR[128 + t] = (b0[t] - mbb) * g0[t];
        PQR[256 + t] = be0[t];
    }
    // loop-invariant per-lane channel params in registers (c = nt*16 + l15)
    float b1r[8], b2r[8], g1r[8], be1r[8], g2r[8], be2r[8];
    #pragma unroll
    for (int nt = 0; nt < 8; nt++) {
        int c = nt * 16 + l15;
        b1r[nt] = b1[c]; b2r[nt] = b2[c];
        g1r[nt] = g1[c]; be1r[nt] = be1[c];
        g2r[nt] = g2[c]; be2r[nt] = be2[c];
    }
    const float bqv = (l15 < 4) ? bqk[l15] : 0.f;
    __syncthreads();

    for (int unit = blockIdx.x * 8 + wv; unit < NU2_; unit += 256 * 8) {
        const int P0w = unit * 16;
        const int b = P0w / (N_ * N_);
        const int rem = P0w - b * (N_ * N_);
        const int ii = rem / N_;
        const int j0 = rem - ii * N_;
        const long bi = (long)(b * N_ + ii);
        const float cix = coors[(b * N_ + ii) * 3 + 0];
        const float ciy = coors[(b * N_ + ii) * 3 + 1];
        const float ciz = coors[(b * N_ + ii) * 3 + 2];
        float tt, uu;
        {
            int j = j0 + l15;
            float dx = cix - coors[(b * N_ + j) * 3 + 0];
            float dy = ciy - coors[(b * N_ + j) * 3 + 1];
            float dz = ciz - coors[(b * N_ + j) * 3 + 2];
            float d = sqrtf(dx * dx + dy * dy + dz * dz);
            float var = (d * d) * A2 + 2.f * d * AD + D2;
            float inv = rsqrtf(var + 1e-5f);
            tt = d * inv; uu = inv;
        }
        // layer0 directly into A-fragments (float4 PQR reads, rcp silu)
        v8h A[4];
        #pragma unroll
        for (int kt = 0; kt < 4; kt++) {
            int base = kt * 32 + quad * 8;
            float4 Pa = *(const float4*)&PQR[base],       Pb = *(const float4*)&PQR[base + 4];
            float4 Qa = *(const float4*)&PQR[128 + base], Qb = *(const float4*)&PQR[128 + base + 4];
            float4 Ra = *(const float4*)&PQR[256 + base], Rb = *(const float4*)&PQR[256 + base + 4];
            float Pj[8] = {Pa.x, Pa.y, Pa.z, Pa.w, Pb.x, Pb.y, Pb.z, Pb.w};
            float Qj[8] = {Qa.x, Qa.y, Qa.z, Qa.w, Qb.x, Qb.y, Qb.z, Qb.w};
            float Rj[8] = {Ra.x, Ra.y, Ra.z, Ra.w, Rb.x, Rb.y, Rb.z, Rb.w};
            v8h av;
            #pragma unroll
            for (int jj = 0; jj < 8; jj++) {
                float y = tt * Pj[jj] + uu * Qj[jj] + Rj[jj];
                av[jj] = (_Float16)silu_(y);
            }
            A[kt] = av;
        }
        v4f acc[8];
        #pragma unroll
        for (int nt = 0; nt < 8; nt++) {
            v4f ci = {b1r[nt], b1r[nt], b1r[nt], b1r[nt]};
            acc[nt] = ci;
        }
        #pragma unroll
        for (int kt = 0; kt < 4; kt++) {
            #pragma unroll
            for (int nt = 0; nt < 8; nt++) {
                v8h Bv = *(const v8h*)&W1T[(nt * 16 + l15) * 136 + kt * 32 + quad * 8];
                acc[nt] = MFMA16(A[kt], Bv, acc[nt]);
            }
        }
        LNAPPLY(g1r, be1r)
        #pragma unroll
        for (int kt = 0; kt < 4; kt++)
            A[kt] = *(const v8h*)&myslice[l15 * 136 + kt * 32 + quad * 8];
        #pragma unroll
        for (int nt = 0; nt < 8; nt++) {
            v4f ci = {b2r[nt], b2r[nt], b2r[nt], b2r[nt]};
            acc[nt] = ci;
        }
        #pragma unroll
        for (int kt = 0; kt < 4; kt++) {
            #pragma unroll
            for (int nt = 0; nt < 8; nt++) {
                v8h Bv = *(const v8h*)&W2T[(nt * 16 + l15) * 136 + kt * 32 + quad * 8];
                acc[nt] = MFMA16(A[kt], Bv, acc[nt]);
            }
        }
        LNAPPLY(g2r, be2r)
        // ---- pT store: contiguous 4KB chunk [c][j16] (coalesced) ----
        {
            _Float16* chunk = pT + (((long)bi * 24 + (j0 >> 4)) << 11);  // *2048
            #pragma unroll
            for (int cc = 0; cc < 2; cc++) {
                int c = lane + cc * 64;
                v8h lo, hi;
                #pragma unroll
                for (int k = 0; k < 8; k++) {
                    lo[k] = myslice[k * 136 + c];
                    hi[k] = myslice[(k + 8) * 136 + c];
                }
                *(v8h*)(chunk + c * 16)     = lo;
                *(v8h*)(chunk + c * 16 + 8) = hi;
            }
        }
        // ---- qk_pos = p @ wqk + bqk ----
        {
            v4f c = {0.f, 0.f, 0.f, 0.f};
            #pragma unroll
            for (int kt = 0; kt < 4; kt++) {
                v8h av = *(const v8h*)&myslice[l15 * 136 + kt * 32 + quad * 8];
                v8h wq = *(const v8h*)&wqT[l15 * 136 + kt * 32 + quad * 8];
                c = MFMA16(av, wq, c);
            }
            if (l15 < 4) {
                #pragma unroll
                for (int rg2 = 0; rg2 < 4; rg2++) {
                    int row = quad * 4 + rg2;
                    qkpos[(long)(P0w + row) * 4 + l15] = c[rg2] + bqv;
                }
            }
        }
    }

    // ---- fused former K2b: first 384 waves each do one 16x384 qk tile ----
    {
        int gw = blockIdx.x * 8 + wv;
        if (gw < 384) {
            const int bh = gw / 48;
            const int rest = gw - bh * 48;
            const int it = rest >> 1, nh = rest & 1;
            const int bb = bh >> 2, hh = bh & 3;
            const int i0 = it * 16;
            v8h A0 = *(const v8h*)&qh[((long)(bh * N_) + i0 + l15) * DH_ + quad * 8];
            v8h A1 = *(const v8h*)&qh[((long)(bh * N_) + i0 + l15) * DH_ + 32 + quad * 8];
            #pragma unroll 1
            for (int nt = 0; nt < 12; nt++) {
                int jq0 = nh * 192 + nt * 16;
                v8h B0 = *(const v8h*)&kh[((long)(bh * N_) + jq0 + l15) * DH_ + quad * 8];
                v8h B1 = *(const v8h*)&kh[((long)(bh * N_) + jq0 + l15) * DH_ + 32 + quad * 8];
                v4f c = {0.f, 0.f, 0.f, 0.f};
                c = MFMA16(A0, B0, c);
                c = MFMA16(A1, B1, c);
                #pragma unroll
                for (int rg2 = 0; rg2 < 4; rg2++) {
                    int i = i0 + quad * 4 + rg2;
                    int j = jq0 + l15;
                    long idx = (((long)(bb * N_ + i)) * N_ + j) * 4 + hh;
                    qkq[idx] = c[rg2];
                }
            }
        }
    }
}

// ---------- K3M: fused edge-MLP/softmax/coor-branch/ap(MFMA)/attn@v/out-proj ----------
__global__ __launch_bounds__(384) void eq_k3m(
    const float* __restrict__ edges, const float* __restrict__ qkpos,
    const float* __restrict__ qkq,
    const _Float16* __restrict__ pT, const float* __restrict__ v,
    const float* __restrict__ coors,
    const float* __restrict__ w_e1, const float* __restrict__ w_e2,
    const float* __restrict__ w_c, const float* __restrict__ w_cg,
    const float* __restrict__ b_cg, const float* __restrict__ w_th,
    const float* __restrict__ cscale, const float* __restrict__ ccomb,
    const float* __restrict__ og, const float* __restrict__ rg,
    const float* __restrict__ w_vpos, const float* __restrict__ b_vpos,
    const float* __restrict__ w_out, const float* __restrict__ b_out,
    float* __restrict__ out0, float* __restrict__ out1) {
    int row = blockIdx.x;           // b*N + i
    int b = row / N_, i = row - b * N_;
    int j = threadIdx.x;            // 0..383
    __shared__ float we1[20 * 40];
    __shared__ float we2[40 * 4];
    __shared__ float wcs[16], wcgs[16], bcgs[4], wths[16];
    __shared__ float attnS[4 * N_];
    __shared__ float apS[2 * 4 * PD_];
    __shared__ float nodeS[256];
    __shared__ float4 red4[34];     // [0..15] reduce slots, [16..33] reduce12

    for (int idx = j; idx < 800; idx += 384) we1[idx] = w_e1[idx];
    if (j < 160) we2[j] = w_e2[j];
    if (j < 16) { wcs[j] = w_c[j]; wcgs[j] = w_cg[j]; wths[j] = w_th[j]; }
    if (j < 4) bcgs[j] = b_cg[j];
    __syncthreads();

    // ---- phase A: scores (pos + qk) + edge MLP ----
    long pair = ((long)row) * N_ + j;
    float in20[20];
    {
        float4 qp = *(const float4*)(qkpos + pair * 4);
        float4 qq = *(const float4*)(qkq + pair * 4);
        in20[0] = qp.x + qq.x; in20[1] = qp.y + qq.y;
        in20[2] = qp.z + qq.z; in20[3] = qp.w + qq.w;
    }
    const float4* ep = (const float4*)(edges + pair * ED_);
    float4 e0 = ep[0], e1 = ep[1], e2 = ep[2], e3 = ep[3];
    in20[4] = e0.x;  in20[5] = e0.y;  in20[6] = e0.z;  in20[7] = e0.w;
    in20[8] = e1.x;  in20[9] = e1.y;  in20[10] = e1.z; in20[11] = e1.w;
    in20[12] = e2.x; in20[13] = e2.y; in20[14] = e2.z; in20[15] = e2.w;
    in20[16] = e3.x; in20[17] = e3.y; in20[18] = e3.z; in20[19] = e3.w;

    float c0 = 0, c1 = 0, c2 = 0, c3 = 0;
    #pragma unroll 1
    for (int oc = 0; oc < 5; oc++) {
        float a8[8] = {0.f, 0.f, 0.f, 0.f, 0.f, 0.f, 0.f, 0.f};
        #pragma unroll
        for (int c = 0; c < 20; c++) {
            float xc = in20[c];
            float4 wa = *(const float4*)&we1[c * 40 + oc * 8];
            float4 wb = *(const float4*)&we1[c * 40 + oc * 8 + 4];
            a8[0] += xc * wa.x; a8[1] += xc * wa.y; a8[2] += xc * wa.z; a8[3] += xc * wa.w;
            a8[4] += xc * wb.x; a8[5] += xc * wb.y; a8[6] += xc * wb.z; a8[7] += xc * wb.w;
        }
        #pragma unroll
        for (int o = 0; o < 8; o++) {
            float gg = gelu_(a8[o]);
            float4 w2v = *(const float4*)&we2[(oc * 8 + o) * 4];
            c0 += gg * w2v.x; c1 += gg * w2v.y; c2 += gg * w2v.z; c3 += gg * w2v.w;
        }
    }
    float cmi[4] = {c0, c1, c2, c3};
    float gc[4], cp[4], rs[4];
    #pragma unroll
    for (int h = 0; h < 4; h++) gc[h] = gelu_(cmi[h]);
    #pragma unroll
    for (int h = 0; h < 4; h++) {
        cp[h] = gc[0] * wcs[h] + gc[1] * wcs[4 + h] + gc[2] * wcs[8 + h] + gc[3] * wcs[12 + h];
        rs[h] = cmi[0] * wcgs[h] + cmi[1] * wcgs[4 + h] + cmi[2] * wcgs[8 + h] + cmi[3] * wcgs[12 + h] + bcgs[h];
    }

    // ---- phase B: softmax over j + talking heads -> attnS ----
    float4 m4 = block_reduce4(make_float4(cmi[0], cmi[1], cmi[2], cmi[3]), true, red4, 0);
    float e[4];
    e[0] = __expf(cmi[0] - m4.x); e[1] = __expf(cmi[1] - m4.y);
    e[2] = __expf(cmi[2] - m4.z); e[3] = __expf(cmi[3] - m4.w);
    float4 l4 = block_reduce4(make_float4(e[0], e[1], e[2], e[3]), false, red4, 1);
    float sm[4] = {e[0] * rcp_(l4.x), e[1] * rcp_(l4.y), e[2] * rcp_(l4.z), e[3] * rcp_(l4.w)};
    #pragma unroll
    for (int h = 0; h < 4; h++)
        attnS[h * N_ + j] = wths[h * 4 + 0] * sm[0] + wths[h * 4 + 1] * sm[1]
                          + wths[h * 4 + 2] * sm[2] + wths[h * 4 + 3] * sm[3];

    // ---- phase C: coordinate branch -> out1 ----
    float dx = coors[(b * N_ + i) * 3 + 0] - coors[(b * N_ + j) * 3 + 0];
    float dy = coors[(b * N_ + i) * 3 + 1] - coors[(b * N_ + j) * 3 + 1];
    float dz = coors[(b * N_ + i) * 3 + 2] - coors[(b * N_ + j) * 3 + 2];
    float nrm = sqrtf(dx * dx + dy * dy + dz * dz);
    float sc = cscale[0] * rcp_(fmaxf(nrm, 1e-8f));
    float rx = dx * sc, ry = dy * sc, rz = dz * sc;
    float4 cm4 = block_reduce4(make_float4(cp[0], cp[1], cp[2], cp[3]), true, red4, 0);
    float ec[4];
    ec[0] = __expf(cp[0] - cm4.x); ec[1] = __expf(cp[1] - cm4.y);
    ec[2] = __expf(cp[2] - cm4.z); ec[3] = __expf(cp[3] - cm4.w);
    float4 cl4 = block_reduce4(make_float4(ec[0], ec[1], ec[2], ec[3]), false, red4, 1);
    float w[4] = {ec[0] * rcp_(cl4.x) * rs[0], ec[1] * rcp_(cl4.y) * rs[1],
                  ec[2] * rcp_(cl4.z) * rs[2], ec[3] * rcp_(cl4.w) * rs[3]};
    float rv[12];
    #pragma unroll
    for (int h = 0; h < 4; h++) { rv[h] = w[h] * rx; rv[4 + h] = w[h] * ry; rv[8 + h] = w[h] * rz; }
    #pragma unroll
    for (int o = 32; o > 0; o >>= 1) {
        #pragma unroll
        for (int k = 0; k < 12; k++) rv[k] += __shfl_xor(rv[k], o);
    }
    if ((j & 63) == 0) {
        int wid = j >> 6;
        red4[16 + wid * 3 + 0] = make_float4(rv[0], rv[1], rv[2], rv[3]);
        red4[16 + wid * 3 + 1] = make_float4(rv[4], rv[5], rv[6], rv[7]);
        red4[16 + wid * 3 + 2] = make_float4(rv[8], rv[9], rv[10], rv[11]);
    }
    __syncthreads();    // attnS + reduce12 ready
    if (j == 0) {
        float4 sx4 = red4[16], sy4 = red4[17], sz4 = red4[18];
        #pragma unroll
        for (int w2 = 1; w2 < 6; w2++) {
            float4 ax = red4[16 + w2 * 3 + 0], ay = red4[16 + w2 * 3 + 1], az = red4[16 + w2 * 3 + 2];
            sx4.x += ax.x; sx4.y += ax.y; sx4.z += ax.z; sx4.w += ax.w;
            sy4.x += ay.x; sy4.y += ay.y; sy4.z += ay.z; sy4.w += ay.w;
            sz4.x += az.x; sz4.y += az.y; sz4.z += az.z; sz4.w += az.w;
        }
        float f0 = ccomb[0] * rg[(b * H_ + 0) * N_ + i];
        float f1 = ccomb[1] * rg[(b * H_ + 1) * N_ + i];
        float f2 = ccomb[2] * rg[(b * H_ + 2) * N_ + i];
        float f3 = ccomb[3] * rg[(b * H_ + 3) * N_ + i];
        out1[(b * N_ + i) * 3 + 0] = f0 * sx4.x + f1 * sx4.y + f2 * sx4.z + f3 * sx4.w;
        out1[(b * N_ + i) * 3 + 1] = f0 * sy4.x + f1 * sy4.y + f2 * sy4.z + f3 * sy4.w;
        out1[(b * N_ + i) * 3 + 2] = f0 * sz4.x + f1 * sz4.y + f2 * sz4.z + f3 * sz4.w;
    }

    // ---- phase D: waves 0-1 -> ap via MFMA; threads 128..383 -> attn@v ----
    if (j < 128) {
        const int lane = j & 63, l15d = lane & 15, quadd = lane >> 4;
        const int parity = j >> 6;
        const int hh = l15d & 3;
        const float msk = (l15d < 4) ? 1.f : 0.f;
        v4f acc[8];
        #pragma unroll
        for (int nt = 0; nt < 8; nt++) { v4f z = {0.f, 0.f, 0.f, 0.f}; acc[nt] = z; }
        #pragma unroll 2
        for (int kth = 0; kth < 6; kth++) {
            int kt = parity * 6 + kth;
            float4 a0 = *(const float4*)&attnS[hh * N_ + kt * 32 + quadd * 8];
            float4 a1 = *(const float4*)&attnS[hh * N_ + kt * 32 + quadd * 8 + 4];
            v8h Af;
            Af[0] = (_Float16)(a0.x * msk); Af[1] = (_Float16)(a0.y * msk);
            Af[2] = (_Float16)(a0.z * msk); Af[3] = (_Float16)(a0.w * msk);
            Af[4] = (_Float16)(a1.x * msk); Af[5] = (_Float16)(a1.y * msk);
            Af[6] = (_Float16)(a1.z * msk); Af[7] = (_Float16)(a1.w * msk);
            const _Float16* chunkp = pT + (((long)row * 24 + kt * 2 + (quadd >> 1)) << 11)
                                        + ((quadd & 1) << 3);
            #pragma unroll
            for (int nt = 0; nt < 8; nt++) {
                v8h Bv = *(const v8h*)&chunkp[(nt * 16 + l15d) * 16];
                acc[nt] = MFMA16(Af, Bv, acc[nt]);
            }
        }
        if (quadd == 0) {
            #pragma unroll
            for (int nt = 0; nt < 8; nt++)
                #pragma unroll
                for (int rg2 = 0; rg2 < 4; rg2++)
                    apS[parity * 512 + rg2 * 128 + nt * 16 + l15d] = acc[nt][rg2];
        }
    } else {
        int tt = j - 128, h = tt >> 6, d = tt & 63;
        float acc = 0;
        const float* vp = v + ((long)(b * H_ + h) * N_) * DH_ + d;
        #pragma unroll 16
        for (int jj = 0; jj < N_; jj++) acc += attnS[h * N_ + jj] * vp[(long)jj * DH_];
        nodeS[tt] = acc;
    }
    __syncthreads();

    // ---- phase E: node = (attnv + ap@w_vpos + Sh*b_vpos) * out_gate ----
    float nv = 0;
    if (j < 256) {
        int h = j >> 6, d = j & 63;
        float accp = 0;
        const float* wv = w_vpos + h * DH_ + d;
        #pragma unroll 8
        for (int c = 0; c < PD_; c++)
            accp += (apS[h * 128 + c] + apS[512 + h * 128 + c]) * wv[(long)c * (H_ * DH_)];
        float Sh = wths[h * 4 + 0] + wths[h * 4 + 1] + wths[h * 4 + 2] + wths[h * 4 + 3];
        nv = (nodeS[j] + accp + Sh * b_vpos[h * DH_ + d]) * og[(b * H_ + h) * N_ + i];
    }
    __syncthreads();
    if (j < 256) nodeS[j] = nv;
    __syncthreads();

    // ---- phase F: out0 = node @ w_out + b_out ----
    if (j < 256) {
        float acc = b_out[j];
        const float* wo = w_out + j;
        #pragma unroll 4
        for (int c4 = 0; c4 < 64; c4++) {
            float4 nv4 = *(const float4*)&nodeS[c4 * 4];
            acc += nv4.x * wo[(long)(c4 * 4 + 0) * 256]
                 + nv4.y * wo[(long)(c4 * 4 + 1) * 256]
                 + nv4.z * wo[(long)(c4 * 4 + 2) * 256]
                 + nv4.w * wo[(long)(c4 * 4 + 3) * 256];
        }
        out0[(long)row * 256 + j] = acc;
    }
}

extern "C" void kernel_launch(void* const* d_in, const int* in_sizes, int n_in,
                              void* d_out, int out_size, void* d_ws, size_t ws_size,
                              hipStream_t stream) {
    (void)in_sizes; (void)n_in; (void)out_size; (void)ws_size;
    const float* feats   = (const float*)d_in[0];
    const float* coors   = (const float*)d_in[1];
    const float* edges   = (const float*)d_in[2];
    const float* gamma   = (const float*)d_in[3];
    const float* w_qkv   = (const float*)d_in[4];
    const float* w_gate  = (const float*)d_in[5];
    const float* b_gate  = (const float*)d_in[6];
    const float* w_th    = (const float*)d_in[7];
    const float* w_e1    = (const float*)d_in[8];
    const float* w_e2    = (const float*)d_in[9];
    const float* w_c     = (const float*)d_in[10];
    const float* w_cg    = (const float*)d_in[11];
    const float* b_cg    = (const float*)d_in[12];
    const float* cscale  = (const float*)d_in[13];
    const float* ccomb   = (const float*)d_in[14];
    const float* pb_w0   = (const float*)d_in[15];
    const float* pb_b0   = (const float*)d_in[16];
    const float* pb_g0   = (const float*)d_in[17];
    const float* pb_be0  = (const float*)d_in[18];
    const float* pb_w1   = (const float*)d_in[19];
    const float* pb_b1   = (const float*)d_in[20];
    const float* pb_g1   = (const float*)d_in[21];
    const float* pb_be1  = (const float*)d_in[22];
    const float* pb_w2   = (const float*)d_in[23];
    const float* pb_b2   = (const float*)d_in[24];
    const float* pb_g2   = (const float*)d_in[25];
    const float* pb_be2  = (const float*)d_in[26];
    const float* w_qkpos = (const float*)d_in[27];
    const float* b_qkpos = (const float*)d_in[28];
    const float* w_vpos  = (const float*)d_in[29];
    const float* b_vpos  = (const float*)d_in[30];
    const float* w_out   = (const float*)d_in[31];
    const float* b_out   = (const float*)d_in[32];

    // workspace carve (bytes)
    char* ws = (char*)d_ws;
    _Float16* qh   = (_Float16*)(ws + 0);            // 393216 B
    _Float16* kh   = (_Float16*)(ws + 393216);       // 393216 B
    float* v       = (float*)(ws + 786432);          // 786432 B
    float* og      = (float*)(ws + 1572864);         // 12288 B
    float* rg      = (float*)(ws + 1585152);         // 12288 B
    float* qkpos   = (float*)(ws + 1597440);         // 4718592 B
    _Float16* pT   = (_Float16*)(ws + 6316032);      // 75497472 B (tiled chunks)
    float* qkq     = (float*)(ws + 81813504);        // 4718592 B

    float* out0 = (float*)d_out;
    float* out1 = out0 + (long)B_ * N_ * DIM_;

    const int K2_LDS = 110336;
    hipFuncSetAttribute((const void*)eq_k2, hipFuncAttributeMaxDynamicSharedMemorySize, K2_LDS);

    eq_k1<<<192, 256, 0, stream>>>(feats, gamma, w_qkv, w_gate, b_gate, qh, kh, v, og, rg);
    eq_k2<<<256, 512, K2_LDS, stream>>>(coors, pb_w0, pb_b0, pb_g0, pb_be0,
                                        pb_w1, pb_b1, pb_g1, pb_be1,
                                        pb_w2, pb_b2, pb_g2, pb_be2,
                                        w_qkpos, b_qkpos, qh, kh, pT, qkpos, qkq);
    eq_k3m<<<B_ * N_, 384, 0, stream>>>(edges, qkpos, qkq, pT, v, coors,
                                        w_e1, w_e2, w_c, w_cg, b_cg, w_th,
                                        cscale, ccomb, og, rg,
                                        w_vpos, b_vpos, w_out, b_out, out0, out1);
}